// Round 2
// baseline (17622.594 us; speedup 1.0000x reference)
//
#include <hip/hip_runtime.h>
#include <hip/hip_cooperative_groups.h>
#include <math.h>

namespace cg = cooperative_groups;

#define BATCH 512
#define TM1   31
#define DIMD  256

typedef _Float16 f16;
typedef _Float16 half2v __attribute__((ext_vector_type(2)));
typedef _Float16 half8 __attribute__((ext_vector_type(8)));
typedef float floatx16 __attribute__((ext_vector_type(16)));

__device__ __forceinline__ float sigmf(float x) { return 1.f / (1.f + __expf(-x)); }

__device__ __forceinline__ float tanh_fast(float x) {
    float ax = fabsf(x);
    float t  = __expf(-2.f * ax);
    float r  = (1.f - t) / (1.f + t);
    return copysignf(r, x);
}

__device__ __forceinline__ float blockReduceSum256(float v, float* sred) {
#pragma unroll
    for (int m = 32; m > 0; m >>= 1) v += __shfl_xor(v, m);
    __syncthreads();
    if ((threadIdx.x & 63) == 0) sred[threadIdx.x >> 6] = v;
    __syncthreads();
    return sred[0] + sred[1] + sred[2] + sred[3];
}

__device__ __forceinline__ float blockReduceMax256(float v, float* sred) {
#pragma unroll
    for (int m = 32; m > 0; m >>= 1) v = fmaxf(v, __shfl_xor(v, m));
    __syncthreads();
    if ((threadIdx.x & 63) == 0) sred[threadIdx.x >> 6] = v;
    __syncthreads();
    return fmaxf(fmaxf(sred[0], sred[1]), fmaxf(sred[2], sred[3]));
}

// ---------------------------------------------------------------------------
// prep + t2s fused (unchanged).
// ---------------------------------------------------------------------------
__global__ __launch_bounds__(256) void prep_t2s_kernel(
    const float* __restrict__ inputs,
    const float* __restrict__ eWih, const float* __restrict__ eWhh,
    const float* __restrict__ ebih, const float* __restrict__ ebhh,
    const float* __restrict__ dW1,  const float* __restrict__ dWhh,
    const float* __restrict__ dbih, const float* __restrict__ dbhh,
    const float* __restrict__ Wd,   const float* __restrict__ bd,
    const float* __restrict__ Wc,
    f16* __restrict__ eWf, f16* __restrict__ dWcf, f16* __restrict__ Vwf,
    float* __restrict__ ebcomb, float* __restrict__ dbias,
    f16* __restrict__ t2s, f16* __restrict__ Wcf)
{
    __shared__ float sX[TM1 * DIMD];
    __shared__ float sWd[TM1 * TM1];
    int b = blockIdx.x, tid = threadIdx.x;
    int idx = b * 256 + tid;
    const int stride = gridDim.x * 256;

    if (b < 512) {
        for (int i = tid; i < TM1 * DIMD; i += 256) {
            int tt = i >> 8, d = i & 255;
            sX[i] = inputs[((size_t)b * TM1 + tt) * 257 + 1 + d];
        }
        for (int i = tid; i < TM1 * TM1; i += 256) sWd[i] = Wd[i];
        __syncthreads();
        int d = tid;
        for (int s = 0; s < TM1; s++) {
            float acc = bd[s];
            for (int tt = 0; tt < TM1; tt++) acc += sX[tt * DIMD + d] * sWd[s * TM1 + tt];
            t2s[((size_t)b * TM1 + s) * DIMD + d] = (f16)acc;
        }
    }

    for (int g = idx; g < 2048 * 96; g += stride) {
        int n = g / 96, k0 = (g % 96) * 8;
        const float* src = (k0 < 256) ? (eWih + n * 256 + k0)
                                      : (eWhh + n * 512 + (k0 - 256));
        float4 v0 = *(const float4*)src;
        float4 v1 = *(const float4*)(src + 4);
        f16 h[8] = {(f16)v0.x, (f16)v0.y, (f16)v0.z, (f16)v0.w,
                    (f16)v1.x, (f16)v1.y, (f16)v1.z, (f16)v1.w};
        *(half8*)(eWf + n * 768 + k0) = *(half8*)h;
    }
    for (int g = idx; g < 2560 * 128; g += stride) {
        int n = g >> 7, k0 = (g & 127) * 8;
        float vv[8] = {};
        if (n < 512) {
            const float* src = dW1 + n * 1536 + k0;
            float4 v0 = *(const float4*)src, v1 = *(const float4*)(src + 4);
            vv[0]=v0.x; vv[1]=v0.y; vv[2]=v0.z; vv[3]=v0.w;
            vv[4]=v1.x; vv[5]=v1.y; vv[6]=v1.z; vv[7]=v1.w;
        } else if (k0 < 512) {
            const float* src = dWhh + (n - 512) * 512 + k0;
            float4 v0 = *(const float4*)src, v1 = *(const float4*)(src + 4);
            vv[0]=v0.x; vv[1]=v0.y; vv[2]=v0.z; vv[3]=v0.w;
            vv[4]=v1.x; vv[5]=v1.y; vv[6]=v1.z; vv[7]=v1.w;
        }
        f16 h[8];
#pragma unroll
        for (int e = 0; e < 8; e++) h[e] = (f16)vv[e];
        *(half8*)(dWcf + n * 1024 + k0) = *(half8*)h;
    }
    for (int g = idx; g < 512 * 64; g += stride) {
        int n = g >> 6, k0 = (g & 63) * 8;
        const float* src = dW1 + n * 1536 + 1024 + k0;
        float4 v0 = *(const float4*)src, v1 = *(const float4*)(src + 4);
        f16 h[8] = {(f16)v0.x, (f16)v0.y, (f16)v0.z, (f16)v0.w,
                    (f16)v1.x, (f16)v1.y, (f16)v1.z, (f16)v1.w};
        *(half8*)(Vwf + n * 512 + k0) = *(half8*)h;
    }
    for (int g = idx; g < 3968; g += stride) {
        int k0 = g * 8;
        float4 v0 = *(const float4*)(Wc + k0);
        float4 v1 = *(const float4*)(Wc + k0 + 4);
        f16 h[8] = {(f16)v0.x, (f16)v0.y, (f16)v0.z, (f16)v0.w,
                    (f16)v1.x, (f16)v1.y, (f16)v1.z, (f16)v1.w};
        *(half8*)(Wcf + k0) = *(half8*)h;
    }
    for (int i = idx; i < 2048; i += stride) ebcomb[i] = ebih[i] + ebhh[i];
    for (int i = idx; i < 2560; i += stride)
        dbias[i] = (i < 512) ? 0.f : (dbih[i - 512] + dbhh[i - 512]);
}

// ---------------------------------------------------------------------------
// FALLBACK: step GEMM (R14-validated).
// ---------------------------------------------------------------------------
__global__ __launch_bounds__(256) void gemm1f(
    const f16* __restrict__ A, int lda,
    const f16* __restrict__ W, int ldw,
    const float* __restrict__ bias, f16* __restrict__ C, int ldc,
    long long Cstride, int K, int nsplit, int NT, int MT, int KS)
{
    __shared__ f16 sAh[64 * 128];
    __shared__ f16 sWh[64 * 128];
    int tid = threadIdx.x, bid = blockIdx.x;
    int nbase = bid % NT;
    int m0 = ((bid / NT) % MT) * 64;
    int ks = bid / (NT * MT);
    int lane = tid & 63, wid = tid >> 6;
    int wm = wid >> 1, wn = wid & 1;
    int rl = lane & 31, kq = lane >> 5;

    int sr = tid >> 2;
    int gb = (tid & 3) * 4;
    int st0 = sr * 128 + (((gb + 0) ^ (sr & 15)) * 8);
    int st1 = sr * 128 + (((gb + 1) ^ (sr & 15)) * 8);
    int st2 = sr * 128 + (((gb + 2) ^ (sr & 15)) * 8);
    int st3 = sr * 128 + (((gb + 3) ^ (sr & 15)) * 8);
    int arow = (wm * 32 + rl) * 128;
    int wrow = (wn * 32 + rl) * 128;
    int swk = rl & 15;

    int n0 = nbase * 64;
    int Kfull = (n0 >= nsplit) ? 512 : K;
    int ksz = Kfull / KS;
    int kbeg = ks * ksz, kend = kbeg + ksz;

    const f16* pA = A + (size_t)(m0 + sr) * lda + gb * 8;
    const f16* pW = W + (size_t)(n0 + sr) * ldw + gb * 8;

    float4 rA0 = *(const float4*)(pA + kbeg);
    float4 rA1 = *(const float4*)(pA + kbeg + 8);
    float4 rA2 = *(const float4*)(pA + kbeg + 16);
    float4 rA3 = *(const float4*)(pA + kbeg + 24);
    float4 rW0 = *(const float4*)(pW + kbeg);
    float4 rW1 = *(const float4*)(pW + kbeg + 8);
    float4 rW2 = *(const float4*)(pW + kbeg + 16);
    float4 rW3 = *(const float4*)(pW + kbeg + 24);

    floatx16 acc = {};
    for (int k0 = kbeg; k0 < kend; k0 += 128) {
        __syncthreads();
        *(float4*)&sAh[st0] = rA0; *(float4*)&sAh[st1] = rA1;
        *(float4*)&sAh[st2] = rA2; *(float4*)&sAh[st3] = rA3;
        *(float4*)&sWh[st0] = rW0; *(float4*)&sWh[st1] = rW1;
        *(float4*)&sWh[st2] = rW2; *(float4*)&sWh[st3] = rW3;
        __syncthreads();
        int kn = k0 + 128;
        if (kn < kend) {
            rA0 = *(const float4*)(pA + kn);      rA1 = *(const float4*)(pA + kn + 8);
            rA2 = *(const float4*)(pA + kn + 16); rA3 = *(const float4*)(pA + kn + 24);
            rW0 = *(const float4*)(pW + kn);      rW1 = *(const float4*)(pW + kn + 8);
            rW2 = *(const float4*)(pW + kn + 16); rW3 = *(const float4*)(pW + kn + 24);
        }
#pragma unroll
        for (int kk = 0; kk < 128; kk += 16) {
            int lg = (kk >> 3) + kq;
            half8 ah = *(const half8*)&sAh[arow + ((lg ^ swk) * 8)];
            half8 wh = *(const half8*)&sWh[wrow + ((lg ^ swk) * 8)];
            acc = __builtin_amdgcn_mfma_f32_32x32x16_f16(ah, wh, acc, 0, 0, 0);
        }
    }

    int col = n0 + wn * 32 + rl;
    float bv = (ks == 0) ? bias[col] : 0.f;
    f16* Cp = C + (size_t)ks * Cstride;
#pragma unroll
    for (int rr = 0; rr < 16; ++rr) {
        int row = m0 + wm * 32 + (rr & 3) + 8 * (rr >> 2) + 4 * kq;
        Cp[(size_t)row * ldc + col] = (f16)(acc[rr] + bv);
    }
}

// ---------------------------------------------------------------------------
// FALLBACK: encoder step (R14-validated).
// ---------------------------------------------------------------------------
__global__ __launch_bounds__(256) void enc_step_kernel(
    const float* __restrict__ inputs, const f16* __restrict__ t2s,
    const f16* __restrict__ Wcf, const float* __restrict__ bc,
    const float* __restrict__ Wa, const float* __restrict__ ba,
    const f16* __restrict__ g, long long gstride,
    float* __restrict__ hc,
    f16* __restrict__ Ahi, f16* __restrict__ enchi,
    float* __restrict__ hc_dec, f16* __restrict__ hdhi,
    int t) {
    __shared__ float sh_hc[1024];
    __shared__ float t1s[32];
    __shared__ float sred[4];
    int b = blockIdx.x, tid = threadIdx.x;

    if (t > 0) {
        int e = tid * 2;
        const f16* gp = g + (size_t)b * 2048 + e;
        float gi0 = 0.f, gi1 = 0.f, gf0 = 0.f, gf1 = 0.f;
        float gg0 = 0.f, gg1 = 0.f, go0 = 0.f, go1 = 0.f;
#pragma unroll
        for (int s = 0; s < 2; s++) {
            const f16* q = gp + s * gstride;
            half2v a = *(const half2v*)(q);
            half2v f = *(const half2v*)(q + 512);
            half2v gv = *(const half2v*)(q + 1024);
            half2v o = *(const half2v*)(q + 1536);
            gi0 += (float)a[0]; gi1 += (float)a[1];
            gf0 += (float)f[0]; gf1 += (float)f[1];
            gg0 += (float)gv[0]; gg1 += (float)gv[1];
            go0 += (float)o[0]; go1 += (float)o[1];
        }
        float2 cpv = *(const float2*)(hc + b * 1024 + 512 + e);
        float c20 = sigmf(gf0) * cpv.x + sigmf(gi0) * tanh_fast(gg0);
        float c21 = sigmf(gf1) * cpv.y + sigmf(gi1) * tanh_fast(gg1);
        float h20 = sigmf(go0) * tanh_fast(c20);
        float h21 = sigmf(go1) * tanh_fast(c21);
        *(float2*)(hc + b * 1024 + 512 + e) = make_float2(c20, c21);
        sh_hc[e] = h20; sh_hc[e + 1] = h21;
        sh_hc[512 + e] = c20; sh_hc[512 + e + 1] = c21;
        half2v hv; hv[0] = (f16)h20; hv[1] = (f16)h21;
        *(half2v*)(enchi + ((size_t)b * TM1 + (t - 1)) * 512 + e) = hv;
    } else {
        for (int j = tid; j < 1024; j += 256) { sh_hc[j] = 0.f; }
        for (int j = tid; j < 512; j += 256) hc[b * 1024 + 512 + j] = 0.f;
    }
    if (t == TM1) {
        for (int j = tid; j < 512; j += 256) hc_dec[b * 1024 + 512 + j] = 0.f;
        for (int j = tid; j < 1024; j += 256) hdhi[b * 1024 + j] = (f16)0.f;
        return;
    }
    __syncthreads();

    if (tid < 248) {
        int s = tid >> 3, l8 = tid & 7;
        const f16* wrow = Wcf + s * 1024;
        float p = 0.f;
        for (int j = l8 * 8; j < 1024; j += 64) {
            half8 w8 = *(const half8*)(wrow + j);
#pragma unroll
            for (int e = 0; e < 8; e++) p += (float)w8[e] * sh_hc[j + e];
        }
        p += __shfl_xor(p, 1); p += __shfl_xor(p, 2); p += __shfl_xor(p, 4);
        if (l8 == 0) t1s[s] = p + bc[s];
    }
    __syncthreads();

    int d = tid;
    float sc = ba[0];
    const f16* t2p = t2s + ((size_t)b * TM1) * DIMD + d;
    for (int s = 0; s < TM1; s++) sc += tanh_fast(t1s[s] + (float)t2p[s * DIMD]) * Wa[s];
    float mx = blockReduceMax256(sc, sred);
    float ex = __expf(sc - mx);
    float sm = blockReduceSum256(ex, sred);
    float w = (ex / sm) * inputs[((size_t)b * TM1 + t) * 257 + 1 + d];
    Ahi[b * 768 + d] = (f16)w;
    {
        int j = tid * 2;
        half2v hv; hv[0] = (f16)sh_hc[j]; hv[1] = (f16)sh_hc[j + 1];
        *(half2v*)(Ahi + b * 768 + 256 + j) = hv;
    }
}

// ---------------------------------------------------------------------------
// FALLBACK: decoder step (R14-validated).
// ---------------------------------------------------------------------------
__global__ __launch_bounds__(256) void dec_step_kernel(
    const float* __restrict__ inputs, const f16* __restrict__ V,
    const float* __restrict__ W2, const float* __restrict__ b2,
    const f16* __restrict__ enchi,
    const float* __restrict__ fcW, const float* __restrict__ fcb,
    const float* __restrict__ Wih,
    const f16* __restrict__ gu, long long ustride,
    float* __restrict__ hc, f16* __restrict__ hdhi,
    const float* __restrict__ fcfW, const float* __restrict__ fcfb,
    float* __restrict__ out, int t) {
    __shared__ float su[512];
    __shared__ float sw2[512];
    __shared__ float s_att[TM1];
    __shared__ float sred[4];
    int b = blockIdx.x, tid = threadIdx.x;
    const bool last = (t == TM1 - 1);
    {
        int e = tid * 2;
        const f16* q = gu + (size_t)b * 2560 + e;
        half2v a0 = *(const half2v*)(q);
        half2v a1 = *(const half2v*)(q + ustride);
        su[e]     = (float)a0[0] + (float)a1[0];
        su[e + 1] = (float)a0[1] + (float)a1[1];
        sw2[e] = W2[e]; sw2[e + 1] = W2[e + 1];
    }
    __syncthreads();
    if (tid < 248) {
        int tp = tid >> 3, l8 = tid & 7;
        const f16* vrow = V + ((size_t)b * TM1 + tp) * 512;
        float p = 0.f;
        for (int j = l8 * 8; j < 512; j += 64) {
            half8 v8 = *(const half8*)(vrow + j);
#pragma unroll
            for (int e = 0; e < 8; e++)
                p += tanh_fast(su[j + e] + (float)v8[e]) * sw2[j + e];
        }
        p += __shfl_xor(p, 1); p += __shfl_xor(p, 2); p += __shfl_xor(p, 4);
        if (l8 == 0) s_att[tp] = p + b2[0];
    }
    __syncthreads();
    if (tid < 64) {
        float v = (tid < TM1) ? s_att[tid] : -3.4e38f;
        float m = v;
#pragma unroll
        for (int k = 32; k > 0; k >>= 1) m = fmaxf(m, __shfl_xor(m, k));
        float e = (tid < TM1) ? __expf(v - m) : 0.f;
        float s = e;
#pragma unroll
        for (int k = 32; k > 0; k >>= 1) s += __shfl_xor(s, k);
        if (tid < TM1) s_att[tid] = e / s;
    }
    __syncthreads();

    float part, pctx = 0.f;
    {
        int e = tid * 2;
        float cx0 = 0.f, cx1 = 0.f;
        const f16* eh = enchi + (size_t)b * TM1 * 512 + e;
        for (int tp = 0; tp < TM1; tp++) {
            half2v v2 = *(const half2v*)(eh + tp * 512);
            cx0 += s_att[tp] * (float)v2[0];
            cx1 += s_att[tp] * (float)v2[1];
        }
        float2 fw = *(const float2*)(fcW + e);
        part = cx0 * fw.x + cx1 * fw.y;
        if (last) {
            float2 fw2 = *(const float2*)(fcfW + 512 + e);
            pctx = cx0 * fw2.x + cx1 * fw2.y;
        }
    }
    float y = inputs[((size_t)b * TM1 + t) * 257];
    float ysum = blockReduceSum256(part, sred);
    float y_til = ysum + y * fcW[512] + fcb[0];

    float ph = 0.f;
    {
        int e = tid * 2;
        const f16* q = gu + (size_t)b * 2560 + e;
        float gi0 = 0.f, gi1 = 0.f, gf0 = 0.f, gf1 = 0.f;
        float gg0 = 0.f, gg1 = 0.f, go0 = 0.f, go1 = 0.f;
#pragma unroll
        for (int s = 0; s < 2; s++) {
            const f16* qq = q + s * ustride;
            half2v a = *(const half2v*)(qq + 512);
            half2v f = *(const half2v*)(qq + 1024);
            half2v gv = *(const half2v*)(qq + 1536);
            half2v o = *(const half2v*)(qq + 2048);
            gi0 += (float)a[0]; gi1 += (float)a[1];
            gf0 += (float)f[0]; gf1 += (float)f[1];
            gg0 += (float)gv[0]; gg1 += (float)gv[1];
            go0 += (float)o[0]; go1 += (float)o[1];
        }
        gi0 += y_til * Wih[e];        gi1 += y_til * Wih[e + 1];
        gf0 += y_til * Wih[512 + e];  gf1 += y_til * Wih[512 + e + 1];
        gg0 += y_til * Wih[1024 + e]; gg1 += y_til * Wih[1024 + e + 1];
        go0 += y_til * Wih[1536 + e]; go1 += y_til * Wih[1536 + e + 1];
        float2 cpv = *(const float2*)(hc + b * 1024 + 512 + e);
        float c20 = sigmf(gf0) * cpv.x + sigmf(gi0) * tanh_fast(gg0);
        float c21 = sigmf(gf1) * cpv.y + sigmf(gi1) * tanh_fast(gg1);
        float h20 = sigmf(go0) * tanh_fast(c20);
        float h21 = sigmf(go1) * tanh_fast(c21);
        if (!last) {
            *(float2*)(hc + b * 1024 + 512 + e) = make_float2(c20, c21);
            half2v hv; hv[0] = (f16)h20; hv[1] = (f16)h21;
            half2v cv; cv[0] = (f16)c20; cv[1] = (f16)c21;
            *(half2v*)(hdhi + (size_t)b * 1024 + e) = hv;
            *(half2v*)(hdhi + (size_t)b * 1024 + 512 + e) = cv;
        } else {
            ph += h20 * fcfW[e] + h21 * fcfW[e + 1];
        }
    }
    if (last) {
        float s = blockReduceSum256(ph + pctx, sred);
        if (tid == 0) out[b] = s + fcfb[0];
    }
}

// ---------------------------------------------------------------------------
// COOP: encoder persistent kernel. Fences around every grid.sync to force
// cross-XCD L2 writeback/invalidate regardless of CG's internal fencing.
// ---------------------------------------------------------------------------
__global__ __launch_bounds__(256, 2) void enc_coop(
    const float* __restrict__ inputs, const f16* __restrict__ t2s,
    const f16* __restrict__ Wcf, const float* __restrict__ bc,
    const float* __restrict__ Wa, const float* __restrict__ ba,
    f16* __restrict__ g, long long gstride,
    f16* __restrict__ Ahi, f16* __restrict__ enchi,
    float* __restrict__ hc_dec, f16* __restrict__ hdhi,
    const f16* __restrict__ eWf, const float* __restrict__ ebcomb)
{
    cg::grid_group gridg = cg::this_grid();
    __shared__ f16 sWh[3 * 8192];      // resident W tile: 64 cols x 384 K (48 KB)
    __shared__ float sh_hc[1024];      // persistent h|c for batch b
    __shared__ float t1s[32];
    __shared__ float sred[4];
    const int b = blockIdx.x, tid = threadIdx.x;

    const int lane = tid & 63, wid = tid >> 6;
    const int wm = wid >> 1, wn = wid & 1;
    const int rl = lane & 31, kq = lane >> 5;
    const int sr = tid >> 2;
    const int gb = (tid & 3) * 4;
    const int st0 = sr * 128 + (((gb + 0) ^ (sr & 15)) * 8);
    const int st1 = sr * 128 + (((gb + 1) ^ (sr & 15)) * 8);
    const int st2 = sr * 128 + (((gb + 2) ^ (sr & 15)) * 8);
    const int st3 = sr * 128 + (((gb + 3) ^ (sr & 15)) * 8);
    const int n0g = (b & 31) * 64;
    const int m0g = ((b >> 5) & 7) * 64;
    const int ksg = b >> 8;
    const int kbeg = ksg * 384;
    const int wrow = (wn * 32 + rl) * 128;
    const int swk = rl & 15;
    const f16* pW  = eWf + (size_t)(n0g + sr) * 768 + gb * 8;
    const f16* pAg = Ahi + (size_t)(m0g + wm * 32 + rl) * 768 + kbeg;
    const int gcol = n0g + wn * 32 + rl;
    const float gbv = (ksg == 0) ? ebcomb[gcol] : 0.f;
    f16* gCp = g + (size_t)ksg * gstride;

    // one-time resident W preload
#pragma unroll
    for (int p = 0; p < 3; ++p) {
        *(float4*)&sWh[p * 8192 + st0] = *(const float4*)(pW + kbeg + p * 128);
        *(float4*)&sWh[p * 8192 + st1] = *(const float4*)(pW + kbeg + p * 128 + 8);
        *(float4*)&sWh[p * 8192 + st2] = *(const float4*)(pW + kbeg + p * 128 + 16);
        *(float4*)&sWh[p * 8192 + st3] = *(const float4*)(pW + kbeg + p * 128 + 24);
    }
    __syncthreads();

    for (int t = 0; t <= TM1; ++t) {
        // ===== phase A: finalize LSTM(t-1) + attention(t) =====
        if (t > 0) {
            int e = tid * 2;
            const f16* gp = g + (size_t)b * 2048 + e;
            float gi0 = 0.f, gi1 = 0.f, gf0 = 0.f, gf1 = 0.f;
            float gg0 = 0.f, gg1 = 0.f, go0 = 0.f, go1 = 0.f;
#pragma unroll
            for (int s = 0; s < 2; s++) {
                const f16* q = gp + s * gstride;
                half2v a = *(const half2v*)(q);
                half2v f = *(const half2v*)(q + 512);
                half2v gv = *(const half2v*)(q + 1024);
                half2v o = *(const half2v*)(q + 1536);
                gi0 += (float)a[0]; gi1 += (float)a[1];
                gf0 += (float)f[0]; gf1 += (float)f[1];
                gg0 += (float)gv[0]; gg1 += (float)gv[1];
                go0 += (float)o[0]; go1 += (float)o[1];
            }
            float c0 = sh_hc[512 + e], c1 = sh_hc[513 + e];
            float c20 = sigmf(gf0) * c0 + sigmf(gi0) * tanh_fast(gg0);
            float c21 = sigmf(gf1) * c1 + sigmf(gi1) * tanh_fast(gg1);
            float h20 = sigmf(go0) * tanh_fast(c20);
            float h21 = sigmf(go1) * tanh_fast(c21);
            sh_hc[e] = h20; sh_hc[e + 1] = h21;
            sh_hc[512 + e] = c20; sh_hc[513 + e] = c21;
            half2v hv; hv[0] = (f16)h20; hv[1] = (f16)h21;
            *(half2v*)(enchi + ((size_t)b * TM1 + (t - 1)) * 512 + e) = hv;
        } else {
            for (int j = tid; j < 1024; j += 256) sh_hc[j] = 0.f;
        }
        if (t == TM1) {
            for (int j = tid; j < 512; j += 256) hc_dec[b * 1024 + 512 + j] = 0.f;
            for (int j = tid; j < 1024; j += 256) hdhi[(size_t)b * 1024 + j] = (f16)0.f;
            break;
        }
        __syncthreads();

        if (tid < 248) {
            int s = tid >> 3, l8 = tid & 7;
            const f16* wr = Wcf + s * 1024;
            float p = 0.f;
            for (int j = l8 * 8; j < 1024; j += 64) {
                half8 w8 = *(const half8*)(wr + j);
#pragma unroll
                for (int e2 = 0; e2 < 8; e2++) p += (float)w8[e2] * sh_hc[j + e2];
            }
            p += __shfl_xor(p, 1); p += __shfl_xor(p, 2); p += __shfl_xor(p, 4);
            if (l8 == 0) t1s[s] = p + bc[s];
        }
        __syncthreads();
        {
            int d = tid;
            float sc = ba[0];
            const f16* t2p = t2s + ((size_t)b * TM1) * DIMD + d;
            for (int s = 0; s < TM1; s++) sc += tanh_fast(t1s[s] + (float)t2p[s * DIMD]) * Wa[s];
            float mx = blockReduceMax256(sc, sred);
            float ex = __expf(sc - mx);
            float sm = blockReduceSum256(ex, sred);
            float w = (ex / sm) * inputs[((size_t)b * TM1 + t) * 257 + 1 + d];
            Ahi[b * 768 + d] = (f16)w;
            int j = tid * 2;
            half2v hv; hv[0] = (f16)sh_hc[j]; hv[1] = (f16)sh_hc[j + 1];
            *(half2v*)(Ahi + b * 768 + 256 + j) = hv;
        }
        __threadfence();
        gridg.sync();
        __threadfence();

        // ===== phase G: g(t) = Ahi @ W^T (tile) =====
        {
            floatx16 acc = {};
            for (int p = 0; p < 3; ++p) {
#pragma unroll
                for (int kk = 0; kk < 128; kk += 16) {
                    int lg = (kk >> 3) + kq;
                    half8 ah = *(const half8*)(pAg + p * 128 + lg * 8);
                    half8 wh = *(const half8*)&sWh[p * 8192 + wrow + ((lg ^ swk) * 8)];
                    acc = __builtin_amdgcn_mfma_f32_32x32x16_f16(ah, wh, acc, 0, 0, 0);
                }
            }
#pragma unroll
            for (int rr = 0; rr < 16; ++rr) {
                int row = m0g + wm * 32 + (rr & 3) + 8 * (rr >> 2) + 4 * kq;
                gCp[(size_t)row * 2048 + gcol] = (f16)(acc[rr] + gbv);
            }
        }
        __threadfence();
        gridg.sync();
        __threadfence();
    }
}

// ---------------------------------------------------------------------------
// V GEMM (unchanged).
// ---------------------------------------------------------------------------
__global__ __launch_bounds__(256) void gemm_v(
    const f16* __restrict__ A, int lda,
    const f16* __restrict__ W, int ldw,
    const float* __restrict__ bias, f16* __restrict__ C, int ldc,
    int K, int NT, int MT, int NREP)
{
    __shared__ f16 sAh[64 * 64];
    __shared__ f16 sWh[64 * 64];
    int tid = threadIdx.x, bid = blockIdx.x;
    int nbase = bid % NT;
    int m0 = ((bid / NT) % MT) * 64;
    int lane = tid & 63, wid = tid >> 6;
    int wm = wid >> 1, wn = wid & 1;
    int rl = lane & 31, kq = lane >> 5;
    int sr = tid >> 2;
    int g0 = (tid & 3) * 2;
    int s0 = sr * 64 + ((g0 ^ (sr & 7)) * 8);
    int s1 = sr * 64 + (((g0 + 1) ^ (sr & 7)) * 8);
    int arow = (wm * 32 + rl) * 64;
    int wrow = (wn * 32 + rl) * 64;
    int sw = (rl & 7);

    const f16* pA = A + (size_t)(m0 + sr) * lda + g0 * 8;

    for (int r = 0; r < NREP; ++r) {
        int n0 = (nbase + r * NT) * 64;
        const f16* pW = W + (size_t)(n0 + sr) * ldw + g0 * 8;
        float4 rA0 = *(const float4*)(pA);
        float4 rA1 = *(const float4*)(pA + 8);
        float4 rW0 = *(const float4*)(pW);
        float4 rW1 = *(const float4*)(pW + 8);
        floatx16 acc = {};
        for (int k0 = 0; k0 < K; k0 += 64) {
            __syncthreads();
            *(float4*)&sAh[s0] = rA0; *(float4*)&sAh[s1] = rA1;
            *(float4*)&sWh[s0] = rW0; *(float4*)&sWh[s1] = rW1;
            __syncthreads();
            int kn = k0 + 64;
            if (kn < K) {
                rA0 = *(const float4*)(pA + kn); rA1 = *(const float4*)(pA + kn + 8);
                rW0 = *(const float4*)(pW + kn); rW1 = *(const float4*)(pW + kn + 8);
            }
#pragma unroll
            for (int kk = 0; kk < 64; kk += 16) {
                int lg = (kk >> 3) + kq;
                int off = ((lg ^ sw) * 8);
                half8 ah = *(const half8*)&sAh[arow + off];
                half8 wh = *(const half8*)&sWh[wrow + off];
                acc = __builtin_amdgcn_mfma_f32_32x32x16_f16(ah, wh, acc, 0, 0, 0);
            }
        }
        int col = n0 + wn * 32 + rl;
        float bv = bias[col];
#pragma unroll
        for (int rr = 0; rr < 16; ++rr) {
            int row = m0 + wm * 32 + (rr & 3) + 8 * (rr >> 2) + 4 * kq;
            C[(size_t)row * ldc + col] = (f16)(acc[rr] + bv);
        }
    }
}

// ---------------------------------------------------------------------------
// COOP: decoder persistent kernel (fenced grid syncs).
// ---------------------------------------------------------------------------
__global__ __launch_bounds__(256, 2) void dec_coop(
    const float* __restrict__ inputs, const f16* __restrict__ V,
    const float* __restrict__ W2, const float* __restrict__ b2,
    const f16* __restrict__ enchi,
    const float* __restrict__ fcW, const float* __restrict__ fcb,
    const float* __restrict__ Wih,
    f16* __restrict__ gu, long long ustride,
    f16* __restrict__ hdhi,
    const float* __restrict__ fcfW, const float* __restrict__ fcfb,
    float* __restrict__ out,
    const f16* __restrict__ dWcf, const float* __restrict__ dbias)
{
    cg::grid_group gridg = cg::this_grid();
    __shared__ f16 sW[4 * 4096];      // resident W tile: 32 cols x 512 K (32 KB)
    __shared__ float su[512];
    __shared__ float sw2[512];
    __shared__ float s_c[512];        // persistent c for batch b
    __shared__ float s_att[TM1];
    __shared__ float sred[4];
    const int b = blockIdx.x, tid = threadIdx.x;
    const int lane = tid & 63, wid = tid >> 6;
    const int rl = lane & 31, kq = lane >> 5;

    const bool gact = (b < 384);
    int n0g = 0, m0g = 0, kbeg = 0, ksf = 0;
    if (b < 256) {            // gate tiles: 64 n x 4 m, K=512 (h only), slice 0
        n0g = 512 + (b & 63) * 32; m0g = (b >> 6) * 128; kbeg = 0; ksf = 0;
    } else if (b < 384) {     // su tiles: 16 n x 4 m x 2 ks over K=1024 ([h,c])
        int i = b - 256;
        n0g = (i & 15) * 32; m0g = ((i >> 4) & 3) * 128;
        ksf = i >> 6; kbeg = ksf * 512;
    }

    if (gact) {
        for (int u = tid; u < 512; u += 256) {
            int r = u >> 4, c = u & 15;
#pragma unroll
            for (int p = 0; p < 4; ++p) {
                *(float4*)&sW[p * 4096 + r * 128 + ((c ^ (r & 15)) * 8)] =
                    *(const float4*)(dWcf + (size_t)(n0g + r) * 1024 + kbeg + p * 128 + c * 8);
            }
        }
    }
    {
        int e = tid * 2;
        sw2[e] = W2[e]; sw2[e + 1] = W2[e + 1];
        s_c[e] = 0.f;  s_c[e + 1] = 0.f;
    }
    __syncthreads();

    const f16* pAg = hdhi + (size_t)(m0g + wid * 32 + rl) * 1024 + kbeg;
    const int gcol = n0g + rl;
    const float gbv = (gact && ksf == 0) ? dbias[gcol] : 0.f;
    f16* gCp = gu + (size_t)ksf * ustride;

    for (int t = 0; t < TM1; ++t) {
        // ===== phase G: gu(t) from hdhi =====
        if (gact) {
            floatx16 acc = {};
            for (int p = 0; p < 4; ++p) {
#pragma unroll
                for (int kk = 0; kk < 128; kk += 16) {
                    int lg = (kk >> 3) + kq;
                    half8 ah = *(const half8*)(pAg + p * 128 + lg * 8);
                    half8 wh = *(const half8*)&sW[p * 4096 + rl * 128 + ((lg ^ (rl & 15)) * 8)];
                    acc = __builtin_amdgcn_mfma_f32_32x32x16_f16(ah, wh, acc, 0, 0, 0);
                }
            }
#pragma unroll
            for (int rr = 0; rr < 16; ++rr) {
                int row = m0g + wid * 32 + (rr & 3) + 8 * (rr >> 2) + 4 * kq;
                gCp[(size_t)row * 2560 + gcol] = (f16)(acc[rr] + gbv);
            }
        }
        __threadfence();
        gridg.sync();
        __threadfence();

        // ===== phase S: dec_step(t) =====
        const bool last = (t == TM1 - 1);
        {
            int e = tid * 2;
            const f16* q = gu + (size_t)b * 2560 + e;
            half2v a0 = *(const half2v*)(q);
            half2v a1 = *(const half2v*)(q + ustride);
            su[e]     = (float)a0[0] + (float)a1[0];
            su[e + 1] = (float)a0[1] + (float)a1[1];
        }
        __syncthreads();
        if (tid < 248) {
            int tp = tid >> 3, l8 = tid & 7;
            const f16* vrow = V + ((size_t)b * TM1 + tp) * 512;
            float p = 0.f;
            for (int j = l8 * 8; j < 512; j += 64) {
                half8 v8 = *(const half8*)(vrow + j);
#pragma unroll
                for (int e = 0; e < 8; e++)
                    p += tanh_fast(su[j + e] + (float)v8[e]) * sw2[j + e];
            }
            p += __shfl_xor(p, 1); p += __shfl_xor(p, 2); p += __shfl_xor(p, 4);
            if (l8 == 0) s_att[tp] = p + b2[0];
        }
        __syncthreads();
        if (tid < 64) {
            float v = (tid < TM1) ? s_att[tid] : -3.4e38f;
            float m = v;
#pragma unroll
            for (int k = 32; k > 0; k >>= 1) m = fmaxf(m, __shfl_xor(m, k));
            float e = (tid < TM1) ? __expf(v - m) : 0.f;
            float s = e;
#pragma unroll
            for (int k = 32; k > 0; k >>= 1) s += __shfl_xor(s, k);
            if (tid < TM1) s_att[tid] = e / s;
        }
        __syncthreads();

        float part, pctx = 0.f;
        {
            int e = tid * 2;
            float cx0 = 0.f, cx1 = 0.f;
            const f16* eh = enchi + (size_t)b * TM1 * 512 + e;
            for (int tp = 0; tp < TM1; tp++) {
                half2v v2 = *(const half2v*)(eh + tp * 512);
                cx0 += s_att[tp] * (float)v2[0];
                cx1 += s_att[tp] * (float)v2[1];
            }
            float2 fw = *(const float2*)(fcW + e);
            part = cx0 * fw.x + cx1 * fw.y;
            if (last) {
                float2 fw2 = *(const float2*)(fcfW + 512 + e);
                pctx = cx0 * fw2.x + cx1 * fw2.y;
            }
        }
        float y = inputs[((size_t)b * TM1 + t) * 257];
        float ysum = blockReduceSum256(part, sred);
        float y_til = ysum + y * fcW[512] + fcb[0];

        float ph = 0.f;
        {
            int e = tid * 2;
            const f16* qq = gu + (size_t)b * 2560 + e;  // gates: slice 0 only
            half2v a = *(const half2v*)(qq + 512);
            half2v f = *(const half2v*)(qq + 1024);
            half2v gv = *(const half2v*)(qq + 1536);
            half2v o = *(const half2v*)(qq + 2048);
            float gi0 = (float)a[0], gi1 = (float)a[1];
            float gf0 = (float)f[0], gf1 = (float)f[1];
            float gg0 = (float)gv[0], gg1 = (float)gv[1];
            float go0 = (float)o[0], go1 = (float)o[1];
            gi0 += y_til * Wih[e];        gi1 += y_til * Wih[e + 1];
            gf0 += y_til * Wih[512 + e];  gf1 += y_til * Wih[512 + e + 1];
            gg0 += y_til * Wih[1024 + e]; gg1 += y_til * Wih[1024 + e + 1];
            go0 += y_til * Wih[1536 + e]; go1 += y_til * Wih[1536 + e + 1];
            float c20 = sigmf(gf0) * s_c[e]     + sigmf(gi0) * tanh_fast(gg0);
            float c21 = sigmf(gf1) * s_c[e + 1] + sigmf(gi1) * tanh_fast(gg1);
            float h20 = sigmf(go0) * tanh_fast(c20);
            float h21 = sigmf(go1) * tanh_fast(c21);
            if (!last) {
                s_c[e] = c20; s_c[e + 1] = c21;
                half2v hv; hv[0] = (f16)h20; hv[1] = (f16)h21;
                half2v cv; cv[0] = (f16)c20; cv[1] = (f16)c21;
                *(half2v*)(hdhi + (size_t)b * 1024 + e) = hv;
                *(half2v*)(hdhi + (size_t)b * 1024 + 512 + e) = cv;
            } else {
                ph += h20 * fcfW[e] + h21 * fcfW[e + 1];
            }
        }
        if (last) {
            float s = blockReduceSum256(ph + pctx, sred);
            if (tid == 0) out[b] = s + fcfb[0];
        }
        if (t < TM1 - 1) {
            __threadfence();
            gridg.sync();
            __threadfence();
        }
    }
}

extern "C" void kernel_launch(void* const* d_in, const int* in_sizes, int n_in,
                              void* d_out, int out_size, void* d_ws, size_t ws_size,
                              hipStream_t stream) {
    const float* inputs  = (const float*)d_in[0];
    const float* eWih    = (const float*)d_in[1];
    const float* eWhh    = (const float*)d_in[2];
    const float* ebih    = (const float*)d_in[3];
    const float* ebhh    = (const float*)d_in[4];
    const float* eWc     = (const float*)d_in[5];
    const float* ebc     = (const float*)d_in[6];
    const float* eWd     = (const float*)d_in[7];
    const float* ebd     = (const float*)d_in[8];
    const float* eWa     = (const float*)d_in[9];
    const float* eba     = (const float*)d_in[10];
    const float* dW1     = (const float*)d_in[11];
    const float* db1     = (const float*)d_in[12];
    const float* dW2     = (const float*)d_in[13];
    const float* db2     = (const float*)d_in[14];
    const float* dWih    = (const float*)d_in[15];
    const float* dWhh    = (const float*)d_in[16];
    const float* dbih    = (const float*)d_in[17];
    const float* dbhh    = (const float*)d_in[18];
    const float* fcW     = (const float*)d_in[19];
    const float* fcb     = (const float*)d_in[20];
    const float* fcfW    = (const float*)d_in[21];
    const float* fcfb    = (const float*)d_in[22];
    float* out = (float*)d_out;

    float* scr = (float*)d_ws;
    f16* t2s = (f16*)scr;                       // 4,063,232 h
    f16* Vf  = (f16*)scr;                       // 8,126,464 h
    f16* g0e = (f16*)(scr + 4063232);           // 2 x 1,048,576 h
    f16* gu0 = (f16*)(scr + 4063232);           // 2 x 1,310,720 h
    float* hc_enc = scr + 6684672;              //   524,288 f
    f16*   Ahi    = (f16*)(scr + 7208960);      //   393,216 h
    float* hc_dec = scr + 7405568;              //   524,288 f
    f16*   hdhi   = (f16*)(scr + 7929856);      //   524,288 h
    f16* fp = (f16*)(scr + 8192000);
    f16* eWf   = fp;             fp += 1572864;
    f16* dWcf  = fp;             fp += 2621440;
    f16* Vwf   = fp;             fp += 262144;
    f16* enchi = fp;             fp += 8126464;
    float* ebcomb = (float*)(((uintptr_t)fp + 15) & ~(uintptr_t)15);
    float* dbias  = ebcomb + 2048;              // 2560 f
    f16* Wcf = (f16*)(dbias + 2560);            // 31,744 h

    hipLaunchKernelGGL(prep_t2s_kernel, dim3(2048), dim3(256), 0, stream,
                       inputs, eWih, eWhh, ebih, ebhh, dW1, dWhh, dbih, dbhh,
                       eWd, ebd, eWc, eWf, dWcf, Vwf,
                       ebcomb, dbias, t2s, Wcf);

    long long gstride = 1048576;   // halves per g slice
    long long ustride = 1310720;   // halves per gu slice

    // -------- encoder: cooperative; fall back to per-step on launch error --
    bool enc_ok = false;
    {
        void* a[] = {(void*)&inputs, (void*)&t2s, (void*)&Wcf, (void*)&ebc,
                     (void*)&eWa, (void*)&eba, (void*)&g0e, (void*)&gstride,
                     (void*)&Ahi, (void*)&enchi, (void*)&hc_dec, (void*)&hdhi,
                     (void*)&eWf, (void*)&ebcomb};
        enc_ok = (hipLaunchCooperativeKernel((const void*)enc_coop, dim3(512),
                                             dim3(256), a, 0, stream) == hipSuccess);
    }
    if (!enc_ok) {
        for (int t = 0; t < TM1; t++) {
            hipLaunchKernelGGL(enc_step_kernel, dim3(BATCH), dim3(256), 0, stream,
                               inputs, t2s, Wcf, ebc, eWa, eba, g0e, gstride, hc_enc,
                               Ahi, enchi, hc_dec, hdhi, t);
            hipLaunchKernelGGL(gemm1f, dim3(512), dim3(256), 0, stream,
                               Ahi, 768, eWf, 768, ebcomb,
                               g0e, 2048, gstride, 768, 1 << 30, 32, 8, 2);
        }
        hipLaunchKernelGGL(enc_step_kernel, dim3(BATCH), dim3(256), 0, stream,
                           inputs, t2s, Wcf, ebc, eWa, eba, g0e, gstride, hc_enc,
                           Ahi, enchi, hc_dec, hdhi, TM1);
    }

    // -------- V = enc_out @ dec_W1[:,1024:]^T + b1 (f16 out) --------
    hipLaunchKernelGGL(gemm_v, dim3(992), dim3(256), 0, stream,
                       enchi, 512, Vwf, 512, db1,
                       Vf, 512, 512, 4, 248, 2);

    // -------- decoder: cooperative; fall back to per-step on launch error --
    bool dec_ok = false;
    {
        void* a[] = {(void*)&inputs, (void*)&Vf, (void*)&dW2, (void*)&db2,
                     (void*)&enchi, (void*)&fcW, (void*)&fcb, (void*)&dWih,
                     (void*)&gu0, (void*)&ustride, (void*)&hdhi,
                     (void*)&fcfW, (void*)&fcfb, (void*)&out,
                     (void*)&dWcf, (void*)&dbias};
        dec_ok = (hipLaunchCooperativeKernel((const void*)dec_coop, dim3(512),
                                             dim3(256), a, 0, stream) == hipSuccess);
    }
    if (!dec_ok) {
        for (int t = 0; t < TM1; t++) {
            hipLaunchKernelGGL(gemm1f, dim3(640), dim3(256), 0, stream,
                               hdhi, 1024, dWcf, 1024, dbias,
                               gu0, 2560, ustride, 1024, 512, 40, 8, 2);
            hipLaunchKernelGGL(dec_step_kernel, dim3(BATCH), dim3(256), 0, stream,
                               inputs, Vf, dW2, db2, enchi, fcW, fcb, dWih,
                               gu0, ustride, hc_dec, hdhi, fcfW, fcfb, out, t);
        }
    }
}

// Round 3
// 4812.373 us; speedup vs baseline: 3.6619x; 3.6619x over previous
//
#include <hip/hip_runtime.h>
#include <math.h>

#define BATCH 512
#define TM1   31
#define DIMD  256

typedef _Float16 f16;
typedef _Float16 half2v __attribute__((ext_vector_type(2)));
typedef _Float16 half8 __attribute__((ext_vector_type(8)));
typedef float floatx16 __attribute__((ext_vector_type(16)));

__device__ __forceinline__ float sigmf(float x) { return 1.f / (1.f + __expf(-x)); }

__device__ __forceinline__ float tanh_fast(float x) {
    float ax = fabsf(x);
    float t  = __expf(-2.f * ax);
    float r  = (1.f - t) / (1.f + t);
    return copysignf(r, x);
}

__device__ __forceinline__ float blockReduceSum256(float v, float* sred) {
#pragma unroll
    for (int m = 32; m > 0; m >>= 1) v += __shfl_xor(v, m);
    __syncthreads();
    if ((threadIdx.x & 63) == 0) sred[threadIdx.x >> 6] = v;
    __syncthreads();
    return sred[0] + sred[1] + sred[2] + sred[3];
}

__device__ __forceinline__ float blockReduceMax256(float v, float* sred) {
#pragma unroll
    for (int m = 32; m > 0; m >>= 1) v = fmaxf(v, __shfl_xor(v, m));
    __syncthreads();
    if ((threadIdx.x & 63) == 0) sred[threadIdx.x >> 6] = v;
    __syncthreads();
    return fmaxf(fmaxf(sred[0], sred[1]), fmaxf(sred[2], sred[3]));
}

// ---------------------------------------------------------------------------
// Fence-minimal grid barrier. Per-step slot (no generation reuse). Only tid0
// of each block performs release-add / spin / acquire-load; other waves wait
// at s_barrier. 8 spread counters (64B apart) avoid a hot-line convoy.
// ---------------------------------------------------------------------------
__device__ __forceinline__ void gbar(unsigned* flags, int slot, int bid) {
    __syncthreads();   // drains this block's outstanding stores (vmcnt) first
    if (threadIdx.x == 0) {
        unsigned* base = flags + slot * 128;
        __hip_atomic_fetch_add(base + (bid & 7) * 16, 1u,
                               __ATOMIC_RELEASE, __HIP_MEMORY_SCOPE_AGENT);
        for (;;) {
            unsigned s = 0;
#pragma unroll
            for (int j = 0; j < 8; j++)
                s += __hip_atomic_load(base + j * 16,
                                       __ATOMIC_RELAXED, __HIP_MEMORY_SCOPE_AGENT);
            if (s >= 512u) break;
            __builtin_amdgcn_s_sleep(8);
        }
        (void)__hip_atomic_load(base, __ATOMIC_ACQUIRE, __HIP_MEMORY_SCOPE_AGENT);
    }
    __syncthreads();
    __builtin_amdgcn_sched_barrier(0);
}

// ---------------------------------------------------------------------------
// prep + t2s fused (+ barrier-flag zeroing).
// ---------------------------------------------------------------------------
__global__ __launch_bounds__(256) void prep_t2s_kernel(
    const float* __restrict__ inputs,
    const float* __restrict__ eWih, const float* __restrict__ eWhh,
    const float* __restrict__ ebih, const float* __restrict__ ebhh,
    const float* __restrict__ dW1,  const float* __restrict__ dWhh,
    const float* __restrict__ dbih, const float* __restrict__ dbhh,
    const float* __restrict__ Wd,   const float* __restrict__ bd,
    const float* __restrict__ Wc,
    f16* __restrict__ eWf, f16* __restrict__ dWcf, f16* __restrict__ Vwf,
    float* __restrict__ ebcomb, float* __restrict__ dbias,
    f16* __restrict__ t2s, f16* __restrict__ Wcf,
    unsigned* __restrict__ flags)
{
    __shared__ float sX[TM1 * DIMD];
    __shared__ float sWd[TM1 * TM1];
    int b = blockIdx.x, tid = threadIdx.x;
    int idx = b * 256 + tid;
    const int stride = gridDim.x * 256;

    if (b < 512) {
        for (int i = tid; i < TM1 * DIMD; i += 256) {
            int tt = i >> 8, d = i & 255;
            sX[i] = inputs[((size_t)b * TM1 + tt) * 257 + 1 + d];
        }
        for (int i = tid; i < TM1 * TM1; i += 256) sWd[i] = Wd[i];
        __syncthreads();
        int d = tid;
        for (int s = 0; s < TM1; s++) {
            float acc = bd[s];
            for (int tt = 0; tt < TM1; tt++) acc += sX[tt * DIMD + d] * sWd[s * TM1 + tt];
            t2s[((size_t)b * TM1 + s) * DIMD + d] = (f16)acc;
        }
    }

    for (int g = idx; g < 2048 * 96; g += stride) {
        int n = g / 96, k0 = (g % 96) * 8;
        const float* src = (k0 < 256) ? (eWih + n * 256 + k0)
                                      : (eWhh + n * 512 + (k0 - 256));
        float4 v0 = *(const float4*)src;
        float4 v1 = *(const float4*)(src + 4);
        f16 h[8] = {(f16)v0.x, (f16)v0.y, (f16)v0.z, (f16)v0.w,
                    (f16)v1.x, (f16)v1.y, (f16)v1.z, (f16)v1.w};
        *(half8*)(eWf + n * 768 + k0) = *(half8*)h;
    }
    for (int g = idx; g < 2560 * 128; g += stride) {
        int n = g >> 7, k0 = (g & 127) * 8;
        float vv[8] = {};
        if (n < 512) {
            const float* src = dW1 + n * 1536 + k0;
            float4 v0 = *(const float4*)src, v1 = *(const float4*)(src + 4);
            vv[0]=v0.x; vv[1]=v0.y; vv[2]=v0.z; vv[3]=v0.w;
            vv[4]=v1.x; vv[5]=v1.y; vv[6]=v1.z; vv[7]=v1.w;
        } else if (k0 < 512) {
            const float* src = dWhh + (n - 512) * 512 + k0;
            float4 v0 = *(const float4*)src, v1 = *(const float4*)(src + 4);
            vv[0]=v0.x; vv[1]=v0.y; vv[2]=v0.z; vv[3]=v0.w;
            vv[4]=v1.x; vv[5]=v1.y; vv[6]=v1.z; vv[7]=v1.w;
        }
        f16 h[8];
#pragma unroll
        for (int e = 0; e < 8; e++) h[e] = (f16)vv[e];
        *(half8*)(dWcf + n * 1024 + k0) = *(half8*)h;
    }
    for (int g = idx; g < 512 * 64; g += stride) {
        int n = g >> 6, k0 = (g & 63) * 8;
        const float* src = dW1 + n * 1536 + 1024 + k0;
        float4 v0 = *(const float4*)src, v1 = *(const float4*)(src + 4);
        f16 h[8] = {(f16)v0.x, (f16)v0.y, (f16)v0.z, (f16)v0.w,
                    (f16)v1.x, (f16)v1.y, (f16)v1.z, (f16)v1.w};
        *(half8*)(Vwf + n * 512 + k0) = *(half8*)h;
    }
    for (int g = idx; g < 3968; g += stride) {
        int k0 = g * 8;
        float4 v0 = *(const float4*)(Wc + k0);
        float4 v1 = *(const float4*)(Wc + k0 + 4);
        f16 h[8] = {(f16)v0.x, (f16)v0.y, (f16)v0.z, (f16)v0.w,
                    (f16)v1.x, (f16)v1.y, (f16)v1.z, (f16)v1.w};
        *(half8*)(Wcf + k0) = *(half8*)h;
    }
    for (int i = idx; i < 2048; i += stride) ebcomb[i] = ebih[i] + ebhh[i];
    for (int i = idx; i < 2560; i += stride)
        dbias[i] = (i < 512) ? 0.f : (dbih[i - 512] + dbhh[i - 512]);
    for (int i = idx; i < 128 * 128; i += stride) flags[i] = 0u;
}

// ---------------------------------------------------------------------------
// FALLBACK: step GEMM (R14-validated).
// ---------------------------------------------------------------------------
__global__ __launch_bounds__(256) void gemm1f(
    const f16* __restrict__ A, int lda,
    const f16* __restrict__ W, int ldw,
    const float* __restrict__ bias, f16* __restrict__ C, int ldc,
    long long Cstride, int K, int nsplit, int NT, int MT, int KS)
{
    __shared__ f16 sAh[64 * 128];
    __shared__ f16 sWh[64 * 128];
    int tid = threadIdx.x, bid = blockIdx.x;
    int nbase = bid % NT;
    int m0 = ((bid / NT) % MT) * 64;
    int ks = bid / (NT * MT);
    int lane = tid & 63, wid = tid >> 6;
    int wm = wid >> 1, wn = wid & 1;
    int rl = lane & 31, kq = lane >> 5;

    int sr = tid >> 2;
    int gb = (tid & 3) * 4;
    int st0 = sr * 128 + (((gb + 0) ^ (sr & 15)) * 8);
    int st1 = sr * 128 + (((gb + 1) ^ (sr & 15)) * 8);
    int st2 = sr * 128 + (((gb + 2) ^ (sr & 15)) * 8);
    int st3 = sr * 128 + (((gb + 3) ^ (sr & 15)) * 8);
    int arow = (wm * 32 + rl) * 128;
    int wrow = (wn * 32 + rl) * 128;
    int swk = rl & 15;

    int n0 = nbase * 64;
    int Kfull = (n0 >= nsplit) ? 512 : K;
    int ksz = Kfull / KS;
    int kbeg = ks * ksz, kend = kbeg + ksz;

    const f16* pA = A + (size_t)(m0 + sr) * lda + gb * 8;
    const f16* pW = W + (size_t)(n0 + sr) * ldw + gb * 8;

    float4 rA0 = *(const float4*)(pA + kbeg);
    float4 rA1 = *(const float4*)(pA + kbeg + 8);
    float4 rA2 = *(const float4*)(pA + kbeg + 16);
    float4 rA3 = *(const float4*)(pA + kbeg + 24);
    float4 rW0 = *(const float4*)(pW + kbeg);
    float4 rW1 = *(const float4*)(pW + kbeg + 8);
    float4 rW2 = *(const float4*)(pW + kbeg + 16);
    float4 rW3 = *(const float4*)(pW + kbeg + 24);

    floatx16 acc = {};
    for (int k0 = kbeg; k0 < kend; k0 += 128) {
        __syncthreads();
        *(float4*)&sAh[st0] = rA0; *(float4*)&sAh[st1] = rA1;
        *(float4*)&sAh[st2] = rA2; *(float4*)&sAh[st3] = rA3;
        *(float4*)&sWh[st0] = rW0; *(float4*)&sWh[st1] = rW1;
        *(float4*)&sWh[st2] = rW2; *(float4*)&sWh[st3] = rW3;
        __syncthreads();
        int kn = k0 + 128;
        if (kn < kend) {
            rA0 = *(const float4*)(pA + kn);      rA1 = *(const float4*)(pA + kn + 8);
            rA2 = *(const float4*)(pA + kn + 16); rA3 = *(const float4*)(pA + kn + 24);
            rW0 = *(const float4*)(pW + kn);      rW1 = *(const float4*)(pW + kn + 8);
            rW2 = *(const float4*)(pW + kn + 16); rW3 = *(const float4*)(pW + kn + 24);
        }
#pragma unroll
        for (int kk = 0; kk < 128; kk += 16) {
            int lg = (kk >> 3) + kq;
            half8 ah = *(const half8*)&sAh[arow + ((lg ^ swk) * 8)];
            half8 wh = *(const half8*)&sWh[wrow + ((lg ^ swk) * 8)];
            acc = __builtin_amdgcn_mfma_f32_32x32x16_f16(ah, wh, acc, 0, 0, 0);
        }
    }

    int col = n0 + wn * 32 + rl;
    float bv = (ks == 0) ? bias[col] : 0.f;
    f16* Cp = C + (size_t)ks * Cstride;
#pragma unroll
    for (int rr = 0; rr < 16; ++rr) {
        int row = m0 + wm * 32 + (rr & 3) + 8 * (rr >> 2) + 4 * kq;
        Cp[(size_t)row * ldc + col] = (f16)(acc[rr] + bv);
    }
}

// ---------------------------------------------------------------------------
// FALLBACK: encoder step (R14-validated).
// ---------------------------------------------------------------------------
__global__ __launch_bounds__(256) void enc_step_kernel(
    const float* __restrict__ inputs, const f16* __restrict__ t2s,
    const f16* __restrict__ Wcf, const float* __restrict__ bc,
    const float* __restrict__ Wa, const float* __restrict__ ba,
    const f16* __restrict__ g, long long gstride,
    float* __restrict__ hc,
    f16* __restrict__ Ahi, f16* __restrict__ enchi,
    float* __restrict__ hc_dec, f16* __restrict__ hdhi,
    int t) {
    __shared__ float sh_hc[1024];
    __shared__ float t1s[32];
    __shared__ float sred[4];
    int b = blockIdx.x, tid = threadIdx.x;

    if (t > 0) {
        int e = tid * 2;
        const f16* gp = g + (size_t)b * 2048 + e;
        float gi0 = 0.f, gi1 = 0.f, gf0 = 0.f, gf1 = 0.f;
        float gg0 = 0.f, gg1 = 0.f, go0 = 0.f, go1 = 0.f;
#pragma unroll
        for (int s = 0; s < 2; s++) {
            const f16* q = gp + s * gstride;
            half2v a = *(const half2v*)(q);
            half2v f = *(const half2v*)(q + 512);
            half2v gv = *(const half2v*)(q + 1024);
            half2v o = *(const half2v*)(q + 1536);
            gi0 += (float)a[0]; gi1 += (float)a[1];
            gf0 += (float)f[0]; gf1 += (float)f[1];
            gg0 += (float)gv[0]; gg1 += (float)gv[1];
            go0 += (float)o[0]; go1 += (float)o[1];
        }
        float2 cpv = *(const float2*)(hc + b * 1024 + 512 + e);
        float c20 = sigmf(gf0) * cpv.x + sigmf(gi0) * tanh_fast(gg0);
        float c21 = sigmf(gf1) * cpv.y + sigmf(gi1) * tanh_fast(gg1);
        float h20 = sigmf(go0) * tanh_fast(c20);
        float h21 = sigmf(go1) * tanh_fast(c21);
        *(float2*)(hc + b * 1024 + 512 + e) = make_float2(c20, c21);
        sh_hc[e] = h20; sh_hc[e + 1] = h21;
        sh_hc[512 + e] = c20; sh_hc[512 + e + 1] = c21;
        half2v hv; hv[0] = (f16)h20; hv[1] = (f16)h21;
        *(half2v*)(enchi + ((size_t)b * TM1 + (t - 1)) * 512 + e) = hv;
    } else {
        for (int j = tid; j < 1024; j += 256) { sh_hc[j] = 0.f; }
        for (int j = tid; j < 512; j += 256) hc[b * 1024 + 512 + j] = 0.f;
    }
    if (t == TM1) {
        for (int j = tid; j < 512; j += 256) hc_dec[b * 1024 + 512 + j] = 0.f;
        for (int j = tid; j < 1024; j += 256) hdhi[b * 1024 + j] = (f16)0.f;
        return;
    }
    __syncthreads();

    if (tid < 248) {
        int s = tid >> 3, l8 = tid & 7;
        const f16* wrow = Wcf + s * 1024;
        float p = 0.f;
        for (int j = l8 * 8; j < 1024; j += 64) {
            half8 w8 = *(const half8*)(wrow + j);
#pragma unroll
            for (int e = 0; e < 8; e++) p += (float)w8[e] * sh_hc[j + e];
        }
        p += __shfl_xor(p, 1); p += __shfl_xor(p, 2); p += __shfl_xor(p, 4);
        if (l8 == 0) t1s[s] = p + bc[s];
    }
    __syncthreads();

    int d = tid;
    float sc = ba[0];
    const f16* t2p = t2s + ((size_t)b * TM1) * DIMD + d;
    for (int s = 0; s < TM1; s++) sc += tanh_fast(t1s[s] + (float)t2p[s * DIMD]) * Wa[s];
    float mx = blockReduceMax256(sc, sred);
    float ex = __expf(sc - mx);
    float sm = blockReduceSum256(ex, sred);
    float w = (ex / sm) * inputs[((size_t)b * TM1 + t) * 257 + 1 + d];
    Ahi[b * 768 + d] = (f16)w;
    {
        int j = tid * 2;
        half2v hv; hv[0] = (f16)sh_hc[j]; hv[1] = (f16)sh_hc[j + 1];
        *(half2v*)(Ahi + b * 768 + 256 + j) = hv;
    }
}

// ---------------------------------------------------------------------------
// FALLBACK: decoder step (R14-validated).
// ---------------------------------------------------------------------------
__global__ __launch_bounds__(256) void dec_step_kernel(
    const float* __restrict__ inputs, const f16* __restrict__ V,
    const float* __restrict__ W2, const float* __restrict__ b2,
    const f16* __restrict__ enchi,
    const float* __restrict__ fcW, const float* __restrict__ fcb,
    const float* __restrict__ Wih,
    const f16* __restrict__ gu, long long ustride,
    float* __restrict__ hc, f16* __restrict__ hdhi,
    const float* __restrict__ fcfW, const float* __restrict__ fcfb,
    float* __restrict__ out, int t) {
    __shared__ float su[512];
    __shared__ float sw2[512];
    __shared__ float s_att[TM1];
    __shared__ float sred[4];
    int b = blockIdx.x, tid = threadIdx.x;
    const bool last = (t == TM1 - 1);
    {
        int e = tid * 2;
        const f16* q = gu + (size_t)b * 2560 + e;
        half2v a0 = *(const half2v*)(q);
        half2v a1 = *(const half2v*)(q + ustride);
        su[e]     = (float)a0[0] + (float)a1[0];
        su[e + 1] = (float)a0[1] + (float)a1[1];
        sw2[e] = W2[e]; sw2[e + 1] = W2[e + 1];
    }
    __syncthreads();
    if (tid < 248) {
        int tp = tid >> 3, l8 = tid & 7;
        const f16* vrow = V + ((size_t)b * TM1 + tp) * 512;
        float p = 0.f;
        for (int j = l8 * 8; j < 512; j += 64) {
            half8 v8 = *(const half8*)(vrow + j);
#pragma unroll
            for (int e = 0; e < 8; e++)
                p += tanh_fast(su[j + e] + (float)v8[e]) * sw2[j + e];
        }
        p += __shfl_xor(p, 1); p += __shfl_xor(p, 2); p += __shfl_xor(p, 4);
        if (l8 == 0) s_att[tp] = p + b2[0];
    }
    __syncthreads();
    if (tid < 64) {
        float v = (tid < TM1) ? s_att[tid] : -3.4e38f;
        float m = v;
#pragma unroll
        for (int k = 32; k > 0; k >>= 1) m = fmaxf(m, __shfl_xor(m, k));
        float e = (tid < TM1) ? __expf(v - m) : 0.f;
        float s = e;
#pragma unroll
        for (int k = 32; k > 0; k >>= 1) s += __shfl_xor(s, k);
        if (tid < TM1) s_att[tid] = e / s;
    }
    __syncthreads();

    float part, pctx = 0.f;
    {
        int e = tid * 2;
        float cx0 = 0.f, cx1 = 0.f;
        const f16* eh = enchi + (size_t)b * TM1 * 512 + e;
        for (int tp = 0; tp < TM1; tp++) {
            half2v v2 = *(const half2v*)(eh + tp * 512);
            cx0 += s_att[tp] * (float)v2[0];
            cx1 += s_att[tp] * (float)v2[1];
        }
        float2 fw = *(const float2*)(fcW + e);
        part = cx0 * fw.x + cx1 * fw.y;
        if (last) {
            float2 fw2 = *(const float2*)(fcfW + 512 + e);
            pctx = cx0 * fw2.x + cx1 * fw2.y;
        }
    }
    float y = inputs[((size_t)b * TM1 + t) * 257];
    float ysum = blockReduceSum256(part, sred);
    float y_til = ysum + y * fcW[512] + fcb[0];

    float ph = 0.f;
    {
        int e = tid * 2;
        const f16* q = gu + (size_t)b * 2560 + e;
        float gi0 = 0.f, gi1 = 0.f, gf0 = 0.f, gf1 = 0.f;
        float gg0 = 0.f, gg1 = 0.f, go0 = 0.f, go1 = 0.f;
#pragma unroll
        for (int s = 0; s < 2; s++) {
            const f16* qq = q + s * ustride;
            half2v a = *(const half2v*)(qq + 512);
            half2v f = *(const half2v*)(qq + 1024);
            half2v gv = *(const half2v*)(qq + 1536);
            half2v o = *(const half2v*)(qq + 2048);
            gi0 += (float)a[0]; gi1 += (float)a[1];
            gf0 += (float)f[0]; gf1 += (float)f[1];
            gg0 += (float)gv[0]; gg1 += (float)gv[1];
            go0 += (float)o[0]; go1 += (float)o[1];
        }
        gi0 += y_til * Wih[e];        gi1 += y_til * Wih[e + 1];
        gf0 += y_til * Wih[512 + e];  gf1 += y_til * Wih[512 + e + 1];
        gg0 += y_til * Wih[1024 + e]; gg1 += y_til * Wih[1024 + e + 1];
        go0 += y_til * Wih[1536 + e]; go1 += y_til * Wih[1536 + e + 1];
        float2 cpv = *(const float2*)(hc + b * 1024 + 512 + e);
        float c20 = sigmf(gf0) * cpv.x + sigmf(gi0) * tanh_fast(gg0);
        float c21 = sigmf(gf1) * cpv.y + sigmf(gi1) * tanh_fast(gg1);
        float h20 = sigmf(go0) * tanh_fast(c20);
        float h21 = sigmf(go1) * tanh_fast(c21);
        if (!last) {
            *(float2*)(hc + b * 1024 + 512 + e) = make_float2(c20, c21);
            half2v hv; hv[0] = (f16)h20; hv[1] = (f16)h21;
            half2v cv; cv[0] = (f16)c20; cv[1] = (f16)c21;
            *(half2v*)(hdhi + (size_t)b * 1024 + e) = hv;
            *(half2v*)(hdhi + (size_t)b * 1024 + 512 + e) = cv;
        } else {
            ph += h20 * fcfW[e] + h21 * fcfW[e + 1];
        }
    }
    if (last) {
        float s = blockReduceSum256(ph + pctx, sred);
        if (tid == 0) out[b] = s + fcfb[0];
    }
}

// ---------------------------------------------------------------------------
// COOP: encoder persistent kernel with fence-minimal custom barriers.
// ---------------------------------------------------------------------------
__global__ __launch_bounds__(256, 2) void enc_coop(
    const float* __restrict__ inputs, const f16* __restrict__ t2s,
    const f16* __restrict__ Wcf, const float* __restrict__ bc,
    const float* __restrict__ Wa, const float* __restrict__ ba,
    f16* __restrict__ g, long long gstride,
    f16* __restrict__ Ahi, f16* __restrict__ enchi,
    float* __restrict__ hc_dec, f16* __restrict__ hdhi,
    const f16* __restrict__ eWf, const float* __restrict__ ebcomb,
    unsigned* __restrict__ flags)
{
    __shared__ f16 sWh[3 * 8192];      // resident W tile: 64 cols x 384 K (48 KB)
    __shared__ float sh_hc[1024];      // persistent h|c for batch b
    __shared__ float t1s[32];
    __shared__ float sred[4];
    const int b = blockIdx.x, tid = threadIdx.x;

    const int lane = tid & 63, wid = tid >> 6;
    const int wm = wid >> 1, wn = wid & 1;
    const int rl = lane & 31, kq = lane >> 5;
    const int sr = tid >> 2;
    const int gb = (tid & 3) * 4;
    const int st0 = sr * 128 + (((gb + 0) ^ (sr & 15)) * 8);
    const int st1 = sr * 128 + (((gb + 1) ^ (sr & 15)) * 8);
    const int st2 = sr * 128 + (((gb + 2) ^ (sr & 15)) * 8);
    const int st3 = sr * 128 + (((gb + 3) ^ (sr & 15)) * 8);
    const int n0g = (b & 31) * 64;
    const int m0g = ((b >> 5) & 7) * 64;
    const int ksg = b >> 8;
    const int kbeg = ksg * 384;
    const int wrow = (wn * 32 + rl) * 128;
    const int swk = rl & 15;
    const f16* pW  = eWf + (size_t)(n0g + sr) * 768 + gb * 8;
    const f16* pAg = Ahi + (size_t)(m0g + wm * 32 + rl) * 768 + kbeg;
    const int gcol = n0g + wn * 32 + rl;
    const float gbv = (ksg == 0) ? ebcomb[gcol] : 0.f;
    f16* gCp = g + (size_t)ksg * gstride;

    // one-time resident W preload
#pragma unroll
    for (int p = 0; p < 3; ++p) {
        *(float4*)&sWh[p * 8192 + st0] = *(const float4*)(pW + kbeg + p * 128);
        *(float4*)&sWh[p * 8192 + st1] = *(const float4*)(pW + kbeg + p * 128 + 8);
        *(float4*)&sWh[p * 8192 + st2] = *(const float4*)(pW + kbeg + p * 128 + 16);
        *(float4*)&sWh[p * 8192 + st3] = *(const float4*)(pW + kbeg + p * 128 + 24);
    }
    __syncthreads();

    for (int t = 0; t <= TM1; ++t) {
        // ===== phase A: finalize LSTM(t-1) + attention(t) =====
        if (t > 0) {
            int e = tid * 2;
            const f16* gp = g + (size_t)b * 2048 + e;
            float gi0 = 0.f, gi1 = 0.f, gf0 = 0.f, gf1 = 0.f;
            float gg0 = 0.f, gg1 = 0.f, go0 = 0.f, go1 = 0.f;
#pragma unroll
            for (int s = 0; s < 2; s++) {
                const f16* q = gp + s * gstride;
                half2v a = *(const half2v*)(q);
                half2v f = *(const half2v*)(q + 512);
                half2v gv = *(const half2v*)(q + 1024);
                half2v o = *(const half2v*)(q + 1536);
                gi0 += (float)a[0]; gi1 += (float)a[1];
                gf0 += (float)f[0]; gf1 += (float)f[1];
                gg0 += (float)gv[0]; gg1 += (float)gv[1];
                go0 += (float)o[0]; go1 += (float)o[1];
            }
            float c0 = sh_hc[512 + e], c1 = sh_hc[513 + e];
            float c20 = sigmf(gf0) * c0 + sigmf(gi0) * tanh_fast(gg0);
            float c21 = sigmf(gf1) * c1 + sigmf(gi1) * tanh_fast(gg1);
            float h20 = sigmf(go0) * tanh_fast(c20);
            float h21 = sigmf(go1) * tanh_fast(c21);
            sh_hc[e] = h20; sh_hc[e + 1] = h21;
            sh_hc[512 + e] = c20; sh_hc[513 + e] = c21;
            half2v hv; hv[0] = (f16)h20; hv[1] = (f16)h21;
            *(half2v*)(enchi + ((size_t)b * TM1 + (t - 1)) * 512 + e) = hv;
        } else {
            for (int j = tid; j < 1024; j += 256) sh_hc[j] = 0.f;
        }
        if (t == TM1) {
            for (int j = tid; j < 512; j += 256) hc_dec[b * 1024 + 512 + j] = 0.f;
            for (int j = tid; j < 1024; j += 256) hdhi[(size_t)b * 1024 + j] = (f16)0.f;
            break;
        }
        __syncthreads();

        if (tid < 248) {
            int s = tid >> 3, l8 = tid & 7;
            const f16* wr = Wcf + s * 1024;
            float p = 0.f;
            for (int j = l8 * 8; j < 1024; j += 64) {
                half8 w8 = *(const half8*)(wr + j);
#pragma unroll
                for (int e2 = 0; e2 < 8; e2++) p += (float)w8[e2] * sh_hc[j + e2];
            }
            p += __shfl_xor(p, 1); p += __shfl_xor(p, 2); p += __shfl_xor(p, 4);
            if (l8 == 0) t1s[s] = p + bc[s];
        }
        __syncthreads();
        {
            int d = tid;
            float sc = ba[0];
            const f16* t2p = t2s + ((size_t)b * TM1) * DIMD + d;
            for (int s = 0; s < TM1; s++) sc += tanh_fast(t1s[s] + (float)t2p[s * DIMD]) * Wa[s];
            float mx = blockReduceMax256(sc, sred);
            float ex = __expf(sc - mx);
            float sm = blockReduceSum256(ex, sred);
            float w = (ex / sm) * inputs[((size_t)b * TM1 + t) * 257 + 1 + d];
            Ahi[b * 768 + d] = (f16)w;
            int j = tid * 2;
            half2v hv; hv[0] = (f16)sh_hc[j]; hv[1] = (f16)sh_hc[j + 1];
            *(half2v*)(Ahi + b * 768 + 256 + j) = hv;
        }
        gbar(flags, 2 * t, b);

        // ===== phase G: g(t) = Ahi @ W^T (tile) =====
        {
            floatx16 acc = {};
            for (int p = 0; p < 3; ++p) {
#pragma unroll
                for (int kk = 0; kk < 128; kk += 16) {
                    int lg = (kk >> 3) + kq;
                    half8 ah = *(const half8*)(pAg + p * 128 + lg * 8);
                    half8 wh = *(const half8*)&sWh[p * 8192 + wrow + ((lg ^ swk) * 8)];
                    acc = __builtin_amdgcn_mfma_f32_32x32x16_f16(ah, wh, acc, 0, 0, 0);
                }
            }
#pragma unroll
            for (int rr = 0; rr < 16; ++rr) {
                int row = m0g + wm * 32 + (rr & 3) + 8 * (rr >> 2) + 4 * kq;
                gCp[(size_t)row * 2048 + gcol] = (f16)(acc[rr] + gbv);
            }
        }
        gbar(flags, 2 * t + 1, b);
    }
}

// ---------------------------------------------------------------------------
// V GEMM (unchanged).
// ---------------------------------------------------------------------------
__global__ __launch_bounds__(256) void gemm_v(
    const f16* __restrict__ A, int lda,
    const f16* __restrict__ W, int ldw,
    const float* __restrict__ bias, f16* __restrict__ C, int ldc,
    int K, int NT, int MT, int NREP)
{
    __shared__ f16 sAh[64 * 64];
    __shared__ f16 sWh[64 * 64];
    int tid = threadIdx.x, bid = blockIdx.x;
    int nbase = bid % NT;
    int m0 = ((bid / NT) % MT) * 64;
    int lane = tid & 63, wid = tid >> 6;
    int wm = wid >> 1, wn = wid & 1;
    int rl = lane & 31, kq = lane >> 5;
    int sr = tid >> 2;
    int g0 = (tid & 3) * 2;
    int s0 = sr * 64 + ((g0 ^ (sr & 7)) * 8);
    int s1 = sr * 64 + (((g0 + 1) ^ (sr & 7)) * 8);
    int arow = (wm * 32 + rl) * 64;
    int wrow = (wn * 32 + rl) * 64;
    int sw = (rl & 7);

    const f16* pA = A + (size_t)(m0 + sr) * lda + g0 * 8;

    for (int r = 0; r < NREP; ++r) {
        int n0 = (nbase + r * NT) * 64;
        const f16* pW = W + (size_t)(n0 + sr) * ldw + g0 * 8;
        float4 rA0 = *(const float4*)(pA);
        float4 rA1 = *(const float4*)(pA + 8);
        float4 rW0 = *(const float4*)(pW);
        float4 rW1 = *(const float4*)(pW + 8);
        floatx16 acc = {};
        for (int k0 = 0; k0 < K; k0 += 64) {
            __syncthreads();
            *(float4*)&sAh[s0] = rA0; *(float4*)&sAh[s1] = rA1;
            *(float4*)&sWh[s0] = rW0; *(float4*)&sWh[s1] = rW1;
            __syncthreads();
            int kn = k0 + 64;
            if (kn < K) {
                rA0 = *(const float4*)(pA + kn); rA1 = *(const float4*)(pA + kn + 8);
                rW0 = *(const float4*)(pW + kn); rW1 = *(const float4*)(pW + kn + 8);
            }
#pragma unroll
            for (int kk = 0; kk < 64; kk += 16) {
                int lg = (kk >> 3) + kq;
                int off = ((lg ^ sw) * 8);
                half8 ah = *(const half8*)&sAh[arow + off];
                half8 wh = *(const half8*)&sWh[wrow + off];
                acc = __builtin_amdgcn_mfma_f32_32x32x16_f16(ah, wh, acc, 0, 0, 0);
            }
        }
        int col = n0 + wn * 32 + rl;
        float bv = bias[col];
#pragma unroll
        for (int rr = 0; rr < 16; ++rr) {
            int row = m0 + wm * 32 + (rr & 3) + 8 * (rr >> 2) + 4 * kq;
            C[(size_t)row * ldc + col] = (f16)(acc[rr] + bv);
        }
    }
}

// ---------------------------------------------------------------------------
// COOP: decoder persistent kernel with fence-minimal custom barriers.
// ---------------------------------------------------------------------------
__global__ __launch_bounds__(256, 2) void dec_coop(
    const float* __restrict__ inputs, const f16* __restrict__ V,
    const float* __restrict__ W2, const float* __restrict__ b2,
    const f16* __restrict__ enchi,
    const float* __restrict__ fcW, const float* __restrict__ fcb,
    const float* __restrict__ Wih,
    f16* __restrict__ gu, long long ustride,
    f16* __restrict__ hdhi,
    const float* __restrict__ fcfW, const float* __restrict__ fcfb,
    float* __restrict__ out,
    const f16* __restrict__ dWcf, const float* __restrict__ dbias,
    unsigned* __restrict__ flags)
{
    __shared__ f16 sW[4 * 4096];      // resident W tile: 32 cols x 512 K (32 KB)
    __shared__ float su[512];
    __shared__ float sw2[512];
    __shared__ float s_c[512];        // persistent c for batch b
    __shared__ float s_att[TM1];
    __shared__ float sred[4];
    const int b = blockIdx.x, tid = threadIdx.x;
    const int lane = tid & 63, wid = tid >> 6;
    const int rl = lane & 31, kq = lane >> 5;

    const bool gact = (b < 384);
    int n0g = 0, m0g = 0, kbeg = 0, ksf = 0;
    if (b < 256) {            // gate tiles: 64 n x 4 m, K=512 (h only), slice 0
        n0g = 512 + (b & 63) * 32; m0g = (b >> 6) * 128; kbeg = 0; ksf = 0;
    } else if (b < 384) {     // su tiles: 16 n x 4 m x 2 ks over K=1024 ([h,c])
        int i = b - 256;
        n0g = (i & 15) * 32; m0g = ((i >> 4) & 3) * 128;
        ksf = i >> 6; kbeg = ksf * 512;
    }

    if (gact) {
        for (int u = tid; u < 512; u += 256) {
            int r = u >> 4, c = u & 15;
#pragma unroll
            for (int p = 0; p < 4; ++p) {
                *(float4*)&sW[p * 4096 + r * 128 + ((c ^ (r & 15)) * 8)] =
                    *(const float4*)(dWcf + (size_t)(n0g + r) * 1024 + kbeg + p * 128 + c * 8);
            }
        }
    }
    {
        int e = tid * 2;
        sw2[e] = W2[e]; sw2[e + 1] = W2[e + 1];
        s_c[e] = 0.f;  s_c[e + 1] = 0.f;
    }
    __syncthreads();

    const f16* pAg = hdhi + (size_t)(m0g + wid * 32 + rl) * 1024 + kbeg;
    const int gcol = n0g + rl;
    const float gbv = (gact && ksf == 0) ? dbias[gcol] : 0.f;
    f16* gCp = gu + (size_t)ksf * ustride;

    for (int t = 0; t < TM1; ++t) {
        // ===== phase G: gu(t) from hdhi =====
        if (gact) {
            floatx16 acc = {};
            for (int p = 0; p < 4; ++p) {
#pragma unroll
                for (int kk = 0; kk < 128; kk += 16) {
                    int lg = (kk >> 3) + kq;
                    half8 ah = *(const half8*)(pAg + p * 128 + lg * 8);
                    half8 wh = *(const half8*)&sW[p * 4096 + rl * 128 + ((lg ^ (rl & 15)) * 8)];
                    acc = __builtin_amdgcn_mfma_f32_32x32x16_f16(ah, wh, acc, 0, 0, 0);
                }
            }
#pragma unroll
            for (int rr = 0; rr < 16; ++rr) {
                int row = m0g + wid * 32 + (rr & 3) + 8 * (rr >> 2) + 4 * kq;
                gCp[(size_t)row * 2560 + gcol] = (f16)(acc[rr] + gbv);
            }
        }
        gbar(flags, 64 + 2 * t, b);

        // ===== phase S: dec_step(t) =====
        const bool last = (t == TM1 - 1);
        {
            int e = tid * 2;
            const f16* q = gu + (size_t)b * 2560 + e;
            half2v a0 = *(const half2v*)(q);
            half2v a1 = *(const half2v*)(q + ustride);
            su[e]     = (float)a0[0] + (float)a1[0];
            su[e + 1] = (float)a0[1] + (float)a1[1];
        }
        __syncthreads();
        if (tid < 248) {
            int tp = tid >> 3, l8 = tid & 7;
            const f16* vrow = V + ((size_t)b * TM1 + tp) * 512;
            float p = 0.f;
            for (int j = l8 * 8; j < 512; j += 64) {
                half8 v8 = *(const half8*)(vrow + j);
#pragma unroll
                for (int e = 0; e < 8; e++)
                    p += tanh_fast(su[j + e] + (float)v8[e]) * sw2[j + e];
            }
            p += __shfl_xor(p, 1); p += __shfl_xor(p, 2); p += __shfl_xor(p, 4);
            if (l8 == 0) s_att[tp] = p + b2[0];
        }
        __syncthreads();
        if (tid < 64) {
            float v = (tid < TM1) ? s_att[tid] : -3.4e38f;
            float m = v;
#pragma unroll
            for (int k = 32; k > 0; k >>= 1) m = fmaxf(m, __shfl_xor(m, k));
            float e = (tid < TM1) ? __expf(v - m) : 0.f;
            float s = e;
#pragma unroll
            for (int k = 32; k > 0; k >>= 1) s += __shfl_xor(s, k);
            if (tid < TM1) s_att[tid] = e / s;
        }
        __syncthreads();

        float part, pctx = 0.f;
        {
            int e = tid * 2;
            float cx0 = 0.f, cx1 = 0.f;
            const f16* eh = enchi + (size_t)b * TM1 * 512 + e;
            for (int tp = 0; tp < TM1; tp++) {
                half2v v2 = *(const half2v*)(eh + tp * 512);
                cx0 += s_att[tp] * (float)v2[0];
                cx1 += s_att[tp] * (float)v2[1];
            }
            float2 fw = *(const float2*)(fcW + e);
            part = cx0 * fw.x + cx1 * fw.y;
            if (last) {
                float2 fw2 = *(const float2*)(fcfW + 512 + e);
                pctx = cx0 * fw2.x + cx1 * fw2.y;
            }
        }
        float y = inputs[((size_t)b * TM1 + t) * 257];
        float ysum = blockReduceSum256(part, sred);
        float y_til = ysum + y * fcW[512] + fcb[0];

        float ph = 0.f;
        {
            int e = tid * 2;
            const f16* qq = gu + (size_t)b * 2560 + e;  // gates: slice 0 only
            half2v a = *(const half2v*)(qq + 512);
            half2v f = *(const half2v*)(qq + 1024);
            half2v gv = *(const half2v*)(qq + 1536);
            half2v o = *(const half2v*)(qq + 2048);
            float gi0 = (float)a[0], gi1 = (float)a[1];
            float gf0 = (float)f[0], gf1 = (float)f[1];
            float gg0 = (float)gv[0], gg1 = (float)gv[1];
            float go0 = (float)o[0], go1 = (float)o[1];
            gi0 += y_til * Wih[e];        gi1 += y_til * Wih[e + 1];
            gf0 += y_til * Wih[512 + e];  gf1 += y_til * Wih[512 + e + 1];
            gg0 += y_til * Wih[1024 + e]; gg1 += y_til * Wih[1024 + e + 1];
            go0 += y_til * Wih[1536 + e]; go1 += y_til * Wih[1536 + e + 1];
            float c20 = sigmf(gf0) * s_c[e]     + sigmf(gi0) * tanh_fast(gg0);
            float c21 = sigmf(gf1) * s_c[e + 1] + sigmf(gi1) * tanh_fast(gg1);
            float h20 = sigmf(go0) * tanh_fast(c20);
            float h21 = sigmf(go1) * tanh_fast(c21);
            if (!last) {
                s_c[e] = c20; s_c[e + 1] = c21;
                half2v hv; hv[0] = (f16)h20; hv[1] = (f16)h21;
                half2v cv; cv[0] = (f16)c20; cv[1] = (f16)c21;
                *(half2v*)(hdhi + (size_t)b * 1024 + e) = hv;
                *(half2v*)(hdhi + (size_t)b * 1024 + 512 + e) = cv;
            } else {
                ph += h20 * fcfW[e] + h21 * fcfW[e + 1];
            }
        }
        if (last) {
            float s = blockReduceSum256(ph + pctx, sred);
            if (tid == 0) out[b] = s + fcfb[0];
        }
        if (t < TM1 - 1) gbar(flags, 64 + 2 * t + 1, b);
    }
}

extern "C" void kernel_launch(void* const* d_in, const int* in_sizes, int n_in,
                              void* d_out, int out_size, void* d_ws, size_t ws_size,
                              hipStream_t stream) {
    const float* inputs  = (const float*)d_in[0];
    const float* eWih    = (const float*)d_in[1];
    const float* eWhh    = (const float*)d_in[2];
    const float* ebih    = (const float*)d_in[3];
    const float* ebhh    = (const float*)d_in[4];
    const float* eWc     = (const float*)d_in[5];
    const float* ebc     = (const float*)d_in[6];
    const float* eWd     = (const float*)d_in[7];
    const float* ebd     = (const float*)d_in[8];
    const float* eWa     = (const float*)d_in[9];
    const float* eba     = (const float*)d_in[10];
    const float* dW1     = (const float*)d_in[11];
    const float* db1     = (const float*)d_in[12];
    const float* dW2     = (const float*)d_in[13];
    const float* db2     = (const float*)d_in[14];
    const float* dWih    = (const float*)d_in[15];
    const float* dWhh    = (const float*)d_in[16];
    const float* dbih    = (const float*)d_in[17];
    const float* dbhh    = (const float*)d_in[18];
    const float* fcW     = (const float*)d_in[19];
    const float* fcb     = (const float*)d_in[20];
    const float* fcfW    = (const float*)d_in[21];
    const float* fcfb    = (const float*)d_in[22];
    float* out = (float*)d_out;

    float* scr = (float*)d_ws;
    f16* t2s = (f16*)scr;                       // 4,063,232 h
    f16* Vf  = (f16*)scr;                       // 8,126,464 h
    f16* g0e = (f16*)(scr + 4063232);           // 2 x 1,048,576 h
    f16* gu0 = (f16*)(scr + 4063232);           // 2 x 1,310,720 h
    float* hc_enc = scr + 6684672;              //   524,288 f
    f16*   Ahi    = (f16*)(scr + 7208960);      //   393,216 h
    float* hc_dec = scr + 7405568;              //   524,288 f
    f16*   hdhi   = (f16*)(scr + 7929856);      //   524,288 h
    f16* fp = (f16*)(scr + 8192000);
    f16* eWf   = fp;             fp += 1572864;
    f16* dWcf  = fp;             fp += 2621440;
    f16* Vwf   = fp;             fp += 262144;
    f16* enchi = fp;             fp += 8126464;
    float* ebcomb = (float*)(((uintptr_t)fp + 15) & ~(uintptr_t)15);
    float* dbias  = ebcomb + 2048;              // 2560 f
    f16* Wcf = (f16*)(dbias + 2560);            // 31,744 h
    unsigned* flags = (unsigned*)(((uintptr_t)(Wcf + 31744) + 255) & ~(uintptr_t)255);

    hipLaunchKernelGGL(prep_t2s_kernel, dim3(2048), dim3(256), 0, stream,
                       inputs, eWih, eWhh, ebih, ebhh, dW1, dWhh, dbih, dbhh,
                       eWd, ebd, eWc, eWf, dWcf, Vwf,
                       ebcomb, dbias, t2s, Wcf, flags);

    long long gstride = 1048576;   // halves per g slice
    long long ustride = 1310720;   // halves per gu slice

    // -------- encoder: cooperative; fall back to per-step on launch error --
    bool enc_ok = false;
    {
        void* a[] = {(void*)&inputs, (void*)&t2s, (void*)&Wcf, (void*)&ebc,
                     (void*)&eWa, (void*)&eba, (void*)&g0e, (void*)&gstride,
                     (void*)&Ahi, (void*)&enchi, (void*)&hc_dec, (void*)&hdhi,
                     (void*)&eWf, (void*)&ebcomb, (void*)&flags};
        enc_ok = (hipLaunchCooperativeKernel((const void*)enc_coop, dim3(512),
                                             dim3(256), a, 0, stream) == hipSuccess);
    }
    if (!enc_ok) {
        for (int t = 0; t < TM1; t++) {
            hipLaunchKernelGGL(enc_step_kernel, dim3(BATCH), dim3(256), 0, stream,
                               inputs, t2s, Wcf, ebc, eWa, eba, g0e, gstride, hc_enc,
                               Ahi, enchi, hc_dec, hdhi, t);
            hipLaunchKernelGGL(gemm1f, dim3(512), dim3(256), 0, stream,
                               Ahi, 768, eWf, 768, ebcomb,
                               g0e, 2048, gstride, 768, 1 << 30, 32, 8, 2);
        }
        hipLaunchKernelGGL(enc_step_kernel, dim3(BATCH), dim3(256), 0, stream,
                           inputs, t2s, Wcf, ebc, eWa, eba, g0e, gstride, hc_enc,
                           Ahi, enchi, hc_dec, hdhi, TM1);
    }

    // -------- V = enc_out @ dec_W1[:,1024:]^T + b1 (f16 out) --------
    hipLaunchKernelGGL(gemm_v, dim3(992), dim3(256), 0, stream,
                       enchi, 512, Vwf, 512, db1,
                       Vf, 512, 512, 4, 248, 2);

    // -------- decoder: cooperative; fall back to per-step on launch error --
    bool dec_ok = false;
    {
        void* a[] = {(void*)&inputs, (void*)&Vf, (void*)&dW2, (void*)&db2,
                     (void*)&enchi, (void*)&fcW, (void*)&fcb, (void*)&dWih,
                     (void*)&gu0, (void*)&ustride, (void*)&hdhi,
                     (void*)&fcfW, (void*)&fcfb, (void*)&out,
                     (void*)&dWcf, (void*)&dbias, (void*)&flags};
        dec_ok = (hipLaunchCooperativeKernel((const void*)dec_coop, dim3(512),
                                             dim3(256), a, 0, stream) == hipSuccess);
    }
    if (!dec_ok) {
        for (int t = 0; t < TM1; t++) {
            hipLaunchKernelGGL(gemm1f, dim3(640), dim3(256), 0, stream,
                               hdhi, 1024, dWcf, 1024, dbias,
                               gu0, 2560, ustride, 1024, 512, 40, 8, 2);
            hipLaunchKernelGGL(dec_step_kernel, dim3(BATCH), dim3(256), 0, stream,
                               inputs, Vf, dW2, db2, enchi, fcW, fcb, dWih,
                               gu0, ustride, hc_dec, hdhi, fcfW, fcfb, out, t);
        }
    }
}

// Round 5
// 3461.585 us; speedup vs baseline: 5.0909x; 1.3902x over previous
//
#include <hip/hip_runtime.h>
#include <math.h>

#define BATCH 512
#define TM1   31
#define DIMD  256

typedef _Float16 f16;
typedef _Float16 half2v __attribute__((ext_vector_type(2)));
typedef _Float16 half8 __attribute__((ext_vector_type(8)));
typedef float floatx16 __attribute__((ext_vector_type(16)));

__device__ __forceinline__ float sigmf(float x) { return 1.f / (1.f + __expf(-x)); }

__device__ __forceinline__ float tanh_fast(float x) {
    float ax = fabsf(x);
    float t  = __expf(-2.f * ax);
    float r  = (1.f - t) / (1.f + t);
    return copysignf(r, x);
}

__device__ __forceinline__ float blockReduceSum256(float v, float* sred) {
#pragma unroll
    for (int m = 32; m > 0; m >>= 1) v += __shfl_xor(v, m);
    __syncthreads();
    if ((threadIdx.x & 63) == 0) sred[threadIdx.x >> 6] = v;
    __syncthreads();
    return sred[0] + sred[1] + sred[2] + sred[3];
}

__device__ __forceinline__ float blockReduceMax256(float v, float* sred) {
#pragma unroll
    for (int m = 32; m > 0; m >>= 1) v = fmaxf(v, __shfl_xor(v, m));
    __syncthreads();
    if ((threadIdx.x & 63) == 0) sred[threadIdx.x >> 6] = v;
    __syncthreads();
    return fmaxf(fmaxf(sred[0], sred[1]), fmaxf(sred[2], sred[3]));
}

// ---------------------------------------------------------------------------
// Coherence-point (sc0 sc1) access helpers: write-through to IF$, loads
// bypass stale per-XCD L2. No cache-maintenance ops needed anywhere.
// ---------------------------------------------------------------------------
__device__ __forceinline__ void st2cc(f16* p, f16 v) {
    unsigned u = (unsigned)__builtin_bit_cast(unsigned short, v);
    asm volatile("global_store_short %0, %1, off sc0 sc1" :: "v"(p), "v"(u) : "memory");
}
__device__ __forceinline__ void st4cc(void* p, unsigned v) {
    asm volatile("global_store_dword %0, %1, off sc0 sc1" :: "v"(p), "v"(v) : "memory");
}
// 8 x 16B contiguous-stride (32B apart) loads, one waitcnt.
__device__ __forceinline__ void ld8x16cc(const f16* base, float4* r) {
    asm volatile(
        "global_load_dwordx4 %0, %8, off sc0 sc1\n\t"
        "global_load_dwordx4 %1, %8, off offset:32 sc0 sc1\n\t"
        "global_load_dwordx4 %2, %8, off offset:64 sc0 sc1\n\t"
        "global_load_dwordx4 %3, %8, off offset:96 sc0 sc1\n\t"
        "global_load_dwordx4 %4, %8, off offset:128 sc0 sc1\n\t"
        "global_load_dwordx4 %5, %8, off offset:160 sc0 sc1\n\t"
        "global_load_dwordx4 %6, %8, off offset:192 sc0 sc1\n\t"
        "global_load_dwordx4 %7, %8, off offset:224 sc0 sc1\n\t"
        "s_waitcnt vmcnt(0)"
        : "=&v"(r[0]), "=&v"(r[1]), "=&v"(r[2]), "=&v"(r[3]),
          "=&v"(r[4]), "=&v"(r[5]), "=&v"(r[6]), "=&v"(r[7])
        : "v"(base) : "memory");
}
// enc A-phase: 8 x 4B gate loads from two slices.
__device__ __forceinline__ void ld_g8cc(const f16* q0, const f16* q1, unsigned* u) {
    asm volatile(
        "global_load_dword %0, %8, off sc0 sc1\n\t"
        "global_load_dword %1, %8, off offset:1024 sc0 sc1\n\t"
        "global_load_dword %2, %8, off offset:2048 sc0 sc1\n\t"
        "global_load_dword %3, %8, off offset:3072 sc0 sc1\n\t"
        "global_load_dword %4, %9, off sc0 sc1\n\t"
        "global_load_dword %5, %9, off offset:1024 sc0 sc1\n\t"
        "global_load_dword %6, %9, off offset:2048 sc0 sc1\n\t"
        "global_load_dword %7, %9, off offset:3072 sc0 sc1\n\t"
        "s_waitcnt vmcnt(0)"
        : "=&v"(u[0]), "=&v"(u[1]), "=&v"(u[2]), "=&v"(u[3]),
          "=&v"(u[4]), "=&v"(u[5]), "=&v"(u[6]), "=&v"(u[7])
        : "v"(q0), "v"(q1) : "memory");
}
// dec S-phase: su (2 slices) + 4 gates (slice 0), 6 x 4B.
__device__ __forceinline__ void ld_gu6cc(const f16* q, const f16* q1, unsigned* u) {
    const f16* qo = q + 2048;
    asm volatile(
        "global_load_dword %0, %6, off sc0 sc1\n\t"
        "global_load_dword %1, %7, off sc0 sc1\n\t"
        "global_load_dword %2, %6, off offset:1024 sc0 sc1\n\t"
        "global_load_dword %3, %6, off offset:2048 sc0 sc1\n\t"
        "global_load_dword %4, %6, off offset:3072 sc0 sc1\n\t"
        "global_load_dword %5, %8, off sc0 sc1\n\t"
        "s_waitcnt vmcnt(0)"
        : "=&v"(u[0]), "=&v"(u[1]), "=&v"(u[2]), "=&v"(u[3]), "=&v"(u[4]), "=&v"(u[5])
        : "v"(q), "v"(q1), "v"(qo) : "memory");
}

// ---------------------------------------------------------------------------
// Fence-free per-tile flags. Data travels via sc0sc1 ops (coherence point),
// so signal = vmcnt-drain + relaxed agent RMW; wait = relaxed BOUNDED spin
// (escape turns any liveness bug into a fast wrong-answer instead of a hang).
// ---------------------------------------------------------------------------
#define ENC_A_SLOT(t, m) ((t) * 8 + (m))
#define ENC_G_SLOT(t, m) (256 + (t) * 8 + (m))
#define DEC_G_SLOT(t, T) (512 + (t) * 4 + (T))
#define DEC_S_SLOT(t, T) (768 + (t) * 4 + (T))

__device__ __forceinline__ void sigflag(unsigned* flags, int slot) {
    asm volatile("s_waitcnt vmcnt(0)" ::: "memory");
    __syncthreads();
    if (threadIdx.x == 0)
        __hip_atomic_fetch_add(flags + slot * 16, 1u,
                               __ATOMIC_RELAXED, __HIP_MEMORY_SCOPE_AGENT);
}
__device__ __forceinline__ void waitflag(unsigned* flags, int slot, unsigned tgt) {
    if (threadIdx.x == 0) {
        for (int it = 0; it < (1 << 20); ++it) {
            if (__hip_atomic_load(flags + slot * 16,
                                  __ATOMIC_RELAXED, __HIP_MEMORY_SCOPE_AGENT) >= tgt)
                break;
            __builtin_amdgcn_s_sleep(2);
        }
    }
    __syncthreads();
    __builtin_amdgcn_sched_barrier(0);
}

// ---------------------------------------------------------------------------
// prep + t2s fused (+ flag zeroing).
// ---------------------------------------------------------------------------
__global__ __launch_bounds__(256) void prep_t2s_kernel(
    const float* __restrict__ inputs,
    const float* __restrict__ eWih, const float* __restrict__ eWhh,
    const float* __restrict__ ebih, const float* __restrict__ ebhh,
    const float* __restrict__ dW1,  const float* __restrict__ dWhh,
    const float* __restrict__ dbih, const float* __restrict__ dbhh,
    const float* __restrict__ Wd,   const float* __restrict__ bd,
    const float* __restrict__ Wc,
    f16* __restrict__ eWf, f16* __restrict__ dWcf, f16* __restrict__ Vwf,
    float* __restrict__ ebcomb, float* __restrict__ dbias,
    f16* __restrict__ t2s, f16* __restrict__ Wcf,
    unsigned* __restrict__ flags)
{
    __shared__ float sX[TM1 * DIMD];
    __shared__ float sWd[TM1 * TM1];
    int b = blockIdx.x, tid = threadIdx.x;
    int idx = b * 256 + tid;
    const int stride = gridDim.x * 256;

    if (b < 512) {
        for (int i = tid; i < TM1 * DIMD; i += 256) {
            int tt = i >> 8, d = i & 255;
            sX[i] = inputs[((size_t)b * TM1 + tt) * 257 + 1 + d];
        }
        for (int i = tid; i < TM1 * TM1; i += 256) sWd[i] = Wd[i];
        __syncthreads();
        int d = tid;
        for (int s = 0; s < TM1; s++) {
            float acc = bd[s];
            for (int tt = 0; tt < TM1; tt++) acc += sX[tt * DIMD + d] * sWd[s * TM1 + tt];
            t2s[((size_t)b * TM1 + s) * DIMD + d] = (f16)acc;
        }
    }

    for (int g = idx; g < 2048 * 96; g += stride) {
        int n = g / 96, k0 = (g % 96) * 8;
        const float* src = (k0 < 256) ? (eWih + n * 256 + k0)
                                      : (eWhh + n * 512 + (k0 - 256));
        float4 v0 = *(const float4*)src;
        float4 v1 = *(const float4*)(src + 4);
        f16 h[8] = {(f16)v0.x, (f16)v0.y, (f16)v0.z, (f16)v0.w,
                    (f16)v1.x, (f16)v1.y, (f16)v1.z, (f16)v1.w};
        *(half8*)(eWf + n * 768 + k0) = *(half8*)h;
    }
    for (int g = idx; g < 2560 * 128; g += stride) {
        int n = g >> 7, k0 = (g & 127) * 8;
        float vv[8] = {};
        if (n < 512) {
            const float* src = dW1 + n * 1536 + k0;
            float4 v0 = *(const float4*)src, v1 = *(const float4*)(src + 4);
            vv[0]=v0.x; vv[1]=v0.y; vv[2]=v0.z; vv[3]=v0.w;
            vv[4]=v1.x; vv[5]=v1.y; vv[6]=v1.z; vv[7]=v1.w;
        } else if (k0 < 512) {
            const float* src = dWhh + (n - 512) * 512 + k0;
            float4 v0 = *(const float4*)src, v1 = *(const float4*)(src + 4);
            vv[0]=v0.x; vv[1]=v0.y; vv[2]=v0.z; vv[3]=v0.w;
            vv[4]=v1.x; vv[5]=v1.y; vv[6]=v1.z; vv[7]=v1.w;
        }
        f16 h[8];
#pragma unroll
        for (int e = 0; e < 8; e++) h[e] = (f16)vv[e];
        *(half8*)(dWcf + n * 1024 + k0) = *(half8*)h;
    }
    for (int g = idx; g < 512 * 64; g += stride) {
        int n = g >> 6, k0 = (g & 63) * 8;
        const float* src = dW1 + n * 1536 + 1024 + k0;
        float4 v0 = *(const float4*)src, v1 = *(const float4*)(src + 4);
        f16 h[8] = {(f16)v0.x, (f16)v0.y, (f16)v0.z, (f16)v0.w,
                    (f16)v1.x, (f16)v1.y, (f16)v1.z, (f16)v1.w};
        *(half8*)(Vwf + n * 512 + k0) = *(half8*)h;
    }
    for (int g = idx; g < 3968; g += stride) {
        int k0 = g * 8;
        float4 v0 = *(const float4*)(Wc + k0);
        float4 v1 = *(const float4*)(Wc + k0 + 4);
        f16 h[8] = {(f16)v0.x, (f16)v0.y, (f16)v0.z, (f16)v0.w,
                    (f16)v1.x, (f16)v1.y, (f16)v1.z, (f16)v1.w};
        *(half8*)(Wcf + k0) = *(half8*)h;
    }
    for (int i = idx; i < 2048; i += stride) ebcomb[i] = ebih[i] + ebhh[i];
    for (int i = idx; i < 2560; i += stride)
        dbias[i] = (i < 512) ? 0.f : (dbih[i - 512] + dbhh[i - 512]);
    for (int i = idx; i < 128 * 128; i += stride) flags[i] = 0u;
}

// ---------------------------------------------------------------------------
// FALLBACK: step GEMM (R14-validated).
// ---------------------------------------------------------------------------
__global__ __launch_bounds__(256) void gemm1f(
    const f16* __restrict__ A, int lda,
    const f16* __restrict__ W, int ldw,
    const float* __restrict__ bias, f16* __restrict__ C, int ldc,
    long long Cstride, int K, int nsplit, int NT, int MT, int KS)
{
    __shared__ f16 sAh[64 * 128];
    __shared__ f16 sWh[64 * 128];
    int tid = threadIdx.x, bid = blockIdx.x;
    int nbase = bid % NT;
    int m0 = ((bid / NT) % MT) * 64;
    int ks = bid / (NT * MT);
    int lane = tid & 63, wid = tid >> 6;
    int wm = wid >> 1, wn = wid & 1;
    int rl = lane & 31, kq = lane >> 5;

    int sr = tid >> 2;
    int gb = (tid & 3) * 4;
    int st0 = sr * 128 + (((gb + 0) ^ (sr & 15)) * 8);
    int st1 = sr * 128 + (((gb + 1) ^ (sr & 15)) * 8);
    int st2 = sr * 128 + (((gb + 2) ^ (sr & 15)) * 8);
    int st3 = sr * 128 + (((gb + 3) ^ (sr & 15)) * 8);
    int arow = (wm * 32 + rl) * 128;
    int wrow = (wn * 32 + rl) * 128;
    int swk = rl & 15;

    int n0 = nbase * 64;
    int Kfull = (n0 >= nsplit) ? 512 : K;
    int ksz = Kfull / KS;
    int kbeg = ks * ksz, kend = kbeg + ksz;

    const f16* pA = A + (size_t)(m0 + sr) * lda + gb * 8;
    const f16* pW = W + (size_t)(n0 + sr) * ldw + gb * 8;

    float4 rA0 = *(const float4*)(pA + kbeg);
    float4 rA1 = *(const float4*)(pA + kbeg + 8);
    float4 rA2 = *(const float4*)(pA + kbeg + 16);
    float4 rA3 = *(const float4*)(pA + kbeg + 24);
    float4 rW0 = *(const float4*)(pW + kbeg);
    float4 rW1 = *(const float4*)(pW + kbeg + 8);
    float4 rW2 = *(const float4*)(pW + kbeg + 16);
    float4 rW3 = *(const float4*)(pW + kbeg + 24);

    floatx16 acc = {};
    for (int k0 = kbeg; k0 < kend; k0 += 128) {
        __syncthreads();
        *(float4*)&sAh[st0] = rA0; *(float4*)&sAh[st1] = rA1;
        *(float4*)&sAh[st2] = rA2; *(float4*)&sAh[st3] = rA3;
        *(float4*)&sWh[st0] = rW0; *(float4*)&sWh[st1] = rW1;
        *(float4*)&sWh[st2] = rW2; *(float4*)&sWh[st3] = rW3;
        __syncthreads();
        int kn = k0 + 128;
        if (kn < kend) {
            rA0 = *(const float4*)(pA + kn);      rA1 = *(const float4*)(pA + kn + 8);
            rA2 = *(const float4*)(pA + kn + 16); rA3 = *(const float4*)(pA + kn + 24);
            rW0 = *(const float4*)(pW + kn);      rW1 = *(const float4*)(pW + kn + 8);
            rW2 = *(const float4*)(pW + kn + 16); rW3 = *(const float4*)(pW + kn + 24);
        }
#pragma unroll
        for (int kk = 0; kk < 128; kk += 16) {
            int lg = (kk >> 3) + kq;
            half8 ah = *(const half8*)&sAh[arow + ((lg ^ swk) * 8)];
            half8 wh = *(const half8*)&sWh[wrow + ((lg ^ swk) * 8)];
            acc = __builtin_amdgcn_mfma_f32_32x32x16_f16(ah, wh, acc, 0, 0, 0);
        }
    }

    int col = n0 + wn * 32 + rl;
    float bv = (ks == 0) ? bias[col] : 0.f;
    f16* Cp = C + (size_t)ks * Cstride;
#pragma unroll
    for (int rr = 0; rr < 16; ++rr) {
        int row = m0 + wm * 32 + (rr & 3) + 8 * (rr >> 2) + 4 * kq;
        Cp[(size_t)row * ldc + col] = (f16)(acc[rr] + bv);
    }
}

// ---------------------------------------------------------------------------
// FALLBACK: encoder step (R14-validated).
// ---------------------------------------------------------------------------
__global__ __launch_bounds__(256) void enc_step_kernel(
    const float* __restrict__ inputs, const f16* __restrict__ t2s,
    const f16* __restrict__ Wcf, const float* __restrict__ bc,
    const float* __restrict__ Wa, const float* __restrict__ ba,
    const f16* __restrict__ g, long long gstride,
    float* __restrict__ hc,
    f16* __restrict__ Ahi, f16* __restrict__ enchi,
    float* __restrict__ hc_dec, f16* __restrict__ hdhi,
    int t) {
    __shared__ float sh_hc[1024];
    __shared__ float t1s[32];
    __shared__ float sred[4];
    int b = blockIdx.x, tid = threadIdx.x;

    if (t > 0) {
        int e = tid * 2;
        const f16* gp = g + (size_t)b * 2048 + e;
        float gi0 = 0.f, gi1 = 0.f, gf0 = 0.f, gf1 = 0.f;
        float gg0 = 0.f, gg1 = 0.f, go0 = 0.f, go1 = 0.f;
#pragma unroll
        for (int s = 0; s < 2; s++) {
            const f16* q = gp + s * gstride;
            half2v a = *(const half2v*)(q);
            half2v f = *(const half2v*)(q + 512);
            half2v gv = *(const half2v*)(q + 1024);
            half2v o = *(const half2v*)(q + 1536);
            gi0 += (float)a[0]; gi1 += (float)a[1];
            gf0 += (float)f[0]; gf1 += (float)f[1];
            gg0 += (float)gv[0]; gg1 += (float)gv[1];
            go0 += (float)o[0]; go1 += (float)o[1];
        }
        float2 cpv = *(const float2*)(hc + b * 1024 + 512 + e);
        float c20 = sigmf(gf0) * cpv.x + sigmf(gi0) * tanh_fast(gg0);
        float c21 = sigmf(gf1) * cpv.y + sigmf(gi1) * tanh_fast(gg1);
        float h20 = sigmf(go0) * tanh_fast(c20);
        float h21 = sigmf(go1) * tanh_fast(c21);
        *(float2*)(hc + b * 1024 + 512 + e) = make_float2(c20, c21);
        sh_hc[e] = h20; sh_hc[e + 1] = h21;
        sh_hc[512 + e] = c20; sh_hc[512 + e + 1] = c21;
        half2v hv; hv[0] = (f16)h20; hv[1] = (f16)h21;
        *(half2v*)(enchi + ((size_t)b * TM1 + (t - 1)) * 512 + e) = hv;
    } else {
        for (int j = tid; j < 1024; j += 256) { sh_hc[j] = 0.f; }
        for (int j = tid; j < 512; j += 256) hc[b * 1024 + 512 + j] = 0.f;
    }
    if (t == TM1) {
        for (int j = tid; j < 512; j += 256) hc_dec[b * 1024 + 512 + j] = 0.f;
        for (int j = tid; j < 1024; j += 256) hdhi[b * 1024 + j] = (f16)0.f;
        return;
    }
    __syncthreads();

    if (tid < 248) {
        int s = tid >> 3, l8 = tid & 7;
        const f16* wrow = Wcf + s * 1024;
        float p = 0.f;
        for (int j = l8 * 8; j < 1024; j += 64) {
            half8 w8 = *(const half8*)(wrow + j);
#pragma unroll
            for (int e = 0; e < 8; e++) p += (float)w8[e] * sh_hc[j + e];
        }
        p += __shfl_xor(p, 1); p += __shfl_xor(p, 2); p += __shfl_xor(p, 4);
        if (l8 == 0) t1s[s] = p + bc[s];
    }
    __syncthreads();

    int d = tid;
    float sc = ba[0];
    const f16* t2p = t2s + ((size_t)b * TM1) * DIMD + d;
    for (int s = 0; s < TM1; s++) sc += tanh_fast(t1s[s] + (float)t2p[s * DIMD]) * Wa[s];
    float mx = blockReduceMax256(sc, sred);
    float ex = __expf(sc - mx);
    float sm = blockReduceSum256(ex, sred);
    float w = (ex / sm) * inputs[((size_t)b * TM1 + t) * 257 + 1 + d];
    Ahi[b * 768 + d] = (f16)w;
    {
        int j = tid * 2;
        half2v hv; hv[0] = (f16)sh_hc[j]; hv[1] = (f16)sh_hc[j + 1];
        *(half2v*)(Ahi + b * 768 + 256 + j) = hv;
    }
}

// ---------------------------------------------------------------------------
// FALLBACK: decoder step (R14-validated).
// ---------------------------------------------------------------------------
__global__ __launch_bounds__(256) void dec_step_kernel(
    const float* __restrict__ inputs, const f16* __restrict__ V,
    const float* __restrict__ W2, const float* __restrict__ b2,
    const f16* __restrict__ enchi,
    const float* __restrict__ fcW, const float* __restrict__ fcb,
    const float* __restrict__ Wih,
    const f16* __restrict__ gu, long long ustride,
    float* __restrict__ hc, f16* __restrict__ hdhi,
    const float* __restrict__ fcfW, const float* __restrict__ fcfb,
    float* __restrict__ out, int t) {
    __shared__ float su[512];
    __shared__ float sw2[512];
    __shared__ float s_att[TM1];
    __shared__ float sred[4];
    int b = blockIdx.x, tid = threadIdx.x;
    const bool last = (t == TM1 - 1);
    {
        int e = tid * 2;
        const f16* q = gu + (size_t)b * 2560 + e;
        half2v a0 = *(const half2v*)(q);
        half2v a1 = *(const half2v*)(q + ustride);
        su[e]     = (float)a0[0] + (float)a1[0];
        su[e + 1] = (float)a0[1] + (float)a1[1];
        sw2[e] = W2[e]; sw2[e + 1] = W2[e + 1];
    }
    __syncthreads();
    if (tid < 248) {
        int tp = tid >> 3, l8 = tid & 7;
        const f16* vrow = V + ((size_t)b * TM1 + tp) * 512;
        float p = 0.f;
        for (int j = l8 * 8; j < 512; j += 64) {
            half8 v8 = *(const half8*)(vrow + j);
#pragma unroll
            for (int e = 0; e < 8; e++)
                p += tanh_fast(su[j + e] + (float)v8[e]) * sw2[j + e];
        }
        p += __shfl_xor(p, 1); p += __shfl_xor(p, 2); p += __shfl_xor(p, 4);
        if (l8 == 0) s_att[tp] = p + b2[0];
    }
    __syncthreads();
    if (tid < 64) {
        float v = (tid < TM1) ? s_att[tid] : -3.4e38f;
        float m = v;
#pragma unroll
        for (int k = 32; k > 0; k >>= 1) m = fmaxf(m, __shfl_xor(m, k));
        float e = (tid < TM1) ? __expf(v - m) : 0.f;
        float s = e;
#pragma unroll
        for (int k = 32; k > 0; k >>= 1) s += __shfl_xor(s, k);
        if (tid < TM1) s_att[tid] = e / s;
    }
    __syncthreads();

    float part, pctx = 0.f;
    {
        int e = tid * 2;
        float cx0 = 0.f, cx1 = 0.f;
        const f16* eh = enchi + (size_t)b * TM1 * 512 + e;
        for (int tp = 0; tp < TM1; tp++) {
            half2v v2 = *(const half2v*)(eh + tp * 512);
            cx0 += s_att[tp] * (float)v2[0];
            cx1 += s_att[tp] * (float)v2[1];
        }
        float2 fw = *(const float2*)(fcW + e);
        part = cx0 * fw.x + cx1 * fw.y;
        if (last) {
            float2 fw2 = *(const float2*)(fcfW + 512 + e);
            pctx = cx0 * fw2.x + cx1 * fw2.y;
        }
    }
    float y = inputs[((size_t)b * TM1 + t) * 257];
    float ysum = blockReduceSum256(part, sred);
    float y_til = ysum + y * fcW[512] + fcb[0];

    float ph = 0.f;
    {
        int e = tid * 2;
        const f16* q = gu + (size_t)b * 2560 + e;
        float gi0 = 0.f, gi1 = 0.f, gf0 = 0.f, gf1 = 0.f;
        float gg0 = 0.f, gg1 = 0.f, go0 = 0.f, go1 = 0.f;
#pragma unroll
        for (int s = 0; s < 2; s++) {
            const f16* qq = q + s * ustride;
            half2v a = *(const half2v*)(qq + 512);
            half2v f = *(const half2v*)(qq + 1024);
            half2v gv = *(const half2v*)(qq + 1536);
            half2v o = *(const half2v*)(qq + 2048);
            gi0 += (float)a[0]; gi1 += (float)a[1];
            gf0 += (float)f[0]; gf1 += (float)f[1];
            gg0 += (float)gv[0]; gg1 += (float)gv[1];
            go0 += (float)o[0]; go1 += (float)o[1];
        }
        gi0 += y_til * Wih[e];        gi1 += y_til * Wih[e + 1];
        gf0 += y_til * Wih[512 + e];  gf1 += y_til * Wih[512 + e + 1];
        gg0 += y_til * Wih[1024 + e]; gg1 += y_til * Wih[1024 + e + 1];
        go0 += y_til * Wih[1536 + e]; go1 += y_til * Wih[1536 + e + 1];
        float2 cpv = *(const float2*)(hc + b * 1024 + 512 + e);
        float c20 = sigmf(gf0) * cpv.x + sigmf(gi0) * tanh_fast(gg0);
        float c21 = sigmf(gf1) * cpv.y + sigmf(gi1) * tanh_fast(gg1);
        float h20 = sigmf(go0) * tanh_fast(c20);
        float h21 = sigmf(go1) * tanh_fast(c21);
        if (!last) {
            *(float2*)(hc + b * 1024 + 512 + e) = make_float2(c20, c21);
            half2v hv; hv[0] = (f16)h20; hv[1] = (f16)h21;
            half2v cv; cv[0] = (f16)c20; cv[1] = (f16)c21;
            *(half2v*)(hdhi + (size_t)b * 1024 + e) = hv;
            *(half2v*)(hdhi + (size_t)b * 1024 + 512 + e) = cv;
        } else {
            ph += h20 * fcfW[e] + h21 * fcfW[e + 1];
        }
    }
    if (last) {
        float s = blockReduceSum256(ph + pctx, sred);
        if (tid == 0) out[b] = s + fcfb[0];
    }
}

// ---------------------------------------------------------------------------
// COOP encoder: per-tile flags + sc0sc1 data, no cache-maintenance ops.
// ---------------------------------------------------------------------------
__global__ __launch_bounds__(256, 2) void enc_coop(
    const float* __restrict__ inputs, const f16* __restrict__ t2s,
    const f16* __restrict__ Wcf, const float* __restrict__ bc,
    const float* __restrict__ Wa, const float* __restrict__ ba,
    f16* __restrict__ g, long long gstride,
    f16* __restrict__ Ahi, f16* __restrict__ enchi,
    float* __restrict__ hc_dec, f16* __restrict__ hdhi,
    const f16* __restrict__ eWf, const float* __restrict__ ebcomb,
    unsigned* __restrict__ flags)
{
    __shared__ f16 sWh[3 * 8192];      // resident W tile (48 KB)
    __shared__ float sh_hc[1024];
    __shared__ float t1s[32];
    __shared__ float sred[4];
    const int b = blockIdx.x, tid = threadIdx.x;

    const int lane = tid & 63, wid = tid >> 6;
    const int wm = wid >> 1, wn = wid & 1;
    const int rl = lane & 31, kq = lane >> 5;
    const int sr = tid >> 2;
    const int gb = (tid & 3) * 4;
    const int st0 = sr * 128 + (((gb + 0) ^ (sr & 15)) * 8);
    const int st1 = sr * 128 + (((gb + 1) ^ (sr & 15)) * 8);
    const int st2_ = sr * 128 + (((gb + 2) ^ (sr & 15)) * 8);
    const int st3 = sr * 128 + (((gb + 3) ^ (sr & 15)) * 8);
    const int n0g = (b & 31) * 64;
    const int m0g = ((b >> 5) & 7) * 64;
    const int ksg = b >> 8;
    const int kbeg = ksg * 384;
    const int wrow = (wn * 32 + rl) * 128;
    const int swk = rl & 15;
    const int atile = b >> 6;          // tile owning this block's batch row
    const int gtile = (b >> 5) & 7;    // tile of G-phase m rows
    const f16* pW  = eWf + (size_t)(n0g + sr) * 768 + gb * 8;
    const f16* pAg = Ahi + (size_t)(m0g + wm * 32 + rl) * 768 + kbeg + kq * 8;
    const int gcol = n0g + wn * 32 + rl;
    const float gbv = (ksg == 0) ? ebcomb[gcol] : 0.f;
    f16* gCp = g + (size_t)ksg * gstride;

    // one-time resident W preload (normal loads; written by prep cross-kernel)
#pragma unroll
    for (int p = 0; p < 3; ++p) {
        *(float4*)&sWh[p * 8192 + st0]  = *(const float4*)(pW + kbeg + p * 128);
        *(float4*)&sWh[p * 8192 + st1]  = *(const float4*)(pW + kbeg + p * 128 + 8);
        *(float4*)&sWh[p * 8192 + st2_] = *(const float4*)(pW + kbeg + p * 128 + 16);
        *(float4*)&sWh[p * 8192 + st3]  = *(const float4*)(pW + kbeg + p * 128 + 24);
    }
    __syncthreads();

    for (int t = 0; t <= TM1; ++t) {
        // ===== phase A: finalize LSTM(t-1) + attention(t) =====
        if (t > 0) {
            waitflag(flags, ENC_G_SLOT(t - 1, atile), 64);
            int e = tid * 2;
            unsigned u[8];
            const f16* q0 = g + (size_t)b * 2048 + e;
            ld_g8cc(q0, q0 + gstride, u);
            half2v a0 = __builtin_bit_cast(half2v, u[0]), a1 = __builtin_bit_cast(half2v, u[4]);
            half2v f0 = __builtin_bit_cast(half2v, u[1]), f1 = __builtin_bit_cast(half2v, u[5]);
            half2v g0 = __builtin_bit_cast(half2v, u[2]), g1 = __builtin_bit_cast(half2v, u[6]);
            half2v o0 = __builtin_bit_cast(half2v, u[3]), o1 = __builtin_bit_cast(half2v, u[7]);
            float gi0 = (float)a0[0] + (float)a1[0], gi1 = (float)a0[1] + (float)a1[1];
            float gf0 = (float)f0[0] + (float)f1[0], gf1 = (float)f0[1] + (float)f1[1];
            float gg0 = (float)g0[0] + (float)g1[0], gg1 = (float)g0[1] + (float)g1[1];
            float go0 = (float)o0[0] + (float)o1[0], go1 = (float)o0[1] + (float)o1[1];
            float c0 = sh_hc[512 + e], c1 = sh_hc[513 + e];
            float c20 = sigmf(gf0) * c0 + sigmf(gi0) * tanh_fast(gg0);
            float c21 = sigmf(gf1) * c1 + sigmf(gi1) * tanh_fast(gg1);
            float h20 = sigmf(go0) * tanh_fast(c20);
            float h21 = sigmf(go1) * tanh_fast(c21);
            sh_hc[e] = h20; sh_hc[e + 1] = h21;
            sh_hc[512 + e] = c20; sh_hc[513 + e] = c21;
            half2v hv; hv[0] = (f16)h20; hv[1] = (f16)h21;
            *(half2v*)(enchi + ((size_t)b * TM1 + (t - 1)) * 512 + e) = hv;
        } else {
            for (int j = tid; j < 1024; j += 256) sh_hc[j] = 0.f;
        }
        if (t == TM1) {
            for (int j = tid; j < 512; j += 256) hc_dec[b * 1024 + 512 + j] = 0.f;
            for (int j = tid; j < 1024; j += 256) hdhi[(size_t)b * 1024 + j] = (f16)0.f;
            break;
        }
        __syncthreads();

        if (tid < 248) {
            int s = tid >> 3, l8 = tid & 7;
            const f16* wr = Wcf + s * 1024;
            float p = 0.f;
            for (int j = l8 * 8; j < 1024; j += 64) {
                half8 w8 = *(const half8*)(wr + j);
#pragma unroll
                for (int e2 = 0; e2 < 8; e2++) p += (float)w8[e2] * sh_hc[j + e2];
            }
            p += __shfl_xor(p, 1); p += __shfl_xor(p, 2); p += __shfl_xor(p, 4);
            if (l8 == 0) t1s[s] = p + bc[s];
        }
        __syncthreads();
        {
            int d = tid;
            float sc = ba[0];
            const f16* t2p = t2s + ((size_t)b * TM1) * DIMD + d;
            for (int s = 0; s < TM1; s++) sc += tanh_fast(t1s[s] + (float)t2p[s * DIMD]) * Wa[s];
            float mx = blockReduceMax256(sc, sred);
            float ex = __expf(sc - mx);
            float sm = blockReduceSum256(ex, sred);
            float w = (ex / sm) * inputs[((size_t)b * TM1 + t) * 257 + 1 + d];
            st2cc(Ahi + b * 768 + d, (f16)w);
            int j = tid * 2;
            half2v hv; hv[0] = (f16)sh_hc[j]; hv[1] = (f16)sh_hc[j + 1];
            st4cc(Ahi + b * 768 + 256 + j, __builtin_bit_cast(unsigned, hv));
        }
        sigflag(flags, ENC_A_SLOT(t, atile));

        // ===== phase G: g(t) = Ahi @ W^T (tile) =====
        waitflag(flags, ENC_A_SLOT(t, gtile), 64);
        {
            float4 ra[8];
            floatx16 acc = {};
            for (int p = 0; p < 3; ++p) {
                ld8x16cc(pAg + p * 128, ra);
#pragma unroll
                for (int j = 0; j < 8; ++j) {
                    int lg = 2 * j + kq;
                    half8 ah = __builtin_bit_cast(half8, ra[j]);
                    half8 wh = *(const half8*)&sWh[p * 8192 + wrow + ((lg ^ swk) * 8)];
                    acc = __builtin_amdgcn_mfma_f32_32x32x16_f16(ah, wh, acc, 0, 0, 0);
                }
            }
#pragma unroll
            for (int rr = 0; rr < 16; ++rr) {
                int row = m0g + wm * 32 + (rr & 3) + 8 * (rr >> 2) + 4 * kq;
                st2cc(gCp + (size_t)row * 2048 + gcol, (f16)(acc[rr] + gbv));
            }
        }
        sigflag(flags, ENC_G_SLOT(t, gtile));
    }
}

// ---------------------------------------------------------------------------
// V GEMM (unchanged).
// ---------------------------------------------------------------------------
__global__ __launch_bounds__(256) void gemm_v(
    const f16* __restrict__ A, int lda,
    const f16* __restrict__ W, int ldw,
    const float* __restrict__ bias, f16* __restrict__ C, int ldc,
    int K, int NT, int MT, int NREP)
{
    __shared__ f16 sAh[64 * 64];
    __shared__ f16 sWh[64 * 64];
    int tid = threadIdx.x, bid = blockIdx.x;
    int nbase = bid % NT;
    int m0 = ((bid / NT) % MT) * 64;
    int lane = tid & 63, wid = tid >> 6;
    int wm = wid >> 1, wn = wid & 1;
    int rl = lane & 31, kq = lane >> 5;
    int sr = tid >> 2;
    int g0 = (tid & 3) * 2;
    int s0 = sr * 64 + ((g0 ^ (sr & 7)) * 8);
    int s1 = sr * 64 + (((g0 + 1) ^ (sr & 7)) * 8);
    int arow = (wm * 32 + rl) * 64;
    int wrow = (wn * 32 + rl) * 64;
    int sw = (rl & 7);

    const f16* pA = A + (size_t)(m0 + sr) * lda + g0 * 8;

    for (int r = 0; r < NREP; ++r) {
        int n0 = (nbase + r * NT) * 64;
        const f16* pW = W + (size_t)(n0 + sr) * ldw + g0 * 8;
        float4 rA0 = *(const float4*)(pA);
        float4 rA1 = *(const float4*)(pA + 8);
        float4 rW0 = *(const float4*)(pW);
        float4 rW1 = *(const float4*)(pW + 8);
        floatx16 acc = {};
        for (int k0 = 0; k0 < K; k0 += 64) {
            __syncthreads();
            *(float4*)&sAh[s0] = rA0; *(float4*)&sAh[s1] = rA1;
            *(float4*)&sWh[s0] = rW0; *(float4*)&sWh[s1] = rW1;
            __syncthreads();
            int kn = k0 + 64;
            if (kn < K) {
                rA0 = *(const float4*)(pA + kn); rA1 = *(const float4*)(pA + kn + 8);
                rW0 = *(const float4*)(pW + kn); rW1 = *(const float4*)(pW + kn + 8);
            }
#pragma unroll
            for (int kk = 0; kk < 64; kk += 16) {
                int lg = (kk >> 3) + kq;
                int off = ((lg ^ sw) * 8);
                half8 ah = *(const half8*)&sAh[arow + off];
                half8 wh = *(const half8*)&sWh[wrow + off];
                acc = __builtin_amdgcn_mfma_f32_32x32x16_f16(ah, wh, acc, 0, 0, 0);
            }
        }
        int col = n0 + wn * 32 + rl;
        float bv = bias[col];
#pragma unroll
        for (int rr = 0; rr < 16; ++rr) {
            int row = m0 + wm * 32 + (rr & 3) + 8 * (rr >> 2) + 4 * kq;
            C[(size_t)row * ldc + col] = (f16)(acc[rr] + bv);
        }
    }
}

// ---------------------------------------------------------------------------
// COOP decoder: per-tile flags + sc0sc1 data.
// ---------------------------------------------------------------------------
__global__ __launch_bounds__(256, 2) void dec_coop(
    const float* __restrict__ inputs, const f16* __restrict__ V,
    const float* __restrict__ W2, const float* __restrict__ b2,
    const f16* __restrict__ enchi,
    const float* __restrict__ fcW, const float* __restrict__ fcb,
    const float* __restrict__ Wih,
    f16* __restrict__ gu, long long ustride,
    f16* __restrict__ hdhi,
    const float* __restrict__ fcfW, const float* __restrict__ fcfb,
    float* __restrict__ out,
    const f16* __restrict__ dWcf, const float* __restrict__ dbias,
    unsigned* __restrict__ flags)
{
    __shared__ f16 sW[4 * 4096];      // resident W tile (32 KB)
    __shared__ float su[512];
    __shared__ float sw2[512];
    __shared__ float s_c[512];
    __shared__ float s_att[TM1];
    __shared__ float sred[4];
    const int b = blockIdx.x, tid = threadIdx.x;
    const int lane = tid & 63, wid = tid >> 6;
    const int rl = lane & 31, kq = lane >> 5;

    const bool gact = (b < 384);
    int n0g = 0, m0g = 0, kbeg = 0, ksf = 0;
    if (b < 256) {            // gate tiles: K=512 (h only), slice 0
        n0g = 512 + (b & 63) * 32; m0g = (b >> 6) * 128; kbeg = 0; ksf = 0;
    } else if (b < 384) {     // su tiles: 2 ks over K=1024 ([h,c])
        int i = b - 256;
        n0g = (i & 15) * 32; m0g = ((i >> 4) & 3) * 128;
        ksf = i >> 6; kbeg = ksf * 512;
    }
    const int gT = m0g >> 7;          // G-phase m-tile (0..3)
    const int sT = b >> 7;            // S-phase tile of this batch

    if (gact) {
        for (int u = tid; u < 512; u += 256) {
            int r = u >> 4, c = u & 15;
#pragma unroll
            for (int p = 0; p < 4; ++p) {
                *(float4*)&sW[p * 4096 + r * 128 + ((c ^ (r & 15)) * 8)] =
                    *(const float4*)(dWcf + (size_t)(n0g + r) * 1024 + kbeg + p * 128 + c * 8);
            }
        }
    }
    {
        int e = tid * 2;
        sw2[e] = W2[e]; sw2[e + 1] = W2[e + 1];
        s_c[e] = 0.f;  s_c[e + 1] = 0.f;
    }
    __syncthreads();

    const f16* pAg = hdhi + (size_t)(m0g + wid * 32 + rl) * 1024 + kbeg + kq * 8;
    const int gcol = n0g + rl;
    const float gbv = (gact && ksf == 0) ? dbias[gcol] : 0.f;
    f16* gCp = gu + (size_t)ksf * ustride;

    for (int t = 0; t < TM1; ++t) {
        // ===== phase G: gu(t) from hdhi =====
        if (gact) {
            if (t > 0) waitflag(flags, DEC_S_SLOT(t - 1, gT), 128);
            float4 ra[8];
            floatx16 acc = {};
            for (int p = 0; p < 4; ++p) {
                ld8x16cc(pAg + p * 128, ra);
#pragma unroll
                for (int j = 0; j < 8; ++j) {
                    int lg = 2 * j + kq;
                    half8 ah = __builtin_bit_cast(half8, ra[j]);
                    half8 wh = *(const half8*)&sW[p * 4096 + rl * 128 + ((lg ^ (rl & 15)) * 8)];
                    acc = __builtin_amdgcn_mfma_f32_32x32x16_f16(ah, wh, acc, 0, 0, 0);
                }
            }
#pragma unroll
            for (int rr = 0; rr < 16; ++rr) {
                int row = m0g + wid * 32 + (rr & 3) + 8 * (rr >> 2) + 4 * kq;
                st2cc(gCp + (size_t)row * 2560 + gcol, (f16)(acc[rr] + gbv));
            }
            sigflag(flags, DEC_G_SLOT(t, gT));
        }

        // ===== phase S: dec_step(t) =====
        waitflag(flags, DEC_G_SLOT(t, sT), 96);
        const bool last = (t == TM1 - 1);
        unsigned ug[6];
        {
            int e = tid * 2;
            const f16* q = gu + (size_t)b * 2560 + e;
            ld_gu6cc(q, q + ustride, ug);
            half2v a0 = __builtin_bit_cast(half2v, ug[0]);
            half2v a1 = __builtin_bit_cast(half2v, ug[1]);
            su[e]     = (float)a0[0] + (float)a1[0];
            su[e + 1] = (float)a0[1] + (float)a1[1];
        }
        __syncthreads();
        if (tid < 248) {
            int tp = tid >> 3, l8 = tid & 7;
            const f16* vrow = V + ((size_t)b * TM1 + tp) * 512;
            float p = 0.f;
            for (int j = l8 * 8; j < 512; j += 64) {
                half8 v8 = *(const half8*)(vrow + j);
#pragma unroll
                for (int e = 0; e < 8; e++)
                    p += tanh_fast(su[j + e] + (float)v8[e]) * sw2[j + e];
            }
            p += __shfl_xor(p, 1); p += __shfl_xor(p, 2); p += __shfl_xor(p, 4);
            if (l8 == 0) s_att[tp] = p + b2[0];
        }
        __syncthreads();
        if (tid < 64) {
            float v = (tid < TM1) ? s_att[tid] : -3.4e38f;
            float m = v;
#pragma unroll
            for (int k = 32; k > 0; k >>= 1) m = fmaxf(m, __shfl_xor(m, k));
            float e = (tid < TM1) ? __expf(v - m) : 0.f;
            float s = e;
#pragma unroll
            for (int k = 32; k > 0; k >>= 1) s += __shfl_xor(s, k);
            if (tid < TM1) s_att[tid] = e / s;
        }
        __syncthreads();

        float part, pctx = 0.f;
        {
            int e = tid * 2;
            float cx0 = 0.f, cx1 = 0.f;
            const f16* eh = enchi + (size_t)b * TM1 * 512 + e;
            for (int tp = 0; tp < TM1; tp++) {
                half2v v2 = *(const half2v*)(eh + tp * 512);
                cx0 += s_att[tp] * (float)v2[0];
                cx1 += s_att[tp] * (float)v2[1];
            }
            float2 fw = *(const float2*)(fcW + e);
            part = cx0 * fw.x + cx1 * fw.y;
            if (last) {
                float2 fw2 = *(const float2*)(fcfW + 512 + e);
                pctx = cx0 * fw2.x + cx1 * fw2.y;
            }
        }
        float y = inputs[((size_t)b * TM1 + t) * 257];
        float ysum = blockReduceSum256(part, sred);
        float y_til = ysum + y * fcW[512] + fcb[0];

        float ph = 0.f;
        {
            int e = tid * 2;
            half2v a = __builtin_bit_cast(half2v, ug[2]);
            half2v f = __builtin_bit_cast(half2v, ug[3]);
            half2v gv = __builtin_bit_cast(half2v, ug[4]);
            half2v o = __builtin_bit_cast(half2v, ug[5]);
            float gi0 = (float)a[0], gi1 = (float)a[1];
            float gf0 = (float)f[0], gf1 = (float)f[1];
            float gg0 = (float)gv[0], gg1 = (float)gv[1];
            float go0 = (float)o[0], go1 = (float)o[1];
            gi0 += y_til * Wih[e];        gi1 += y_til * Wih[e + 1];
            gf0 += y_til * Wih[512 + e];  gf1 += y_til * Wih[512 + e + 1];
            gg0 += y_til * Wih[1024 + e]; gg1 += y_til * Wih[1024 + e + 1];
            go0 += y_til * Wih[1536 + e]; go1 += y_til * Wih[1536 + e + 1];
            float c20 = sigmf(gf0) * s_c[e]     + sigmf(gi0) * tanh_fast(gg0);
            float c21 = sigmf(gf1) * s_c[e + 1] + sigmf(gi1) * tanh_fast(gg1);
            float h20 = sigmf(go0) * tanh_fast(c20);
            float h21 = sigmf(go1) * tanh_fast(c21);
            if (!last) {
                s_c[e] = c20; s_c[e + 1] = c21;
                half2v hv; hv[0] = (f16)h20; hv[1] = (f16)h21;
                half2v cv; cv[0] = (f16)c20; cv[1] = (f16)c21;
                st4cc(hdhi + (size_t)b * 1024 + e, __builtin_bit_cast(unsigned, hv));
                st4cc(hdhi + (size_t)b * 1024 + 512 + e, __builtin_bit_cast(unsigned, cv));
            } else {
                ph += h20 * fcfW[e] + h21 * fcfW[e + 1];
            }
        }
        if (!last) {
            sigflag(flags, DEC_S_SLOT(t, sT));
        } else {
            float s = blockReduceSum256(ph + pctx, sred);
            if (tid == 0) out[b] = s + fcfb[0];
        }
    }
}

extern "C" void kernel_launch(void* const* d_in, const int* in_sizes, int n_in,
                              void* d_out, int out_size, void* d_ws, size_t ws_size,
                              hipStream_t stream) {
    const float* inputs  = (const float*)d_in[0];
    const float* eWih    = (const float*)d_in[1];
    const float* eWhh    = (const float*)d_in[2];
    const float* ebih    = (const float*)d_in[3];
    const float* ebhh    = (const float*)d_in[4];
    const float* eWc     = (const float*)d_in[5];
    const float* ebc     = (const float*)d_in[6];
    const float* eWd     = (const float*)d_in[7];
    const float* ebd     = (const float*)d_in[8];
    const float* eWa     = (const float*)d_in[9];
    const float* eba     = (const float*)d_in[10];
    const float* dW1     = (const float*)d_in[11];
    const float* db1     = (const float*)d_in[12];
    const float* dW2     = (const float*)d_in[13];
    const float* db2     = (const float*)d_in[14];
    const float* dWih    = (const float*)d_in[15];
    const float* dWhh    = (const float*)d_in[16];
    const float* dbih    = (const float*)d_in[17];
    const float* dbhh    = (const float*)d_in[18];
    const float* fcW     = (const float*)d_in[19];
    const float* fcb     = (const float*)d_in[20];
    const float* fcfW    = (const float*)d_in[21];
    const float* fcfb    = (const float*)d_in[22];
    float* out = (float*)d_out;

    float* scr = (float*)d_ws;
    f16* t2s = (f16*)scr;                       // 4,063,232 h
    f16* Vf  = (f16*)scr;                       // 8,126,464 h
    f16* g0e = (f16*)(scr + 4063232);           // 2 x 1,048,576 h
    f16* gu0 = (f16*)(scr + 4063232);           // 2 x 1,310,720 h
    float* hc_enc = scr + 6684672;              //   524,288 f
    f16*   Ahi    = (f16*)(scr + 7208960);      //   393,216 h
    float* hc_dec = scr + 7405568;              //   524,288 f
    f16*   hdhi   = (f16*)(scr + 7929856);      //   524,288 h
    f16* fp = (f16*)(scr + 8192000);
    f16* eWf   = fp;             fp += 1572864;
    f16* dWcf  = fp;             fp += 2621440;
    f16* Vwf   = fp;             fp += 262144;
    f16* enchi = fp;             fp += 8126464;
    float* ebcomb = (float*)(((uintptr_t)fp + 15) & ~(uintptr_t)15);
    float* dbias  = ebcomb + 2048;              // 2560 f
    f16* Wcf = (f16*)(dbias + 2560);            // 31,744 h
    unsigned* flags = (unsigned*)(((uintptr_t)(Wcf + 31744) + 255) & ~(uintptr_t)255);

    hipLaunchKernelGGL(prep_t2s_kernel, dim3(2048), dim3(256), 0, stream,
                       inputs, eWih, eWhh, ebih, ebhh, dW1, dWhh, dbih, dbhh,
                       eWd, ebd, eWc, eWf, dWcf, Vwf,
                       ebcomb, dbias, t2s, Wcf, flags);

    long long gstride = 1048576;   // halves per g slice
    long long ustride = 1310720;   // halves per gu slice

    // -------- encoder: cooperative; fall back to per-step on launch error --
    bool enc_ok = false;
    {
        void* a[] = {(void*)&inputs, (void*)&t2s, (void*)&Wcf, (void*)&ebc,
                     (void*)&eWa, (void*)&eba, (void*)&g0e, (void*)&gstride,
                     (void*)&Ahi, (void*)&enchi, (void*)&hc_dec, (void*)&hdhi,
                     (void*)&eWf, (void*)&ebcomb, (void*)&flags};
        enc_ok = (hipLaunchCooperativeKernel((const void*)enc_coop, dim3(512),
                                             dim3(256), a, 0, stream) == hipSuccess);
    }
    if (!enc_ok) {
        for (int t = 0; t < TM1; t++) {
            hipLaunchKernelGGL(enc_step_kernel, dim3(BATCH), dim3(256), 0, stream,
                               inputs, t2s, Wcf, ebc, eWa, eba, g0e, gstride, hc_enc,
                               Ahi, enchi, hc_dec, hdhi, t);
            hipLaunchKernelGGL(gemm1f, dim3(512), dim3(256), 0, stream,
                               Ahi, 768, eWf, 768, ebcomb,
                               g0e, 2048, gstride, 768, 1 << 30, 32, 8, 2);
        }
        hipLaunchKernelGGL(enc_step_kernel, dim3(BATCH), dim3(256), 0, stream,
                           inputs, t2s, Wcf, ebc, eWa, eba, g0e, gstride, hc_enc,
                           Ahi, enchi, hc_dec, hdhi, TM1);
    }

    // -------- V = enc_out @ dec_W1[:,1024:]^T + b1 (f16 out) --------
    hipLaunchKernelGGL(gemm_v, dim3(992), dim3(256), 0, stream,
                       enchi, 512, Vwf, 512, db1,
                       Vf, 512, 512, 4, 248, 2);

    // -------- decoder: cooperative; fall back to per-step on launch error --
    bool dec_ok = false;
    {
        void* a[] = {(void*)&inputs, (void*)&Vf, (void*)&dW2, (void*)&db2,
                     (void*)&enchi, (void*)&fcW, (void*)&fcb, (void*)&dWih,
                     (void*)&gu0, (void*)&ustride, (void*)&hdhi,
                     (void*)&fcfW, (void*)&fcfb, (void*)&out,
                     (void*)&dWcf, (void*)&dbias, (void*)&flags};
        dec_ok = (hipLaunchCooperativeKernel((const void*)dec_coop, dim3(512),
                                             dim3(256), a, 0, stream) == hipSuccess);
    }
    if (!dec_ok) {
        for (int t = 0; t < TM1; t++) {
            hipLaunchKernelGGL(gemm1f, dim3(640), dim3(256), 0, stream,
                               hdhi, 1024, dWcf, 1024, dbias,
                               gu0, 2560, ustride, 1024, 512, 40, 8, 2);
            hipLaunchKernelGGL(dec_step_kernel, dim3(BATCH), dim3(256), 0, stream,
                               inputs, Vf, dW2, db2, enchi, fcW, fcb, dWih,
                               gu0, ustride, hc_dec, hdhi, fcfW, fcfb, out, t);
        }
    }
}

// Round 6
// 2089.953 us; speedup vs baseline: 8.4321x; 1.6563x over previous
//
#include <hip/hip_runtime.h>
#include <math.h>

#define BATCH 512
#define TM1   31
#define DIMD  256

typedef _Float16 f16;
typedef _Float16 half2v __attribute__((ext_vector_type(2)));
typedef _Float16 half8 __attribute__((ext_vector_type(8)));
typedef float floatx16 __attribute__((ext_vector_type(16)));

__device__ __forceinline__ float sigmf(float x) { return 1.f / (1.f + __expf(-x)); }

__device__ __forceinline__ float tanh_fast(float x) {
    float ax = fabsf(x);
    float t  = __expf(-2.f * ax);
    float r  = (1.f - t) / (1.f + t);
    return copysignf(r, x);
}

__device__ __forceinline__ float blockReduceSum256(float v, float* sred) {
#pragma unroll
    for (int m = 32; m > 0; m >>= 1) v += __shfl_xor(v, m);
    __syncthreads();
    if ((threadIdx.x & 63) == 0) sred[threadIdx.x >> 6] = v;
    __syncthreads();
    return sred[0] + sred[1] + sred[2] + sred[3];
}

__device__ __forceinline__ float blockReduceMax256(float v, float* sred) {
#pragma unroll
    for (int m = 32; m > 0; m >>= 1) v = fmaxf(v, __shfl_xor(v, m));
    __syncthreads();
    if ((threadIdx.x & 63) == 0) sred[threadIdx.x >> 6] = v;
    __syncthreads();
    return fmaxf(fmaxf(sred[0], sred[1]), fmaxf(sred[2], sred[3]));
}

// ---------------------------------------------------------------------------
// Coherence-point (sc0 sc1) access helpers: write-through to IF$, loads
// bypass stale per-XCD L2. No cache-maintenance ops needed anywhere.
// ---------------------------------------------------------------------------
__device__ __forceinline__ void st2cc(f16* p, f16 v) {
    unsigned u = (unsigned)__builtin_bit_cast(unsigned short, v);
    asm volatile("global_store_short %0, %1, off sc0 sc1" :: "v"(p), "v"(u) : "memory");
}
__device__ __forceinline__ void st4cc(void* p, unsigned v) {
    asm volatile("global_store_dword %0, %1, off sc0 sc1" :: "v"(p), "v"(v) : "memory");
}
// 8 x 16B contiguous-stride (32B apart) loads, one waitcnt.
__device__ __forceinline__ void ld8x16cc(const f16* base, float4* r) {
    asm volatile(
        "global_load_dwordx4 %0, %8, off sc0 sc1\n\t"
        "global_load_dwordx4 %1, %8, off offset:32 sc0 sc1\n\t"
        "global_load_dwordx4 %2, %8, off offset:64 sc0 sc1\n\t"
        "global_load_dwordx4 %3, %8, off offset:96 sc0 sc1\n\t"
        "global_load_dwordx4 %4, %8, off offset:128 sc0 sc1\n\t"
        "global_load_dwordx4 %5, %8, off offset:160 sc0 sc1\n\t"
        "global_load_dwordx4 %6, %8, off offset:192 sc0 sc1\n\t"
        "global_load_dwordx4 %7, %8, off offset:224 sc0 sc1\n\t"
        "s_waitcnt vmcnt(0)"
        : "=&v"(r[0]), "=&v"(r[1]), "=&v"(r[2]), "=&v"(r[3]),
          "=&v"(r[4]), "=&v"(r[5]), "=&v"(r[6]), "=&v"(r[7])
        : "v"(base) : "memory");
}
// enc A-phase: 8 x 4B gate loads from two slices.
__device__ __forceinline__ void ld_g8cc(const f16* q0, const f16* q1, unsigned* u) {
    asm volatile(
        "global_load_dword %0, %8, off sc0 sc1\n\t"
        "global_load_dword %1, %8, off offset:1024 sc0 sc1\n\t"
        "global_load_dword %2, %8, off offset:2048 sc0 sc1\n\t"
        "global_load_dword %3, %8, off offset:3072 sc0 sc1\n\t"
        "global_load_dword %4, %9, off sc0 sc1\n\t"
        "global_load_dword %5, %9, off offset:1024 sc0 sc1\n\t"
        "global_load_dword %6, %9, off offset:2048 sc0 sc1\n\t"
        "global_load_dword %7, %9, off offset:3072 sc0 sc1\n\t"
        "s_waitcnt vmcnt(0)"
        : "=&v"(u[0]), "=&v"(u[1]), "=&v"(u[2]), "=&v"(u[3]),
          "=&v"(u[4]), "=&v"(u[5]), "=&v"(u[6]), "=&v"(u[7])
        : "v"(q0), "v"(q1) : "memory");
}
// dec S-phase: su (2 slices) + 4 gates (slice 0), 6 x 4B.
__device__ __forceinline__ void ld_gu6cc(const f16* q, const f16* q1, unsigned* u) {
    const f16* qo = q + 2048;
    asm volatile(
        "global_load_dword %0, %6, off sc0 sc1\n\t"
        "global_load_dword %1, %7, off sc0 sc1\n\t"
        "global_load_dword %2, %6, off offset:1024 sc0 sc1\n\t"
        "global_load_dword %3, %6, off offset:2048 sc0 sc1\n\t"
        "global_load_dword %4, %6, off offset:3072 sc0 sc1\n\t"
        "global_load_dword %5, %8, off sc0 sc1\n\t"
        "s_waitcnt vmcnt(0)"
        : "=&v"(u[0]), "=&v"(u[1]), "=&v"(u[2]), "=&v"(u[3]), "=&v"(u[4]), "=&v"(u[5])
        : "v"(q), "v"(q1), "v"(qo) : "memory");
}

// ---------------------------------------------------------------------------
// Fence-free per-tile flags, 16-way spread (R21): each slot = 16 words on 16
// DISTINCT 64B lines (slot stride 1 KB). Producer adds to word bid&15 ->
// <=8 serialized RMWs per line, parallel across 16 TCC channels. Waiter sums
// 16 relaxed loads. Data travels via sc0sc1 ops; signal needs no fence.
// Bounded spin turns any liveness bug into fast wrong-answer, not a hang.
// ---------------------------------------------------------------------------
#define ENC_A_SLOT(t, m) ((t) * 8 + (m))
#define ENC_G_SLOT(t, m) (256 + (t) * 8 + (m))
#define DEC_G_SLOT(t, T) (512 + (t) * 4 + (T))
#define DEC_S_SLOT(t, T) (768 + (t) * 4 + (T))

__device__ __forceinline__ void sigflag(unsigned* flags, int slot, int bid) {
    asm volatile("s_waitcnt vmcnt(0)" ::: "memory");
    __syncthreads();
    if (threadIdx.x == 0)
        __hip_atomic_fetch_add(flags + slot * 256 + (bid & 15) * 16, 1u,
                               __ATOMIC_RELAXED, __HIP_MEMORY_SCOPE_AGENT);
}
__device__ __forceinline__ void waitflag(unsigned* flags, int slot, unsigned tgt) {
    if (threadIdx.x == 0) {
        unsigned* base = flags + slot * 256;
        for (int it = 0; it < (1 << 20); ++it) {
            unsigned s = 0;
#pragma unroll
            for (int j = 0; j < 16; j++)
                s += __hip_atomic_load(base + j * 16,
                                       __ATOMIC_RELAXED, __HIP_MEMORY_SCOPE_AGENT);
            if (s >= tgt) break;
            __builtin_amdgcn_s_sleep(2);
        }
    }
    __syncthreads();
    __builtin_amdgcn_sched_barrier(0);
}

// ---------------------------------------------------------------------------
// prep + t2s fused (+ flag zeroing, 1 MB region).
// ---------------------------------------------------------------------------
__global__ __launch_bounds__(256) void prep_t2s_kernel(
    const float* __restrict__ inputs,
    const float* __restrict__ eWih, const float* __restrict__ eWhh,
    const float* __restrict__ ebih, const float* __restrict__ ebhh,
    const float* __restrict__ dW1,  const float* __restrict__ dWhh,
    const float* __restrict__ dbih, const float* __restrict__ dbhh,
    const float* __restrict__ Wd,   const float* __restrict__ bd,
    const float* __restrict__ Wc,
    f16* __restrict__ eWf, f16* __restrict__ dWcf, f16* __restrict__ Vwf,
    float* __restrict__ ebcomb, float* __restrict__ dbias,
    f16* __restrict__ t2s, f16* __restrict__ Wcf,
    unsigned* __restrict__ flags)
{
    __shared__ float sX[TM1 * DIMD];
    __shared__ float sWd[TM1 * TM1];
    int b = blockIdx.x, tid = threadIdx.x;
    int idx = b * 256 + tid;
    const int stride = gridDim.x * 256;

    if (b < 512) {
        for (int i = tid; i < TM1 * DIMD; i += 256) {
            int tt = i >> 8, d = i & 255;
            sX[i] = inputs[((size_t)b * TM1 + tt) * 257 + 1 + d];
        }
        for (int i = tid; i < TM1 * TM1; i += 256) sWd[i] = Wd[i];
        __syncthreads();
        int d = tid;
        for (int s = 0; s < TM1; s++) {
            float acc = bd[s];
            for (int tt = 0; tt < TM1; tt++) acc += sX[tt * DIMD + d] * sWd[s * TM1 + tt];
            t2s[((size_t)b * TM1 + s) * DIMD + d] = (f16)acc;
        }
    }

    for (int g = idx; g < 2048 * 96; g += stride) {
        int n = g / 96, k0 = (g % 96) * 8;
        const float* src = (k0 < 256) ? (eWih + n * 256 + k0)
                                      : (eWhh + n * 512 + (k0 - 256));
        float4 v0 = *(const float4*)src;
        float4 v1 = *(const float4*)(src + 4);
        f16 h[8] = {(f16)v0.x, (f16)v0.y, (f16)v0.z, (f16)v0.w,
                    (f16)v1.x, (f16)v1.y, (f16)v1.z, (f16)v1.w};
        *(half8*)(eWf + n * 768 + k0) = *(half8*)h;
    }
    for (int g = idx; g < 2560 * 128; g += stride) {
        int n = g >> 7, k0 = (g & 127) * 8;
        float vv[8] = {};
        if (n < 512) {
            const float* src = dW1 + n * 1536 + k0;
            float4 v0 = *(const float4*)src, v1 = *(const float4*)(src + 4);
            vv[0]=v0.x; vv[1]=v0.y; vv[2]=v0.z; vv[3]=v0.w;
            vv[4]=v1.x; vv[5]=v1.y; vv[6]=v1.z; vv[7]=v1.w;
        } else if (k0 < 512) {
            const float* src = dWhh + (n - 512) * 512 + k0;
            float4 v0 = *(const float4*)src, v1 = *(const float4*)(src + 4);
            vv[0]=v0.x; vv[1]=v0.y; vv[2]=v0.z; vv[3]=v0.w;
            vv[4]=v1.x; vv[5]=v1.y; vv[6]=v1.z; vv[7]=v1.w;
        }
        f16 h[8];
#pragma unroll
        for (int e = 0; e < 8; e++) h[e] = (f16)vv[e];
        *(half8*)(dWcf + n * 1024 + k0) = *(half8*)h;
    }
    for (int g = idx; g < 512 * 64; g += stride) {
        int n = g >> 6, k0 = (g & 63) * 8;
        const float* src = dW1 + n * 1536 + 1024 + k0;
        float4 v0 = *(const float4*)src, v1 = *(const float4*)(src + 4);
        f16 h[8] = {(f16)v0.x, (f16)v0.y, (f16)v0.z, (f16)v0.w,
                    (f16)v1.x, (f16)v1.y, (f16)v1.z, (f16)v1.w};
        *(half8*)(Vwf + n * 512 + k0) = *(half8*)h;
    }
    for (int g = idx; g < 3968; g += stride) {
        int k0 = g * 8;
        float4 v0 = *(const float4*)(Wc + k0);
        float4 v1 = *(const float4*)(Wc + k0 + 4);
        f16 h[8] = {(f16)v0.x, (f16)v0.y, (f16)v0.z, (f16)v0.w,
                    (f16)v1.x, (f16)v1.y, (f16)v1.z, (f16)v1.w};
        *(half8*)(Wcf + k0) = *(half8*)h;
    }
    for (int i = idx; i < 2048; i += stride) ebcomb[i] = ebih[i] + ebhh[i];
    for (int i = idx; i < 2560; i += stride)
        dbias[i] = (i < 512) ? 0.f : (dbih[i - 512] + dbhh[i - 512]);
    for (int i = idx; i < 1024 * 256; i += stride) flags[i] = 0u;
}

// ---------------------------------------------------------------------------
// FALLBACK: step GEMM (R14-validated).
// ---------------------------------------------------------------------------
__global__ __launch_bounds__(256) void gemm1f(
    const f16* __restrict__ A, int lda,
    const f16* __restrict__ W, int ldw,
    const float* __restrict__ bias, f16* __restrict__ C, int ldc,
    long long Cstride, int K, int nsplit, int NT, int MT, int KS)
{
    __shared__ f16 sAh[64 * 128];
    __shared__ f16 sWh[64 * 128];
    int tid = threadIdx.x, bid = blockIdx.x;
    int nbase = bid % NT;
    int m0 = ((bid / NT) % MT) * 64;
    int ks = bid / (NT * MT);
    int lane = tid & 63, wid = tid >> 6;
    int wm = wid >> 1, wn = wid & 1;
    int rl = lane & 31, kq = lane >> 5;

    int sr = tid >> 2;
    int gb = (tid & 3) * 4;
    int st0 = sr * 128 + (((gb + 0) ^ (sr & 15)) * 8);
    int st1 = sr * 128 + (((gb + 1) ^ (sr & 15)) * 8);
    int st2 = sr * 128 + (((gb + 2) ^ (sr & 15)) * 8);
    int st3 = sr * 128 + (((gb + 3) ^ (sr & 15)) * 8);
    int arow = (wm * 32 + rl) * 128;
    int wrow = (wn * 32 + rl) * 128;
    int swk = rl & 15;

    int n0 = nbase * 64;
    int Kfull = (n0 >= nsplit) ? 512 : K;
    int ksz = Kfull / KS;
    int kbeg = ks * ksz, kend = kbeg + ksz;

    const f16* pA = A + (size_t)(m0 + sr) * lda + gb * 8;
    const f16* pW = W + (size_t)(n0 + sr) * ldw + gb * 8;

    float4 rA0 = *(const float4*)(pA + kbeg);
    float4 rA1 = *(const float4*)(pA + kbeg + 8);
    float4 rA2 = *(const float4*)(pA + kbeg + 16);
    float4 rA3 = *(const float4*)(pA + kbeg + 24);
    float4 rW0 = *(const float4*)(pW + kbeg);
    float4 rW1 = *(const float4*)(pW + kbeg + 8);
    float4 rW2 = *(const float4*)(pW + kbeg + 16);
    float4 rW3 = *(const float4*)(pW + kbeg + 24);

    floatx16 acc = {};
    for (int k0 = kbeg; k0 < kend; k0 += 128) {
        __syncthreads();
        *(float4*)&sAh[st0] = rA0; *(float4*)&sAh[st1] = rA1;
        *(float4*)&sAh[st2] = rA2; *(float4*)&sAh[st3] = rA3;
        *(float4*)&sWh[st0] = rW0; *(float4*)&sWh[st1] = rW1;
        *(float4*)&sWh[st2] = rW2; *(float4*)&sWh[st3] = rW3;
        __syncthreads();
        int kn = k0 + 128;
        if (kn < kend) {
            rA0 = *(const float4*)(pA + kn);      rA1 = *(const float4*)(pA + kn + 8);
            rA2 = *(const float4*)(pA + kn + 16); rA3 = *(const float4*)(pA + kn + 24);
            rW0 = *(const float4*)(pW + kn);      rW1 = *(const float4*)(pW + kn + 8);
            rW2 = *(const float4*)(pW + kn + 16); rW3 = *(const float4*)(pW + kn + 24);
        }
#pragma unroll
        for (int kk = 0; kk < 128; kk += 16) {
            int lg = (kk >> 3) + kq;
            half8 ah = *(const half8*)&sAh[arow + ((lg ^ swk) * 8)];
            half8 wh = *(const half8*)&sWh[wrow + ((lg ^ swk) * 8)];
            acc = __builtin_amdgcn_mfma_f32_32x32x16_f16(ah, wh, acc, 0, 0, 0);
        }
    }

    int col = n0 + wn * 32 + rl;
    float bv = (ks == 0) ? bias[col] : 0.f;
    f16* Cp = C + (size_t)ks * Cstride;
#pragma unroll
    for (int rr = 0; rr < 16; ++rr) {
        int row = m0 + wm * 32 + (rr & 3) + 8 * (rr >> 2) + 4 * kq;
        Cp[(size_t)row * ldc + col] = (f16)(acc[rr] + bv);
    }
}

// ---------------------------------------------------------------------------
// FALLBACK: encoder step (R14-validated).
// ---------------------------------------------------------------------------
__global__ __launch_bounds__(256) void enc_step_kernel(
    const float* __restrict__ inputs, const f16* __restrict__ t2s,
    const f16* __restrict__ Wcf, const float* __restrict__ bc,
    const float* __restrict__ Wa, const float* __restrict__ ba,
    const f16* __restrict__ g, long long gstride,
    float* __restrict__ hc,
    f16* __restrict__ Ahi, f16* __restrict__ enchi,
    float* __restrict__ hc_dec, f16* __restrict__ hdhi,
    int t) {
    __shared__ float sh_hc[1024];
    __shared__ float t1s[32];
    __shared__ float sred[4];
    int b = blockIdx.x, tid = threadIdx.x;

    if (t > 0) {
        int e = tid * 2;
        const f16* gp = g + (size_t)b * 2048 + e;
        float gi0 = 0.f, gi1 = 0.f, gf0 = 0.f, gf1 = 0.f;
        float gg0 = 0.f, gg1 = 0.f, go0 = 0.f, go1 = 0.f;
#pragma unroll
        for (int s = 0; s < 2; s++) {
            const f16* q = gp + s * gstride;
            half2v a = *(const half2v*)(q);
            half2v f = *(const half2v*)(q + 512);
            half2v gv = *(const half2v*)(q + 1024);
            half2v o = *(const half2v*)(q + 1536);
            gi0 += (float)a[0]; gi1 += (float)a[1];
            gf0 += (float)f[0]; gf1 += (float)f[1];
            gg0 += (float)gv[0]; gg1 += (float)gv[1];
            go0 += (float)o[0]; go1 += (float)o[1];
        }
        float2 cpv = *(const float2*)(hc + b * 1024 + 512 + e);
        float c20 = sigmf(gf0) * cpv.x + sigmf(gi0) * tanh_fast(gg0);
        float c21 = sigmf(gf1) * cpv.y + sigmf(gi1) * tanh_fast(gg1);
        float h20 = sigmf(go0) * tanh_fast(c20);
        float h21 = sigmf(go1) * tanh_fast(c21);
        *(float2*)(hc + b * 1024 + 512 + e) = make_float2(c20, c21);
        sh_hc[e] = h20; sh_hc[e + 1] = h21;
        sh_hc[512 + e] = c20; sh_hc[512 + e + 1] = c21;
        half2v hv; hv[0] = (f16)h20; hv[1] = (f16)h21;
        *(half2v*)(enchi + ((size_t)b * TM1 + (t - 1)) * 512 + e) = hv;
    } else {
        for (int j = tid; j < 1024; j += 256) { sh_hc[j] = 0.f; }
        for (int j = tid; j < 512; j += 256) hc[b * 1024 + 512 + j] = 0.f;
    }
    if (t == TM1) {
        for (int j = tid; j < 512; j += 256) hc_dec[b * 1024 + 512 + j] = 0.f;
        for (int j = tid; j < 1024; j += 256) hdhi[b * 1024 + j] = (f16)0.f;
        return;
    }
    __syncthreads();

    if (tid < 248) {
        int s = tid >> 3, l8 = tid & 7;
        const f16* wrow = Wcf + s * 1024;
        float p = 0.f;
        for (int j = l8 * 8; j < 1024; j += 64) {
            half8 w8 = *(const half8*)(wrow + j);
#pragma unroll
            for (int e = 0; e < 8; e++) p += (float)w8[e] * sh_hc[j + e];
        }
        p += __shfl_xor(p, 1); p += __shfl_xor(p, 2); p += __shfl_xor(p, 4);
        if (l8 == 0) t1s[s] = p + bc[s];
    }
    __syncthreads();

    int d = tid;
    float sc = ba[0];
    const f16* t2p = t2s + ((size_t)b * TM1) * DIMD + d;
    for (int s = 0; s < TM1; s++) sc += tanh_fast(t1s[s] + (float)t2p[s * DIMD]) * Wa[s];
    float mx = blockReduceMax256(sc, sred);
    float ex = __expf(sc - mx);
    float sm = blockReduceSum256(ex, sred);
    float w = (ex / sm) * inputs[((size_t)b * TM1 + t) * 257 + 1 + d];
    Ahi[b * 768 + d] = (f16)w;
    {
        int j = tid * 2;
        half2v hv; hv[0] = (f16)sh_hc[j]; hv[1] = (f16)sh_hc[j + 1];
        *(half2v*)(Ahi + b * 768 + 256 + j) = hv;
    }
}

// ---------------------------------------------------------------------------
// FALLBACK: decoder step (R14-validated).
// ---------------------------------------------------------------------------
__global__ __launch_bounds__(256) void dec_step_kernel(
    const float* __restrict__ inputs, const f16* __restrict__ V,
    const float* __restrict__ W2, const float* __restrict__ b2,
    const f16* __restrict__ enchi,
    const float* __restrict__ fcW, const float* __restrict__ fcb,
    const float* __restrict__ Wih,
    const f16* __restrict__ gu, long long ustride,
    float* __restrict__ hc, f16* __restrict__ hdhi,
    const float* __restrict__ fcfW, const float* __restrict__ fcfb,
    float* __restrict__ out, int t) {
    __shared__ float su[512];
    __shared__ float sw2[512];
    __shared__ float s_att[TM1];
    __shared__ float sred[4];
    int b = blockIdx.x, tid = threadIdx.x;
    const bool last = (t == TM1 - 1);
    {
        int e = tid * 2;
        const f16* q = gu + (size_t)b * 2560 + e;
        half2v a0 = *(const half2v*)(q);
        half2v a1 = *(const half2v*)(q + ustride);
        su[e]     = (float)a0[0] + (float)a1[0];
        su[e + 1] = (float)a0[1] + (float)a1[1];
        sw2[e] = W2[e]; sw2[e + 1] = W2[e + 1];
    }
    __syncthreads();
    if (tid < 248) {
        int tp = tid >> 3, l8 = tid & 7;
        const f16* vrow = V + ((size_t)b * TM1 + tp) * 512;
        float p = 0.f;
        for (int j = l8 * 8; j < 512; j += 64) {
            half8 v8 = *(const half8*)(vrow + j);
#pragma unroll
            for (int e = 0; e < 8; e++)
                p += tanh_fast(su[j + e] + (float)v8[e]) * sw2[j + e];
        }
        p += __shfl_xor(p, 1); p += __shfl_xor(p, 2); p += __shfl_xor(p, 4);
        if (l8 == 0) s_att[tp] = p + b2[0];
    }
    __syncthreads();
    if (tid < 64) {
        float v = (tid < TM1) ? s_att[tid] : -3.4e38f;
        float m = v;
#pragma unroll
        for (int k = 32; k > 0; k >>= 1) m = fmaxf(m, __shfl_xor(m, k));
        float e = (tid < TM1) ? __expf(v - m) : 0.f;
        float s = e;
#pragma unroll
        for (int k = 32; k > 0; k >>= 1) s += __shfl_xor(s, k);
        if (tid < TM1) s_att[tid] = e / s;
    }
    __syncthreads();

    float part, pctx = 0.f;
    {
        int e = tid * 2;
        float cx0 = 0.f, cx1 = 0.f;
        const f16* eh = enchi + (size_t)b * TM1 * 512 + e;
        for (int tp = 0; tp < TM1; tp++) {
            half2v v2 = *(const half2v*)(eh + tp * 512);
            cx0 += s_att[tp] * (float)v2[0];
            cx1 += s_att[tp] * (float)v2[1];
        }
        float2 fw = *(const float2*)(fcW + e);
        part = cx0 * fw.x + cx1 * fw.y;
        if (last) {
            float2 fw2 = *(const float2*)(fcfW + 512 + e);
            pctx = cx0 * fw2.x + cx1 * fw2.y;
        }
    }
    float y = inputs[((size_t)b * TM1 + t) * 257];
    float ysum = blockReduceSum256(part, sred);
    float y_til = ysum + y * fcW[512] + fcb[0];

    float ph = 0.f;
    {
        int e = tid * 2;
        const f16* q = gu + (size_t)b * 2560 + e;
        float gi0 = 0.f, gi1 = 0.f, gf0 = 0.f, gf1 = 0.f;
        float gg0 = 0.f, gg1 = 0.f, go0 = 0.f, go1 = 0.f;
#pragma unroll
        for (int s = 0; s < 2; s++) {
            const f16* qq = q + s * ustride;
            half2v a = *(const half2v*)(qq + 512);
            half2v f = *(const half2v*)(qq + 1024);
            half2v gv = *(const half2v*)(qq + 1536);
            half2v o = *(const half2v*)(qq + 2048);
            gi0 += (float)a[0]; gi1 += (float)a[1];
            gf0 += (float)f[0]; gf1 += (float)f[1];
            gg0 += (float)gv[0]; gg1 += (float)gv[1];
            go0 += (float)o[0]; go1 += (float)o[1];
        }
        gi0 += y_til * Wih[e];        gi1 += y_til * Wih[e + 1];
        gf0 += y_til * Wih[512 + e];  gf1 += y_til * Wih[512 + e + 1];
        gg0 += y_til * Wih[1024 + e]; gg1 += y_til * Wih[1024 + e + 1];
        go0 += y_til * Wih[1536 + e]; go1 += y_til * Wih[1536 + e + 1];
        float2 cpv = *(const float2*)(hc + b * 1024 + 512 + e);
        float c20 = sigmf(gf0) * cpv.x + sigmf(gi0) * tanh_fast(gg0);
        float c21 = sigmf(gf1) * cpv.y + sigmf(gi1) * tanh_fast(gg1);
        float h20 = sigmf(go0) * tanh_fast(c20);
        float h21 = sigmf(go1) * tanh_fast(c21);
        if (!last) {
            *(float2*)(hc + b * 1024 + 512 + e) = make_float2(c20, c21);
            half2v hv; hv[0] = (f16)h20; hv[1] = (f16)h21;
            half2v cv; cv[0] = (f16)c20; cv[1] = (f16)c21;
            *(half2v*)(hdhi + (size_t)b * 1024 + e) = hv;
            *(half2v*)(hdhi + (size_t)b * 1024 + 512 + e) = cv;
        } else {
            ph += h20 * fcfW[e] + h21 * fcfW[e + 1];
        }
    }
    if (last) {
        float s = blockReduceSum256(ph + pctx, sred);
        if (tid == 0) out[b] = s + fcfb[0];
    }
}

// ---------------------------------------------------------------------------
// COOP encoder: per-tile 16-way-spread flags + sc0sc1 data.
// ---------------------------------------------------------------------------
__global__ __launch_bounds__(256, 2) void enc_coop(
    const float* __restrict__ inputs, const f16* __restrict__ t2s,
    const f16* __restrict__ Wcf, const float* __restrict__ bc,
    const float* __restrict__ Wa, const float* __restrict__ ba,
    f16* __restrict__ g, long long gstride,
    f16* __restrict__ Ahi, f16* __restrict__ enchi,
    float* __restrict__ hc_dec, f16* __restrict__ hdhi,
    const f16* __restrict__ eWf, const float* __restrict__ ebcomb,
    unsigned* __restrict__ flags)
{
    __shared__ f16 sWh[3 * 8192];      // resident W tile (48 KB)
    __shared__ float sh_hc[1024];
    __shared__ float t1s[32];
    __shared__ float sred[4];
    const int b = blockIdx.x, tid = threadIdx.x;

    const int lane = tid & 63, wid = tid >> 6;
    const int wm = wid >> 1, wn = wid & 1;
    const int rl = lane & 31, kq = lane >> 5;
    const int sr = tid >> 2;
    const int gb = (tid & 3) * 4;
    const int st0 = sr * 128 + (((gb + 0) ^ (sr & 15)) * 8);
    const int st1 = sr * 128 + (((gb + 1) ^ (sr & 15)) * 8);
    const int st2_ = sr * 128 + (((gb + 2) ^ (sr & 15)) * 8);
    const int st3 = sr * 128 + (((gb + 3) ^ (sr & 15)) * 8);
    const int n0g = (b & 31) * 64;
    const int m0g = ((b >> 5) & 7) * 64;
    const int ksg = b >> 8;
    const int kbeg = ksg * 384;
    const int wrow = (wn * 32 + rl) * 128;
    const int swk = rl & 15;
    const int atile = b >> 6;          // tile owning this block's batch row
    const int gtile = (b >> 5) & 7;    // tile of G-phase m rows
    const f16* pW  = eWf + (size_t)(n0g + sr) * 768 + gb * 8;
    const f16* pAg = Ahi + (size_t)(m0g + wm * 32 + rl) * 768 + kbeg + kq * 8;
    const int gcol = n0g + wn * 32 + rl;
    const float gbv = (ksg == 0) ? ebcomb[gcol] : 0.f;
    f16* gCp = g + (size_t)ksg * gstride;

    // one-time resident W preload (normal loads; written by prep cross-kernel)
#pragma unroll
    for (int p = 0; p < 3; ++p) {
        *(float4*)&sWh[p * 8192 + st0]  = *(const float4*)(pW + kbeg + p * 128);
        *(float4*)&sWh[p * 8192 + st1]  = *(const float4*)(pW + kbeg + p * 128 + 8);
        *(float4*)&sWh[p * 8192 + st2_] = *(const float4*)(pW + kbeg + p * 128 + 16);
        *(float4*)&sWh[p * 8192 + st3]  = *(const float4*)(pW + kbeg + p * 128 + 24);
    }
    __syncthreads();

    for (int t = 0; t <= TM1; ++t) {
        // ===== phase A: finalize LSTM(t-1) + attention(t) =====
        if (t > 0) {
            waitflag(flags, ENC_G_SLOT(t - 1, atile), 64);
            int e = tid * 2;
            unsigned u[8];
            const f16* q0 = g + (size_t)b * 2048 + e;
            ld_g8cc(q0, q0 + gstride, u);
            half2v a0 = __builtin_bit_cast(half2v, u[0]), a1 = __builtin_bit_cast(half2v, u[4]);
            half2v f0 = __builtin_bit_cast(half2v, u[1]), f1 = __builtin_bit_cast(half2v, u[5]);
            half2v g0 = __builtin_bit_cast(half2v, u[2]), g1 = __builtin_bit_cast(half2v, u[6]);
            half2v o0 = __builtin_bit_cast(half2v, u[3]), o1 = __builtin_bit_cast(half2v, u[7]);
            float gi0 = (float)a0[0] + (float)a1[0], gi1 = (float)a0[1] + (float)a1[1];
            float gf0 = (float)f0[0] + (float)f1[0], gf1 = (float)f0[1] + (float)f1[1];
            float gg0 = (float)g0[0] + (float)g1[0], gg1 = (float)g0[1] + (float)g1[1];
            float go0 = (float)o0[0] + (float)o1[0], go1 = (float)o0[1] + (float)o1[1];
            float c0 = sh_hc[512 + e], c1 = sh_hc[513 + e];
            float c20 = sigmf(gf0) * c0 + sigmf(gi0) * tanh_fast(gg0);
            float c21 = sigmf(gf1) * c1 + sigmf(gi1) * tanh_fast(gg1);
            float h20 = sigmf(go0) * tanh_fast(c20);
            float h21 = sigmf(go1) * tanh_fast(c21);
            sh_hc[e] = h20; sh_hc[e + 1] = h21;
            sh_hc[512 + e] = c20; sh_hc[513 + e] = c21;
            half2v hv; hv[0] = (f16)h20; hv[1] = (f16)h21;
            *(half2v*)(enchi + ((size_t)b * TM1 + (t - 1)) * 512 + e) = hv;
        } else {
            for (int j = tid; j < 1024; j += 256) sh_hc[j] = 0.f;
        }
        if (t == TM1) {
            for (int j = tid; j < 512; j += 256) hc_dec[b * 1024 + 512 + j] = 0.f;
            for (int j = tid; j < 1024; j += 256) hdhi[(size_t)b * 1024 + j] = (f16)0.f;
            break;
        }
        __syncthreads();

        if (tid < 248) {
            int s = tid >> 3, l8 = tid & 7;
            const f16* wr = Wcf + s * 1024;
            float p = 0.f;
            for (int j = l8 * 8; j < 1024; j += 64) {
                half8 w8 = *(const half8*)(wr + j);
#pragma unroll
                for (int e2 = 0; e2 < 8; e2++) p += (float)w8[e2] * sh_hc[j + e2];
            }
            p += __shfl_xor(p, 1); p += __shfl_xor(p, 2); p += __shfl_xor(p, 4);
            if (l8 == 0) t1s[s] = p + bc[s];
        }
        __syncthreads();
        {
            int d = tid;
            float sc = ba[0];
            const f16* t2p = t2s + ((size_t)b * TM1) * DIMD + d;
            for (int s = 0; s < TM1; s++) sc += tanh_fast(t1s[s] + (float)t2p[s * DIMD]) * Wa[s];
            float mx = blockReduceMax256(sc, sred);
            float ex = __expf(sc - mx);
            float sm = blockReduceSum256(ex, sred);
            float w = (ex / sm) * inputs[((size_t)b * TM1 + t) * 257 + 1 + d];
            st2cc(Ahi + b * 768 + d, (f16)w);
            int j = tid * 2;
            half2v hv; hv[0] = (f16)sh_hc[j]; hv[1] = (f16)sh_hc[j + 1];
            st4cc(Ahi + b * 768 + 256 + j, __builtin_bit_cast(unsigned, hv));
        }
        sigflag(flags, ENC_A_SLOT(t, atile), b);

        // ===== phase G: g(t) = Ahi @ W^T (tile) =====
        waitflag(flags, ENC_A_SLOT(t, gtile), 64);
        {
            float4 ra[8];
            floatx16 acc = {};
            for (int p = 0; p < 3; ++p) {
                ld8x16cc(pAg + p * 128, ra);
#pragma unroll
                for (int j = 0; j < 8; ++j) {
                    int lg = 2 * j + kq;
                    half8 ah = __builtin_bit_cast(half8, ra[j]);
                    half8 wh = *(const half8*)&sWh[p * 8192 + wrow + ((lg ^ swk) * 8)];
                    acc = __builtin_amdgcn_mfma_f32_32x32x16_f16(ah, wh, acc, 0, 0, 0);
                }
            }
#pragma unroll
            for (int rr = 0; rr < 16; ++rr) {
                int row = m0g + wm * 32 + (rr & 3) + 8 * (rr >> 2) + 4 * kq;
                st2cc(gCp + (size_t)row * 2048 + gcol, (f16)(acc[rr] + gbv));
            }
        }
        sigflag(flags, ENC_G_SLOT(t, gtile), b);
    }
}

// ---------------------------------------------------------------------------
// V GEMM (unchanged).
// ---------------------------------------------------------------------------
__global__ __launch_bounds__(256) void gemm_v(
    const f16* __restrict__ A, int lda,
    const f16* __restrict__ W, int ldw,
    const float* __restrict__ bias, f16* __restrict__ C, int ldc,
    int K, int NT, int MT, int NREP)
{
    __shared__ f16 sAh[64 * 64];
    __shared__ f16 sWh[64 * 64];
    int tid = threadIdx.x, bid = blockIdx.x;
    int nbase = bid % NT;
    int m0 = ((bid / NT) % MT) * 64;
    int lane = tid & 63, wid = tid >> 6;
    int wm = wid >> 1, wn = wid & 1;
    int rl = lane & 31, kq = lane >> 5;
    int sr = tid >> 2;
    int g0 = (tid & 3) * 2;
    int s0 = sr * 64 + ((g0 ^ (sr & 7)) * 8);
    int s1 = sr * 64 + (((g0 + 1) ^ (sr & 7)) * 8);
    int arow = (wm * 32 + rl) * 64;
    int wrow = (wn * 32 + rl) * 64;
    int sw = (rl & 7);

    const f16* pA = A + (size_t)(m0 + sr) * lda + g0 * 8;

    for (int r = 0; r < NREP; ++r) {
        int n0 = (nbase + r * NT) * 64;
        const f16* pW = W + (size_t)(n0 + sr) * ldw + g0 * 8;
        float4 rA0 = *(const float4*)(pA);
        float4 rA1 = *(const float4*)(pA + 8);
        float4 rW0 = *(const float4*)(pW);
        float4 rW1 = *(const float4*)(pW + 8);
        floatx16 acc = {};
        for (int k0 = 0; k0 < K; k0 += 64) {
            __syncthreads();
            *(float4*)&sAh[s0] = rA0; *(float4*)&sAh[s1] = rA1;
            *(float4*)&sWh[s0] = rW0; *(float4*)&sWh[s1] = rW1;
            __syncthreads();
            int kn = k0 + 64;
            if (kn < K) {
                rA0 = *(const float4*)(pA + kn); rA1 = *(const float4*)(pA + kn + 8);
                rW0 = *(const float4*)(pW + kn); rW1 = *(const float4*)(pW + kn + 8);
            }
#pragma unroll
            for (int kk = 0; kk < 64; kk += 16) {
                int lg = (kk >> 3) + kq;
                int off = ((lg ^ sw) * 8);
                half8 ah = *(const half8*)&sAh[arow + off];
                half8 wh = *(const half8*)&sWh[wrow + off];
                acc = __builtin_amdgcn_mfma_f32_32x32x16_f16(ah, wh, acc, 0, 0, 0);
            }
        }
        int col = n0 + wn * 32 + rl;
        float bv = bias[col];
#pragma unroll
        for (int rr = 0; rr < 16; ++rr) {
            int row = m0 + wm * 32 + (rr & 3) + 8 * (rr >> 2) + 4 * kq;
            C[(size_t)row * ldc + col] = (f16)(acc[rr] + bv);
        }
    }
}

// ---------------------------------------------------------------------------
// COOP decoder: per-tile 16-way-spread flags + sc0sc1 data.
// ---------------------------------------------------------------------------
__global__ __launch_bounds__(256, 2) void dec_coop(
    const float* __restrict__ inputs, const f16* __restrict__ V,
    const float* __restrict__ W2, const float* __restrict__ b2,
    const f16* __restrict__ enchi,
    const float* __restrict__ fcW, const float* __restrict__ fcb,
    const float* __restrict__ Wih,
    f16* __restrict__ gu, long long ustride,
    f16* __restrict__ hdhi,
    const float* __restrict__ fcfW, const float* __restrict__ fcfb,
    float* __restrict__ out,
    const f16* __restrict__ dWcf, const float* __restrict__ dbias,
    unsigned* __restrict__ flags)
{
    __shared__ f16 sW[4 * 4096];      // resident W tile (32 KB)
    __shared__ float su[512];
    __shared__ float sw2[512];
    __shared__ float s_c[512];
    __shared__ float s_att[TM1];
    __shared__ float sred[4];
    const int b = blockIdx.x, tid = threadIdx.x;
    const int lane = tid & 63, wid = tid >> 6;
    const int rl = lane & 31, kq = lane >> 5;

    const bool gact = (b < 384);
    int n0g = 0, m0g = 0, kbeg = 0, ksf = 0;
    if (b < 256) {            // gate tiles: K=512 (h only), slice 0
        n0g = 512 + (b & 63) * 32; m0g = (b >> 6) * 128; kbeg = 0; ksf = 0;
    } else if (b < 384) {     // su tiles: 2 ks over K=1024 ([h,c])
        int i = b - 256;
        n0g = (i & 15) * 32; m0g = ((i >> 4) & 3) * 128;
        ksf = i >> 6; kbeg = ksf * 512;
    }
    const int gT = m0g >> 7;          // G-phase m-tile (0..3)
    const int sT = b >> 7;            // S-phase tile of this batch

    if (gact) {
        for (int u = tid; u < 512; u += 256) {
            int r = u >> 4, c = u & 15;
#pragma unroll
            for (int p = 0; p < 4; ++p) {
                *(float4*)&sW[p * 4096 + r * 128 + ((c ^ (r & 15)) * 8)] =
                    *(const float4*)(dWcf + (size_t)(n0g + r) * 1024 + kbeg + p * 128 + c * 8);
            }
        }
    }
    {
        int e = tid * 2;
        sw2[e] = W2[e]; sw2[e + 1] = W2[e + 1];
        s_c[e] = 0.f;  s_c[e + 1] = 0.f;
    }
    __syncthreads();

    const f16* pAg = hdhi + (size_t)(m0g + wid * 32 + rl) * 1024 + kbeg + kq * 8;
    const int gcol = n0g + rl;
    const float gbv = (gact && ksf == 0) ? dbias[gcol] : 0.f;
    f16* gCp = gu + (size_t)ksf * ustride;

    for (int t = 0; t < TM1; ++t) {
        // ===== phase G: gu(t) from hdhi =====
        if (gact) {
            if (t > 0) waitflag(flags, DEC_S_SLOT(t - 1, gT), 128);
            float4 ra[8];
            floatx16 acc = {};
            for (int p = 0; p < 4; ++p) {
                ld8x16cc(pAg + p * 128, ra);
#pragma unroll
                for (int j = 0; j < 8; ++j) {
                    int lg = 2 * j + kq;
                    half8 ah = __builtin_bit_cast(half8, ra[j]);
                    half8 wh = *(const half8*)&sW[p * 4096 + rl * 128 + ((lg ^ (rl & 15)) * 8)];
                    acc = __builtin_amdgcn_mfma_f32_32x32x16_f16(ah, wh, acc, 0, 0, 0);
                }
            }
#pragma unroll
            for (int rr = 0; rr < 16; ++rr) {
                int row = m0g + wid * 32 + (rr & 3) + 8 * (rr >> 2) + 4 * kq;
                st2cc(gCp + (size_t)row * 2560 + gcol, (f16)(acc[rr] + gbv));
            }
            sigflag(flags, DEC_G_SLOT(t, gT), b);
        }

        // ===== phase S: dec_step(t) =====
        waitflag(flags, DEC_G_SLOT(t, sT), 96);
        const bool last = (t == TM1 - 1);
        unsigned ug[6];
        {
            int e = tid * 2;
            const f16* q = gu + (size_t)b * 2560 + e;
            ld_gu6cc(q, q + ustride, ug);
            half2v a0 = __builtin_bit_cast(half2v, ug[0]);
            half2v a1 = __builtin_bit_cast(half2v, ug[1]);
            su[e]     = (float)a0[0] + (float)a1[0];
            su[e + 1] = (float)a0[1] + (float)a1[1];
        }
        __syncthreads();
        if (tid < 248) {
            int tp = tid >> 3, l8 = tid & 7;
            const f16* vrow = V + ((size_t)b * TM1 + tp) * 512;
            float p = 0.f;
            for (int j = l8 * 8; j < 512; j += 64) {
                half8 v8 = *(const half8*)(vrow + j);
#pragma unroll
                for (int e = 0; e < 8; e++)
                    p += tanh_fast(su[j + e] + (float)v8[e]) * sw2[j + e];
            }
            p += __shfl_xor(p, 1); p += __shfl_xor(p, 2); p += __shfl_xor(p, 4);
            if (l8 == 0) s_att[tp] = p + b2[0];
        }
        __syncthreads();
        if (tid < 64) {
            float v = (tid < TM1) ? s_att[tid] : -3.4e38f;
            float m = v;
#pragma unroll
            for (int k = 32; k > 0; k >>= 1) m = fmaxf(m, __shfl_xor(m, k));
            float e = (tid < TM1) ? __expf(v - m) : 0.f;
            float s = e;
#pragma unroll
            for (int k = 32; k > 0; k >>= 1) s += __shfl_xor(s, k);
            if (tid < TM1) s_att[tid] = e / s;
        }
        __syncthreads();

        float part, pctx = 0.f;
        {
            int e = tid * 2;
            float cx0 = 0.f, cx1 = 0.f;
            const f16* eh = enchi + (size_t)b * TM1 * 512 + e;
            for (int tp = 0; tp < TM1; tp++) {
                half2v v2 = *(const half2v*)(eh + tp * 512);
                cx0 += s_att[tp] * (float)v2[0];
                cx1 += s_att[tp] * (float)v2[1];
            }
            float2 fw = *(const float2*)(fcW + e);
            part = cx0 * fw.x + cx1 * fw.y;
            if (last) {
                float2 fw2 = *(const float2*)(fcfW + 512 + e);
                pctx = cx0 * fw2.x + cx1 * fw2.y;
            }
        }
        float y = inputs[((size_t)b * TM1 + t) * 257];
        float ysum = blockReduceSum256(part, sred);
        float y_til = ysum + y * fcW[512] + fcb[0];

        float ph = 0.f;
        {
            int e = tid * 2;
            half2v a = __builtin_bit_cast(half2v, ug[2]);
            half2v f = __builtin_bit_cast(half2v, ug[3]);
            half2v gv = __builtin_bit_cast(half2v, ug[4]);
            half2v o = __builtin_bit_cast(half2v, ug[5]);
            float gi0 = (float)a[0], gi1 = (float)a[1];
            float gf0 = (float)f[0], gf1 = (float)f[1];
            float gg0 = (float)gv[0], gg1 = (float)gv[1];
            float go0 = (float)o[0], go1 = (float)o[1];
            gi0 += y_til * Wih[e];        gi1 += y_til * Wih[e + 1];
            gf0 += y_til * Wih[512 + e];  gf1 += y_til * Wih[512 + e + 1];
            gg0 += y_til * Wih[1024 + e]; gg1 += y_til * Wih[1024 + e + 1];
            go0 += y_til * Wih[1536 + e]; go1 += y_til * Wih[1536 + e + 1];
            float c20 = sigmf(gf0) * s_c[e]     + sigmf(gi0) * tanh_fast(gg0);
            float c21 = sigmf(gf1) * s_c[e + 1] + sigmf(gi1) * tanh_fast(gg1);
            float h20 = sigmf(go0) * tanh_fast(c20);
            float h21 = sigmf(go1) * tanh_fast(c21);
            if (!last) {
                s_c[e] = c20; s_c[e + 1] = c21;
                half2v hv; hv[0] = (f16)h20; hv[1] = (f16)h21;
                half2v cv; cv[0] = (f16)c20; cv[1] = (f16)c21;
                st4cc(hdhi + (size_t)b * 1024 + e, __builtin_bit_cast(unsigned, hv));
                st4cc(hdhi + (size_t)b * 1024 + 512 + e, __builtin_bit_cast(unsigned, cv));
            } else {
                ph += h20 * fcfW[e] + h21 * fcfW[e + 1];
            }
        }
        if (!last) {
            sigflag(flags, DEC_S_SLOT(t, sT), b);
        } else {
            float s = blockReduceSum256(ph + pctx, sred);
            if (tid == 0) out[b] = s + fcfb[0];
        }
    }
}

extern "C" void kernel_launch(void* const* d_in, const int* in_sizes, int n_in,
                              void* d_out, int out_size, void* d_ws, size_t ws_size,
                              hipStream_t stream) {
    const float* inputs  = (const float*)d_in[0];
    const float* eWih    = (const float*)d_in[1];
    const float* eWhh    = (const float*)d_in[2];
    const float* ebih    = (const float*)d_in[3];
    const float* ebhh    = (const float*)d_in[4];
    const float* eWc     = (const float*)d_in[5];
    const float* ebc     = (const float*)d_in[6];
    const float* eWd     = (const float*)d_in[7];
    const float* ebd     = (const float*)d_in[8];
    const float* eWa     = (const float*)d_in[9];
    const float* eba     = (const float*)d_in[10];
    const float* dW1     = (const float*)d_in[11];
    const float* db1     = (const float*)d_in[12];
    const float* dW2     = (const float*)d_in[13];
    const float* db2     = (const float*)d_in[14];
    const float* dWih    = (const float*)d_in[15];
    const float* dWhh    = (const float*)d_in[16];
    const float* dbih    = (const float*)d_in[17];
    const float* dbhh    = (const float*)d_in[18];
    const float* fcW     = (const float*)d_in[19];
    const float* fcb     = (const float*)d_in[20];
    const float* fcfW    = (const float*)d_in[21];
    const float* fcfb    = (const float*)d_in[22];
    float* out = (float*)d_out;

    float* scr = (float*)d_ws;
    f16* t2s = (f16*)scr;                       // 4,063,232 h
    f16* Vf  = (f16*)scr;                       // 8,126,464 h
    f16* g0e = (f16*)(scr + 4063232);           // 2 x 1,048,576 h
    f16* gu0 = (f16*)(scr + 4063232);           // 2 x 1,310,720 h
    // hc_enc hole doubles as the 1 MB flag region (coop never uses hc_enc;
    // fallback never uses flags — prep's zeroing is harmless either way).
    float* hc_enc = scr + 6684672;              //   524,288 f (2 MB hole)
    unsigned* flags = (unsigned*)(scr + 6684672); // 1024 slots x 256 u32 = 1 MB
    f16*   Ahi    = (f16*)(scr + 7208960);      //   393,216 h
    float* hc_dec = scr + 7405568;              //   524,288 f
    f16*   hdhi   = (f16*)(scr + 7929856);      //   524,288 h
    f16* fp = (f16*)(scr + 8192000);
    f16* eWf   = fp;             fp += 1572864;
    f16* dWcf  = fp;             fp += 2621440;
    f16* Vwf   = fp;             fp += 262144;
    f16* enchi = fp;             fp += 8126464;
    float* ebcomb = (float*)(((uintptr_t)fp + 15) & ~(uintptr_t)15);
    float* dbias  = ebcomb + 2048;              // 2560 f
    f16* Wcf = (f16*)(dbias + 2560);            // 31,744 h

    hipLaunchKernelGGL(prep_t2s_kernel, dim3(2048), dim3(256), 0, stream,
                       inputs, eWih, eWhh, ebih, ebhh, dW1, dWhh, dbih, dbhh,
                       eWd, ebd, eWc, eWf, dWcf, Vwf,
                       ebcomb, dbias, t2s, Wcf, flags);

    long long gstride = 1048576;   // halves per g slice
    long long ustride = 1310720;   // halves per gu slice

    // -------- encoder: cooperative; fall back to per-step on launch error --
    bool enc_ok = false;
    {
        void* a[] = {(void*)&inputs, (void*)&t2s, (void*)&Wcf, (void*)&ebc,
                     (void*)&eWa, (void*)&eba, (void*)&g0e, (void*)&gstride,
                     (void*)&Ahi, (void*)&enchi, (void*)&hc_dec, (void*)&hdhi,
                     (void*)&eWf, (void*)&ebcomb, (void*)&flags};
        enc_ok = (hipLaunchCooperativeKernel((const void*)enc_coop, dim3(512),
                                             dim3(256), a, 0, stream) == hipSuccess);
    }
    if (!enc_ok) {
        for (int t = 0; t < TM1; t++) {
            hipLaunchKernelGGL(enc_step_kernel, dim3(BATCH), dim3(256), 0, stream,
                               inputs, t2s, Wcf, ebc, eWa, eba, g0e, gstride, hc_enc,
                               Ahi, enchi, hc_dec, hdhi, t);
            hipLaunchKernelGGL(gemm1f, dim3(512), dim3(256), 0, stream,
                               Ahi, 768, eWf, 768, ebcomb,
                               g0e, 2048, gstride, 768, 1 << 30, 32, 8, 2);
        }
        hipLaunchKernelGGL(enc_step_kernel, dim3(BATCH), dim3(256), 0, stream,
                           inputs, t2s, Wcf, ebc, eWa, eba, g0e, gstride, hc_enc,
                           Ahi, enchi, hc_dec, hdhi, TM1);
    }

    // -------- V = enc_out @ dec_W1[:,1024:]^T + b1 (f16 out) --------
    hipLaunchKernelGGL(gemm_v, dim3(992), dim3(256), 0, stream,
                       enchi, 512, Vwf, 512, db1,
                       Vf, 512, 512, 4, 248, 2);

    // -------- decoder: cooperative; fall back to per-step on launch error --
    bool dec_ok = false;
    {
        void* a[] = {(void*)&inputs, (void*)&Vf, (void*)&dW2, (void*)&db2,
                     (void*)&enchi, (void*)&fcW, (void*)&fcb, (void*)&dWih,
                     (void*)&gu0, (void*)&ustride, (void*)&hdhi,
                     (void*)&fcfW, (void*)&fcfb, (void*)&out,
                     (void*)&dWcf, (void*)&dbias, (void*)&flags};
        dec_ok = (hipLaunchCooperativeKernel((const void*)dec_coop, dim3(512),
                                             dim3(256), a, 0, stream) == hipSuccess);
    }
    if (!dec_ok) {
        for (int t = 0; t < TM1; t++) {
            hipLaunchKernelGGL(gemm1f, dim3(640), dim3(256), 0, stream,
                               hdhi, 1024, dWcf, 1024, dbias,
                               gu0, 2560, ustride, 1024, 512, 40, 8, 2);
            hipLaunchKernelGGL(dec_step_kernel, dim3(BATCH), dim3(256), 0, stream,
                               inputs, Vf, dW2, db2, enchi, fcW, fcb, dWih,
                               gu0, ustride, hc_dec, hdhi, fcfW, fcfb, out, t);
        }
    }
}

// Round 8
// 1822.360 us; speedup vs baseline: 9.6702x; 1.1468x over previous
//
#include <hip/hip_runtime.h>
#include <math.h>

#define BATCH 512
#define TM1   31
#define DIMD  256

typedef _Float16 f16;
typedef _Float16 half2v __attribute__((ext_vector_type(2)));
typedef _Float16 half8 __attribute__((ext_vector_type(8)));
typedef float floatx16 __attribute__((ext_vector_type(16)));

__device__ __forceinline__ float sigmf(float x) { return 1.f / (1.f + __expf(-x)); }

__device__ __forceinline__ float tanh_fast(float x) {
    float ax = fabsf(x);
    float t  = __expf(-2.f * ax);
    float r  = (1.f - t) / (1.f + t);
    return copysignf(r, x);
}

__device__ __forceinline__ float blockReduceSum256(float v, float* sred) {
#pragma unroll
    for (int m = 32; m > 0; m >>= 1) v += __shfl_xor(v, m);
    __syncthreads();
    if ((threadIdx.x & 63) == 0) sred[threadIdx.x >> 6] = v;
    __syncthreads();
    return sred[0] + sred[1] + sred[2] + sred[3];
}

__device__ __forceinline__ float blockReduceMax256(float v, float* sred) {
#pragma unroll
    for (int m = 32; m > 0; m >>= 1) v = fmaxf(v, __shfl_xor(v, m));
    __syncthreads();
    if ((threadIdx.x & 63) == 0) sred[threadIdx.x >> 6] = v;
    __syncthreads();
    return fmaxf(fmaxf(sred[0], sred[1]), fmaxf(sred[2], sred[3]));
}

// ---------------------------------------------------------------------------
// Coherence-point (sc0 sc1) access helpers: write-through to IF$, loads
// bypass stale per-XCD L2. No cache-maintenance ops needed anywhere.
// ---------------------------------------------------------------------------
__device__ __forceinline__ void st2cc(f16* p, f16 v) {
    unsigned u = (unsigned)__builtin_bit_cast(unsigned short, v);
    asm volatile("global_store_short %0, %1, off sc0 sc1" :: "v"(p), "v"(u) : "memory");
}
__device__ __forceinline__ void st4cc(void* p, unsigned v) {
    asm volatile("global_store_dword %0, %1, off sc0 sc1" :: "v"(p), "v"(v) : "memory");
}
__device__ __forceinline__ unsigned ld4cc(const unsigned* p) {
    unsigned v;
    asm volatile("global_load_dword %0, %1, off sc0 sc1\n\ts_waitcnt vmcnt(0)"
                 : "=v"(v) : "v"(p) : "memory");
    return v;
}
// 8 x 16B contiguous-stride (32B apart) loads, one waitcnt.
__device__ __forceinline__ void ld8x16cc(const f16* base, float4* r) {
    asm volatile(
        "global_load_dwordx4 %0, %8, off sc0 sc1\n\t"
        "global_load_dwordx4 %1, %8, off offset:32 sc0 sc1\n\t"
        "global_load_dwordx4 %2, %8, off offset:64 sc0 sc1\n\t"
        "global_load_dwordx4 %3, %8, off offset:96 sc0 sc1\n\t"
        "global_load_dwordx4 %4, %8, off offset:128 sc0 sc1\n\t"
        "global_load_dwordx4 %5, %8, off offset:160 sc0 sc1\n\t"
        "global_load_dwordx4 %6, %8, off offset:192 sc0 sc1\n\t"
        "global_load_dwordx4 %7, %8, off offset:224 sc0 sc1\n\t"
        "s_waitcnt vmcnt(0)"
        : "=&v"(r[0]), "=&v"(r[1]), "=&v"(r[2]), "=&v"(r[3]),
          "=&v"(r[4]), "=&v"(r[5]), "=&v"(r[6]), "=&v"(r[7])
        : "v"(base) : "memory");
}
// enc A-phase: 8 x 4B gate loads from two slices.
__device__ __forceinline__ void ld_g8cc(const f16* q0, const f16* q1, unsigned* u) {
    asm volatile(
        "global_load_dword %0, %8, off sc0 sc1\n\t"
        "global_load_dword %1, %8, off offset:1024 sc0 sc1\n\t"
        "global_load_dword %2, %8, off offset:2048 sc0 sc1\n\t"
        "global_load_dword %3, %8, off offset:3072 sc0 sc1\n\t"
        "global_load_dword %4, %9, off sc0 sc1\n\t"
        "global_load_dword %5, %9, off offset:1024 sc0 sc1\n\t"
        "global_load_dword %6, %9, off offset:2048 sc0 sc1\n\t"
        "global_load_dword %7, %9, off offset:3072 sc0 sc1\n\t"
        "s_waitcnt vmcnt(0)"
        : "=&v"(u[0]), "=&v"(u[1]), "=&v"(u[2]), "=&v"(u[3]),
          "=&v"(u[4]), "=&v"(u[5]), "=&v"(u[6]), "=&v"(u[7])
        : "v"(q0), "v"(q1) : "memory");
}
// dec S-phase: su (2 slices) + 4 gates (slice 0), 6 x 4B.
__device__ __forceinline__ void ld_gu6cc(const f16* q, const f16* q1, unsigned* u) {
    const f16* qo = q + 2048;
    asm volatile(
        "global_load_dword %0, %6, off sc0 sc1\n\t"
        "global_load_dword %1, %7, off sc0 sc1\n\t"
        "global_load_dword %2, %6, off offset:1024 sc0 sc1\n\t"
        "global_load_dword %3, %6, off offset:2048 sc0 sc1\n\t"
        "global_load_dword %4, %6, off offset:3072 sc0 sc1\n\t"
        "global_load_dword %5, %8, off sc0 sc1\n\t"
        "s_waitcnt vmcnt(0)"
        : "=&v"(u[0]), "=&v"(u[1]), "=&v"(u[2]), "=&v"(u[3]), "=&v"(u[4]), "=&v"(u[5])
        : "v"(q), "v"(q1), "v"(qo) : "memory");
}

// ---------------------------------------------------------------------------
// R25 sync: per-producer done-words, zero RMWs, all signal/poll traffic on the
// PROVEN sc0sc1 inline-asm path (same instruction class as the data plane,
// validated R20/R22). Signal = plain sc0sc1 store of monotonic step number.
// Waiter = wave 0, lane l polls producer l in parallel, __all(v >= tgt).
// Spin bound 2^12: a liveness bug fails FAST (wrong answer + data), no hang.
// Region layout (entries, each 16 u32 = 64B):
//   EA  = 0    : 8 tiles x 64 producers   (enc A-phase)
//   EG  = 512  : 8 tiles x 64 producers   (enc G-phase)
//   DG  = 1024 : 4 tiles x 96 producers   (dec G-phase)
//   DS  = 1408 : 4 tiles x 128 producers  (dec S-phase)
// Total 1920 entries = 120 KB (lives in the hc_enc hole).
// ---------------------------------------------------------------------------
#define EA_BASE 0
#define EG_BASE 512
#define DG_BASE 1024
#define DS_BASE 1408

__device__ __forceinline__ void sigdone(unsigned* d, int entry, unsigned val) {
    asm volatile("s_waitcnt vmcnt(0)" ::: "memory");
    __syncthreads();
    if (threadIdx.x == 0)
        st4cc(d + (size_t)entry * 16, val);
}
// wait for n producers (n <= 128) at entries [base, base+n)
__device__ __forceinline__ void waitdone(unsigned* d, int base, int n, unsigned tgt) {
    if (threadIdx.x < 64) {
        int l = threadIdx.x;
        const unsigned* p0 = d + (size_t)(base + l) * 16;
        const unsigned* p1 = d + (size_t)(base + 64 + l) * 16;
        const bool one = l < n;
        const bool two = (64 + l) < n;
        for (int it = 0; it < (1 << 12); ++it) {
            unsigned v0 = one ? ld4cc(p0) : tgt;
            unsigned v1 = two ? ld4cc(p1) : tgt;
            if (__all(v0 >= tgt && v1 >= tgt)) break;
            __builtin_amdgcn_s_sleep(1);
        }
    }
    __syncthreads();
    __builtin_amdgcn_sched_barrier(0);
}

// ---------------------------------------------------------------------------
// prep + t2s fused (+ done-word zeroing).
// ---------------------------------------------------------------------------
__global__ __launch_bounds__(256) void prep_t2s_kernel(
    const float* __restrict__ inputs,
    const float* __restrict__ eWih, const float* __restrict__ eWhh,
    const float* __restrict__ ebih, const float* __restrict__ ebhh,
    const float* __restrict__ dW1,  const float* __restrict__ dWhh,
    const float* __restrict__ dbih, const float* __restrict__ dbhh,
    const float* __restrict__ Wd,   const float* __restrict__ bd,
    const float* __restrict__ Wc,
    f16* __restrict__ eWf, f16* __restrict__ dWcf, f16* __restrict__ Vwf,
    float* __restrict__ ebcomb, float* __restrict__ dbias,
    f16* __restrict__ t2s, f16* __restrict__ Wcf,
    unsigned* __restrict__ flags)
{
    __shared__ float sX[TM1 * DIMD];
    __shared__ float sWd[TM1 * TM1];
    int b = blockIdx.x, tid = threadIdx.x;
    int idx = b * 256 + tid;
    const int stride = gridDim.x * 256;

    if (b < 512) {
        for (int i = tid; i < TM1 * DIMD; i += 256) {
            int tt = i >> 8, d = i & 255;
            sX[i] = inputs[((size_t)b * TM1 + tt) * 257 + 1 + d];
        }
        for (int i = tid; i < TM1 * TM1; i += 256) sWd[i] = Wd[i];
        __syncthreads();
        int d = tid;
        for (int s = 0; s < TM1; s++) {
            float acc = bd[s];
            for (int tt = 0; tt < TM1; tt++) acc += sX[tt * DIMD + d] * sWd[s * TM1 + tt];
            t2s[((size_t)b * TM1 + s) * DIMD + d] = (f16)acc;
        }
    }

    for (int g = idx; g < 2048 * 96; g += stride) {
        int n = g / 96, k0 = (g % 96) * 8;
        const float* src = (k0 < 256) ? (eWih + n * 256 + k0)
                                      : (eWhh + n * 512 + (k0 - 256));
        float4 v0 = *(const float4*)src;
        float4 v1 = *(const float4*)(src + 4);
        f16 h[8] = {(f16)v0.x, (f16)v0.y, (f16)v0.z, (f16)v0.w,
                    (f16)v1.x, (f16)v1.y, (f16)v1.z, (f16)v1.w};
        *(half8*)(eWf + n * 768 + k0) = *(half8*)h;
    }
    for (int g = idx; g < 2560 * 128; g += stride) {
        int n = g >> 7, k0 = (g & 127) * 8;
        float vv[8] = {};
        if (n < 512) {
            const float* src = dW1 + n * 1536 + k0;
            float4 v0 = *(const float4*)src, v1 = *(const float4*)(src + 4);
            vv[0]=v0.x; vv[1]=v0.y; vv[2]=v0.z; vv[3]=v0.w;
            vv[4]=v1.x; vv[5]=v1.y; vv[6]=v1.z; vv[7]=v1.w;
        } else if (k0 < 512) {
            const float* src = dWhh + (n - 512) * 512 + k0;
            float4 v0 = *(const float4*)src, v1 = *(const float4*)(src + 4);
            vv[0]=v0.x; vv[1]=v0.y; vv[2]=v0.z; vv[3]=v0.w;
            vv[4]=v1.x; vv[5]=v1.y; vv[6]=v1.z; vv[7]=v1.w;
        }
        f16 h[8];
#pragma unroll
        for (int e = 0; e < 8; e++) h[e] = (f16)vv[e];
        *(half8*)(dWcf + n * 1024 + k0) = *(half8*)h;
    }
    for (int g = idx; g < 512 * 64; g += stride) {
        int n = g >> 6, k0 = (g & 63) * 8;
        const float* src = dW1 + n * 1536 + 1024 + k0;
        float4 v0 = *(const float4*)src, v1 = *(const float4*)(src + 4);
        f16 h[8] = {(f16)v0.x, (f16)v0.y, (f16)v0.z, (f16)v0.w,
                    (f16)v1.x, (f16)v1.y, (f16)v1.z, (f16)v1.w};
        *(half8*)(Vwf + n * 512 + k0) = *(half8*)h;
    }
    for (int g = idx; g < 3968; g += stride) {
        int k0 = g * 8;
        float4 v0 = *(const float4*)(Wc + k0);
        float4 v1 = *(const float4*)(Wc + k0 + 4);
        f16 h[8] = {(f16)v0.x, (f16)v0.y, (f16)v0.z, (f16)v0.w,
                    (f16)v1.x, (f16)v1.y, (f16)v1.z, (f16)v1.w};
        *(half8*)(Wcf + k0) = *(half8*)h;
    }
    for (int i = idx; i < 2048; i += stride) ebcomb[i] = ebih[i] + ebhh[i];
    for (int i = idx; i < 2560; i += stride)
        dbias[i] = (i < 512) ? 0.f : (dbih[i - 512] + dbhh[i - 512]);
    for (int i = idx; i < 1920 * 16; i += stride) flags[i] = 0u;
}

// ---------------------------------------------------------------------------
// FALLBACK: step GEMM (R14-validated).
// ---------------------------------------------------------------------------
__global__ __launch_bounds__(256) void gemm1f(
    const f16* __restrict__ A, int lda,
    const f16* __restrict__ W, int ldw,
    const float* __restrict__ bias, f16* __restrict__ C, int ldc,
    long long Cstride, int K, int nsplit, int NT, int MT, int KS)
{
    __shared__ f16 sAh[64 * 128];
    __shared__ f16 sWh[64 * 128];
    int tid = threadIdx.x, bid = blockIdx.x;
    int nbase = bid % NT;
    int m0 = ((bid / NT) % MT) * 64;
    int ks = bid / (NT * MT);
    int lane = tid & 63, wid = tid >> 6;
    int wm = wid >> 1, wn = wid & 1;
    int rl = lane & 31, kq = lane >> 5;

    int sr = tid >> 2;
    int gb = (tid & 3) * 4;
    int st0 = sr * 128 + (((gb + 0) ^ (sr & 15)) * 8);
    int st1 = sr * 128 + (((gb + 1) ^ (sr & 15)) * 8);
    int st2 = sr * 128 + (((gb + 2) ^ (sr & 15)) * 8);
    int st3 = sr * 128 + (((gb + 3) ^ (sr & 15)) * 8);
    int arow = (wm * 32 + rl) * 128;
    int wrow = (wn * 32 + rl) * 128;
    int swk = rl & 15;

    int n0 = nbase * 64;
    int Kfull = (n0 >= nsplit) ? 512 : K;
    int ksz = Kfull / KS;
    int kbeg = ks * ksz, kend = kbeg + ksz;

    const f16* pA = A + (size_t)(m0 + sr) * lda + gb * 8;
    const f16* pW = W + (size_t)(n0 + sr) * ldw + gb * 8;

    float4 rA0 = *(const float4*)(pA + kbeg);
    float4 rA1 = *(const float4*)(pA + kbeg + 8);
    float4 rA2 = *(const float4*)(pA + kbeg + 16);
    float4 rA3 = *(const float4*)(pA + kbeg + 24);
    float4 rW0 = *(const float4*)(pW + kbeg);
    float4 rW1 = *(const float4*)(pW + kbeg + 8);
    float4 rW2 = *(const float4*)(pW + kbeg + 16);
    float4 rW3 = *(const float4*)(pW + kbeg + 24);

    floatx16 acc = {};
    for (int k0 = kbeg; k0 < kend; k0 += 128) {
        __syncthreads();
        *(float4*)&sAh[st0] = rA0; *(float4*)&sAh[st1] = rA1;
        *(float4*)&sAh[st2] = rA2; *(float4*)&sAh[st3] = rA3;
        *(float4*)&sWh[st0] = rW0; *(float4*)&sWh[st1] = rW1;
        *(float4*)&sWh[st2] = rW2; *(float4*)&sWh[st3] = rW3;
        __syncthreads();
        int kn = k0 + 128;
        if (kn < kend) {
            rA0 = *(const float4*)(pA + kn);      rA1 = *(const float4*)(pA + kn + 8);
            rA2 = *(const float4*)(pA + kn + 16); rA3 = *(const float4*)(pA + kn + 24);
            rW0 = *(const float4*)(pW + kn);      rW1 = *(const float4*)(pW + kn + 8);
            rW2 = *(const float4*)(pW + kn + 16); rW3 = *(const float4*)(pW + kn + 24);
        }
#pragma unroll
        for (int kk = 0; kk < 128; kk += 16) {
            int lg = (kk >> 3) + kq;
            half8 ah = *(const half8*)&sAh[arow + ((lg ^ swk) * 8)];
            half8 wh = *(const half8*)&sWh[wrow + ((lg ^ swk) * 8)];
            acc = __builtin_amdgcn_mfma_f32_32x32x16_f16(ah, wh, acc, 0, 0, 0);
        }
    }

    int col = n0 + wn * 32 + rl;
    float bv = (ks == 0) ? bias[col] : 0.f;
    f16* Cp = C + (size_t)ks * Cstride;
#pragma unroll
    for (int rr = 0; rr < 16; ++rr) {
        int row = m0 + wm * 32 + (rr & 3) + 8 * (rr >> 2) + 4 * kq;
        Cp[(size_t)row * ldc + col] = (f16)(acc[rr] + bv);
    }
}

// ---------------------------------------------------------------------------
// FALLBACK: encoder step (R14-validated).
// ---------------------------------------------------------------------------
__global__ __launch_bounds__(256) void enc_step_kernel(
    const float* __restrict__ inputs, const f16* __restrict__ t2s,
    const f16* __restrict__ Wcf, const float* __restrict__ bc,
    const float* __restrict__ Wa, const float* __restrict__ ba,
    const f16* __restrict__ g, long long gstride,
    float* __restrict__ hc,
    f16* __restrict__ Ahi, f16* __restrict__ enchi,
    float* __restrict__ hc_dec, f16* __restrict__ hdhi,
    int t) {
    __shared__ float sh_hc[1024];
    __shared__ float t1s[32];
    __shared__ float sred[4];
    int b = blockIdx.x, tid = threadIdx.x;

    if (t > 0) {
        int e = tid * 2;
        const f16* gp = g + (size_t)b * 2048 + e;
        float gi0 = 0.f, gi1 = 0.f, gf0 = 0.f, gf1 = 0.f;
        float gg0 = 0.f, gg1 = 0.f, go0 = 0.f, go1 = 0.f;
#pragma unroll
        for (int s = 0; s < 2; s++) {
            const f16* q = gp + s * gstride;
            half2v a = *(const half2v*)(q);
            half2v f = *(const half2v*)(q + 512);
            half2v gv = *(const half2v*)(q + 1024);
            half2v o = *(const half2v*)(q + 1536);
            gi0 += (float)a[0]; gi1 += (float)a[1];
            gf0 += (float)f[0]; gf1 += (float)f[1];
            gg0 += (float)gv[0]; gg1 += (float)gv[1];
            go0 += (float)o[0]; go1 += (float)o[1];
        }
        float2 cpv = *(const float2*)(hc + b * 1024 + 512 + e);
        float c20 = sigmf(gf0) * cpv.x + sigmf(gi0) * tanh_fast(gg0);
        float c21 = sigmf(gf1) * cpv.y + sigmf(gi1) * tanh_fast(gg1);
        float h20 = sigmf(go0) * tanh_fast(c20);
        float h21 = sigmf(go1) * tanh_fast(c21);
        *(float2*)(hc + b * 1024 + 512 + e) = make_float2(c20, c21);
        sh_hc[e] = h20; sh_hc[e + 1] = h21;
        sh_hc[512 + e] = c20; sh_hc[512 + e + 1] = c21;
        half2v hv; hv[0] = (f16)h20; hv[1] = (f16)h21;
        *(half2v*)(enchi + ((size_t)b * TM1 + (t - 1)) * 512 + e) = hv;
    } else {
        for (int j = tid; j < 1024; j += 256) { sh_hc[j] = 0.f; }
        for (int j = tid; j < 512; j += 256) hc[b * 1024 + 512 + j] = 0.f;
    }
    if (t == TM1) {
        for (int j = tid; j < 512; j += 256) hc_dec[b * 1024 + 512 + j] = 0.f;
        for (int j = tid; j < 1024; j += 256) hdhi[b * 1024 + j] = (f16)0.f;
        return;
    }
    __syncthreads();

    if (tid < 248) {
        int s = tid >> 3, l8 = tid & 7;
        const f16* wrow = Wcf + s * 1024;
        float p = 0.f;
        for (int j = l8 * 8; j < 1024; j += 64) {
            half8 w8 = *(const half8*)(wrow + j);
#pragma unroll
            for (int e = 0; e < 8; e++) p += (float)w8[e] * sh_hc[j + e];
        }
        p += __shfl_xor(p, 1); p += __shfl_xor(p, 2); p += __shfl_xor(p, 4);
        if (l8 == 0) t1s[s] = p + bc[s];
    }
    __syncthreads();

    int d = tid;
    float sc = ba[0];
    const f16* t2p = t2s + ((size_t)b * TM1) * DIMD + d;
    for (int s = 0; s < TM1; s++) sc += tanh_fast(t1s[s] + (float)t2p[s * DIMD]) * Wa[s];
    float mx = blockReduceMax256(sc, sred);
    float ex = __expf(sc - mx);
    float sm = blockReduceSum256(ex, sred);
    float w = (ex / sm) * inputs[((size_t)b * TM1 + t) * 257 + 1 + d];
    Ahi[b * 768 + d] = (f16)w;
    {
        int j = tid * 2;
        half2v hv; hv[0] = (f16)sh_hc[j]; hv[1] = (f16)sh_hc[j + 1];
        *(half2v*)(Ahi + b * 768 + 256 + j) = hv;
    }
}

// ---------------------------------------------------------------------------
// FALLBACK: decoder step (R14-validated).
// ---------------------------------------------------------------------------
__global__ __launch_bounds__(256) void dec_step_kernel(
    const float* __restrict__ inputs, const f16* __restrict__ V,
    const float* __restrict__ W2, const float* __restrict__ b2,
    const f16* __restrict__ enchi,
    const float* __restrict__ fcW, const float* __restrict__ fcb,
    const float* __restrict__ Wih,
    const f16* __restrict__ gu, long long ustride,
    float* __restrict__ hc, f16* __restrict__ hdhi,
    const float* __restrict__ fcfW, const float* __restrict__ fcfb,
    float* __restrict__ out, int t) {
    __shared__ float su[512];
    __shared__ float sw2[512];
    __shared__ float s_att[TM1];
    __shared__ float sred[4];
    int b = blockIdx.x, tid = threadIdx.x;
    const bool last = (t == TM1 - 1);
    {
        int e = tid * 2;
        const f16* q = gu + (size_t)b * 2560 + e;
        half2v a0 = *(const half2v*)(q);
        half2v a1 = *(const half2v*)(q + ustride);
        su[e]     = (float)a0[0] + (float)a1[0];
        su[e + 1] = (float)a0[1] + (float)a1[1];
        sw2[e] = W2[e]; sw2[e + 1] = W2[e + 1];
    }
    __syncthreads();
    if (tid < 248) {
        int tp = tid >> 3, l8 = tid & 7;
        const f16* vrow = V + ((size_t)b * TM1 + tp) * 512;
        float p = 0.f;
        for (int j = l8 * 8; j < 512; j += 64) {
            half8 v8 = *(const half8*)(vrow + j);
#pragma unroll
            for (int e = 0; e < 8; e++)
                p += tanh_fast(su[j + e] + (float)v8[e]) * sw2[j + e];
        }
        p += __shfl_xor(p, 1); p += __shfl_xor(p, 2); p += __shfl_xor(p, 4);
        if (l8 == 0) s_att[tp] = p + b2[0];
    }
    __syncthreads();
    if (tid < 64) {
        float v = (tid < TM1) ? s_att[tid] : -3.4e38f;
        float m = v;
#pragma unroll
        for (int k = 32; k > 0; k >>= 1) m = fmaxf(m, __shfl_xor(m, k));
        float e = (tid < TM1) ? __expf(v - m) : 0.f;
        float s = e;
#pragma unroll
        for (int k = 32; k > 0; k >>= 1) s += __shfl_xor(s, k);
        if (tid < TM1) s_att[tid] = e / s;
    }
    __syncthreads();

    float part, pctx = 0.f;
    {
        int e = tid * 2;
        float cx0 = 0.f, cx1 = 0.f;
        const f16* eh = enchi + (size_t)b * TM1 * 512 + e;
        for (int tp = 0; tp < TM1; tp++) {
            half2v v2 = *(const half2v*)(eh + tp * 512);
            cx0 += s_att[tp] * (float)v2[0];
            cx1 += s_att[tp] * (float)v2[1];
        }
        float2 fw = *(const float2*)(fcW + e);
        part = cx0 * fw.x + cx1 * fw.y;
        if (last) {
            float2 fw2 = *(const float2*)(fcfW + 512 + e);
            pctx = cx0 * fw2.x + cx1 * fw2.y;
        }
    }
    float y = inputs[((size_t)b * TM1 + t) * 257];
    float ysum = blockReduceSum256(part, sred);
    float y_til = ysum + y * fcW[512] + fcb[0];

    float ph = 0.f;
    {
        int e = tid * 2;
        const f16* q = gu + (size_t)b * 2560 + e;
        float gi0 = 0.f, gi1 = 0.f, gf0 = 0.f, gf1 = 0.f;
        float gg0 = 0.f, gg1 = 0.f, go0 = 0.f, go1 = 0.f;
#pragma unroll
        for (int s = 0; s < 2; s++) {
            const f16* qq = q + s * ustride;
            half2v a = *(const half2v*)(qq + 512);
            half2v f = *(const half2v*)(qq + 1024);
            half2v gv = *(const half2v*)(qq + 1536);
            half2v o = *(const half2v*)(qq + 2048);
            gi0 += (float)a[0]; gi1 += (float)a[1];
            gf0 += (float)f[0]; gf1 += (float)f[1];
            gg0 += (float)gv[0]; gg1 += (float)gv[1];
            go0 += (float)o[0]; go1 += (float)o[1];
        }
        gi0 += y_til * Wih[e];        gi1 += y_til * Wih[e + 1];
        gf0 += y_til * Wih[512 + e];  gf1 += y_til * Wih[512 + e + 1];
        gg0 += y_til * Wih[1024 + e]; gg1 += y_til * Wih[1024 + e + 1];
        go0 += y_til * Wih[1536 + e]; go1 += y_til * Wih[1536 + e + 1];
        float2 cpv = *(const float2*)(hc + b * 1024 + 512 + e);
        float c20 = sigmf(gf0) * cpv.x + sigmf(gi0) * tanh_fast(gg0);
        float c21 = sigmf(gf1) * cpv.y + sigmf(gi1) * tanh_fast(gg1);
        float h20 = sigmf(go0) * tanh_fast(c20);
        float h21 = sigmf(go1) * tanh_fast(c21);
        if (!last) {
            *(float2*)(hc + b * 1024 + 512 + e) = make_float2(c20, c21);
            half2v hv; hv[0] = (f16)h20; hv[1] = (f16)h21;
            half2v cv; cv[0] = (f16)c20; cv[1] = (f16)c21;
            *(half2v*)(hdhi + (size_t)b * 1024 + e) = hv;
            *(half2v*)(hdhi + (size_t)b * 1024 + 512 + e) = cv;
        } else {
            ph += h20 * fcfW[e] + h21 * fcfW[e + 1];
        }
    }
    if (last) {
        float s = blockReduceSum256(ph + pctx, sred);
        if (tid == 0) out[b] = s + fcfb[0];
    }
}

// ---------------------------------------------------------------------------
// COOP encoder: per-producer done-words + sc0sc1 data.
// ---------------------------------------------------------------------------
__global__ __launch_bounds__(256, 2) void enc_coop(
    const float* __restrict__ inputs, const f16* __restrict__ t2s,
    const f16* __restrict__ Wcf, const float* __restrict__ bc,
    const float* __restrict__ Wa, const float* __restrict__ ba,
    f16* __restrict__ g, long long gstride,
    f16* __restrict__ Ahi, f16* __restrict__ enchi,
    float* __restrict__ hc_dec, f16* __restrict__ hdhi,
    const f16* __restrict__ eWf, const float* __restrict__ ebcomb,
    unsigned* __restrict__ flags)
{
    __shared__ f16 sWh[3 * 8192];      // resident W tile (48 KB)
    __shared__ float sh_hc[1024];
    __shared__ float t1s[32];
    __shared__ float sred[4];
    const int b = blockIdx.x, tid = threadIdx.x;

    const int lane = tid & 63, wid = tid >> 6;
    const int wm = wid >> 1, wn = wid & 1;
    const int rl = lane & 31, kq = lane >> 5;
    const int sr = tid >> 2;
    const int gb = (tid & 3) * 4;
    const int st0 = sr * 128 + (((gb + 0) ^ (sr & 15)) * 8);
    const int st1 = sr * 128 + (((gb + 1) ^ (sr & 15)) * 8);
    const int st2_ = sr * 128 + (((gb + 2) ^ (sr & 15)) * 8);
    const int st3 = sr * 128 + (((gb + 3) ^ (sr & 15)) * 8);
    const int n0g = (b & 31) * 64;
    const int m0g = ((b >> 5) & 7) * 64;
    const int ksg = b >> 8;
    const int kbeg = ksg * 384;
    const int wrow = (wn * 32 + rl) * 128;
    const int swk = rl & 15;
    const int atile = b >> 6;                       // tile of this block's batch row
    const int gtile = (b >> 5) & 7;                 // m-tile this block computes in G
    const int gidx  = (b & 31) | (ksg << 5);        // producer index within G tile
    const f16* pW  = eWf + (size_t)(n0g + sr) * 768 + gb * 8;
    const f16* pAg = Ahi + (size_t)(m0g + wm * 32 + rl) * 768 + kbeg + kq * 8;
    const int gcol = n0g + wn * 32 + rl;
    const float gbv = (ksg == 0) ? ebcomb[gcol] : 0.f;
    f16* gCp = g + (size_t)ksg * gstride;

    // one-time resident W preload (normal loads; written by prep cross-kernel)
#pragma unroll
    for (int p = 0; p < 3; ++p) {
        *(float4*)&sWh[p * 8192 + st0]  = *(const float4*)(pW + kbeg + p * 128);
        *(float4*)&sWh[p * 8192 + st1]  = *(const float4*)(pW + kbeg + p * 128 + 8);
        *(float4*)&sWh[p * 8192 + st2_] = *(const float4*)(pW + kbeg + p * 128 + 16);
        *(float4*)&sWh[p * 8192 + st3]  = *(const float4*)(pW + kbeg + p * 128 + 24);
    }
    __syncthreads();

    for (int t = 0; t <= TM1; ++t) {
        // ===== phase A: finalize LSTM(t-1) + attention(t) =====
        if (t > 0) {
            // wait G(t-1) of the tile covering this batch row (wrote value t)
            waitdone(flags, EG_BASE + atile * 64, 64, (unsigned)t);
            int e = tid * 2;
            unsigned u[8];
            const f16* q0 = g + (size_t)b * 2048 + e;
            ld_g8cc(q0, q0 + gstride, u);
            half2v a0 = __builtin_bit_cast(half2v, u[0]), a1 = __builtin_bit_cast(half2v, u[4]);
            half2v f0 = __builtin_bit_cast(half2v, u[1]), f1 = __builtin_bit_cast(half2v, u[5]);
            half2v g0 = __builtin_bit_cast(half2v, u[2]), g1 = __builtin_bit_cast(half2v, u[6]);
            half2v o0 = __builtin_bit_cast(half2v, u[3]), o1 = __builtin_bit_cast(half2v, u[7]);
            float gi0 = (float)a0[0] + (float)a1[0], gi1 = (float)a0[1] + (float)a1[1];
            float gf0 = (float)f0[0] + (float)f1[0], gf1 = (float)f0[1] + (float)f1[1];
            float gg0 = (float)g0[0] + (float)g1[0], gg1 = (float)g0[1] + (float)g1[1];
            float go0 = (float)o0[0] + (float)o1[0], go1 = (float)o0[1] + (float)o1[1];
            float c0 = sh_hc[512 + e], c1 = sh_hc[513 + e];
            float c20 = sigmf(gf0) * c0 + sigmf(gi0) * tanh_fast(gg0);
            float c21 = sigmf(gf1) * c1 + sigmf(gi1) * tanh_fast(gg1);
            float h20 = sigmf(go0) * tanh_fast(c20);
            float h21 = sigmf(go1) * tanh_fast(c21);
            sh_hc[e] = h20; sh_hc[e + 1] = h21;
            sh_hc[512 + e] = c20; sh_hc[513 + e] = c21;
            half2v hv; hv[0] = (f16)h20; hv[1] = (f16)h21;
            *(half2v*)(enchi + ((size_t)b * TM1 + (t - 1)) * 512 + e) = hv;
        } else {
            for (int j = tid; j < 1024; j += 256) sh_hc[j] = 0.f;
        }
        if (t == TM1) {
            for (int j = tid; j < 512; j += 256) hc_dec[b * 1024 + 512 + j] = 0.f;
            for (int j = tid; j < 1024; j += 256) hdhi[(size_t)b * 1024 + j] = (f16)0.f;
            break;
        }
        __syncthreads();

        if (tid < 248) {
            int s = tid >> 3, l8 = tid & 7;
            const f16* wr = Wcf + s * 1024;
            float p = 0.f;
            for (int j = l8 * 8; j < 1024; j += 64) {
                half8 w8 = *(const half8*)(wr + j);
#pragma unroll
                for (int e2 = 0; e2 < 8; e2++) p += (float)w8[e2] * sh_hc[j + e2];
            }
            p += __shfl_xor(p, 1); p += __shfl_xor(p, 2); p += __shfl_xor(p, 4);
            if (l8 == 0) t1s[s] = p + bc[s];
        }
        __syncthreads();
        {
            int d = tid;
            float sc = ba[0];
            const f16* t2p = t2s + ((size_t)b * TM1) * DIMD + d;
            for (int s = 0; s < TM1; s++) sc += tanh_fast(t1s[s] + (float)t2p[s * DIMD]) * Wa[s];
            float mx = blockReduceMax256(sc, sred);
            float ex = __expf(sc - mx);
            float sm = blockReduceSum256(ex, sred);
            float w = (ex / sm) * inputs[((size_t)b * TM1 + t) * 257 + 1 + d];
            st2cc(Ahi + b * 768 + d, (f16)w);
            int j = tid * 2;
            half2v hv; hv[0] = (f16)sh_hc[j]; hv[1] = (f16)sh_hc[j + 1];
            st4cc(Ahi + b * 768 + 256 + j, __builtin_bit_cast(unsigned, hv));
        }
        sigdone(flags, EA_BASE + atile * 64 + (b & 63), (unsigned)(t + 1));

        // ===== phase G: g(t) = Ahi @ W^T (tile) =====
        waitdone(flags, EA_BASE + gtile * 64, 64, (unsigned)(t + 1));
        {
            float4 ra[8];
            floatx16 acc = {};
            for (int p = 0; p < 3; ++p) {
                ld8x16cc(pAg + p * 128, ra);
#pragma unroll
                for (int j = 0; j < 8; ++j) {
                    int lg = 2 * j + kq;
                    half8 ah = __builtin_bit_cast(half8, ra[j]);
                    half8 wh = *(const half8*)&sWh[p * 8192 + wrow + ((lg ^ swk) * 8)];
                    acc = __builtin_amdgcn_mfma_f32_32x32x16_f16(ah, wh, acc, 0, 0, 0);
                }
            }
#pragma unroll
            for (int rr = 0; rr < 16; ++rr) {
                int row = m0g + wm * 32 + (rr & 3) + 8 * (rr >> 2) + 4 * kq;
                st2cc(gCp + (size_t)row * 2048 + gcol, (f16)(acc[rr] + gbv));
            }
        }
        sigdone(flags, EG_BASE + gtile * 64 + gidx, (unsigned)(t + 1));
    }
}

// ---------------------------------------------------------------------------
// V GEMM (unchanged).
// ---------------------------------------------------------------------------
__global__ __launch_bounds__(256) void gemm_v(
    const f16* __restrict__ A, int lda,
    const f16* __restrict__ W, int ldw,
    const float* __restrict__ bias, f16* __restrict__ C, int ldc,
    int K, int NT, int MT, int NREP)
{
    __shared__ f16 sAh[64 * 64];
    __shared__ f16 sWh[64 * 64];
    int tid = threadIdx.x, bid = blockIdx.x;
    int nbase = bid % NT;
    int m0 = ((bid / NT) % MT) * 64;
    int lane = tid & 63, wid = tid >> 6;
    int wm = wid >> 1, wn = wid & 1;
    int rl = lane & 31, kq = lane >> 5;
    int sr = tid >> 2;
    int g0 = (tid & 3) * 2;
    int s0 = sr * 64 + ((g0 ^ (sr & 7)) * 8);
    int s1 = sr * 64 + (((g0 + 1) ^ (sr & 7)) * 8);
    int arow = (wm * 32 + rl) * 64;
    int wrow = (wn * 32 + rl) * 64;
    int sw = (rl & 7);

    const f16* pA = A + (size_t)(m0 + sr) * lda + g0 * 8;

    for (int r = 0; r < NREP; ++r) {
        int n0 = (nbase + r * NT) * 64;
        const f16* pW = W + (size_t)(n0 + sr) * ldw + g0 * 8;
        float4 rA0 = *(const float4*)(pA);
        float4 rA1 = *(const float4*)(pA + 8);
        float4 rW0 = *(const float4*)(pW);
        float4 rW1 = *(const float4*)(pW + 8);
        floatx16 acc = {};
        for (int k0 = 0; k0 < K; k0 += 64) {
            __syncthreads();
            *(float4*)&sAh[s0] = rA0; *(float4*)&sAh[s1] = rA1;
            *(float4*)&sWh[s0] = rW0; *(float4*)&sWh[s1] = rW1;
            __syncthreads();
            int kn = k0 + 64;
            if (kn < K) {
                rA0 = *(const float4*)(pA + kn); rA1 = *(const float4*)(pA + kn + 8);
                rW0 = *(const float4*)(pW + kn); rW1 = *(const float4*)(pW + kn + 8);
            }
#pragma unroll
            for (int kk = 0; kk < 64; kk += 16) {
                int lg = (kk >> 3) + kq;
                int off = ((lg ^ sw) * 8);
                half8 ah = *(const half8*)&sAh[arow + off];
                half8 wh = *(const half8*)&sWh[wrow + off];
                acc = __builtin_amdgcn_mfma_f32_32x32x16_f16(ah, wh, acc, 0, 0, 0);
            }
        }
        int col = n0 + wn * 32 + rl;
        float bv = bias[col];
#pragma unroll
        for (int rr = 0; rr < 16; ++rr) {
            int row = m0 + wm * 32 + (rr & 3) + 8 * (rr >> 2) + 4 * kq;
            C[(size_t)row * ldc + col] = (f16)(acc[rr] + bv);
        }
    }
}

// ---------------------------------------------------------------------------
// COOP decoder: per-producer done-words + sc0sc1 data.
// ---------------------------------------------------------------------------
__global__ __launch_bounds__(256, 2) void dec_coop(
    const float* __restrict__ inputs, const f16* __restrict__ V,
    const float* __restrict__ W2, const float* __restrict__ b2,
    const f16* __restrict__ enchi,
    const float* __restrict__ fcW, const float* __restrict__ fcb,
    const float* __restrict__ Wih,
    f16* __restrict__ gu, long long ustride,
    f16* __restrict__ hdhi,
    const float* __restrict__ fcfW, const float* __restrict__ fcfb,
    float* __restrict__ out,
    const f16* __restrict__ dWcf, const float* __restrict__ dbias,
    unsigned* __restrict__ flags)
{
    __shared__ f16 sW[4 * 4096];      // resident W tile (32 KB)
    __shared__ float su[512];
    __shared__ float sw2[512];
    __shared__ float s_c[512];
    __shared__ float s_att[TM1];
    __shared__ float sred[4];
    const int b = blockIdx.x, tid = threadIdx.x;
    const int lane = tid & 63, wid = tid >> 6;
    const int rl = lane & 31, kq = lane >> 5;

    const bool gact = (b < 384);
    int n0g = 0, m0g = 0, kbeg = 0, ksf = 0, didx = 0;
    if (b < 256) {            // gate tiles: K=512 (h only), slice 0
        n0g = 512 + (b & 63) * 32; m0g = (b >> 6) * 128; kbeg = 0; ksf = 0;
        didx = b & 63;
    } else if (b < 384) {     // su tiles: 2 ks over K=1024 ([h,c])
        int i = b - 256;
        n0g = (i & 15) * 32; m0g = ((i >> 4) & 3) * 128;
        ksf = i >> 6; kbeg = ksf * 512;
        didx = 64 + ksf * 16 + (i & 15);
    }
    const int gT = m0g >> 7;          // G-phase m-tile (0..3)
    const int sT = b >> 7;            // S-phase tile of this batch

    if (gact) {
        for (int u = tid; u < 512; u += 256) {
            int r = u >> 4, c = u & 15;
#pragma unroll
            for (int p = 0; p < 4; ++p) {
                *(float4*)&sW[p * 4096 + r * 128 + ((c ^ (r & 15)) * 8)] =
                    *(const float4*)(dWcf + (size_t)(n0g + r) * 1024 + kbeg + p * 128 + c * 8);
            }
        }
    }
    {
        int e = tid * 2;
        sw2[e] = W2[e]; sw2[e + 1] = W2[e + 1];
        s_c[e] = 0.f;  s_c[e + 1] = 0.f;
    }
    __syncthreads();

    const f16* pAg = hdhi + (size_t)(m0g + wid * 32 + rl) * 1024 + kbeg + kq * 8;
    const int gcol = n0g + rl;
    const float gbv = (gact && ksf == 0) ? dbias[gcol] : 0.f;
    f16* gCp = gu + (size_t)ksf * ustride;

    for (int t = 0; t < TM1; ++t) {
        // ===== phase G: gu(t) from hdhi =====
        if (gact) {
            if (t > 0) waitdone(flags, DS_BASE + gT * 128, 128, (unsigned)t);
            float4 ra[8];
            floatx16 acc = {};
            for (int p = 0; p < 4; ++p) {
                ld8x16cc(pAg + p * 128, ra);
#pragma unroll
                for (int j = 0; j < 8; ++j) {
                    int lg = 2 * j + kq;
                    half8 ah = __builtin_bit_cast(half8, ra[j]);
                    half8 wh = *(const half8*)&sW[p * 4096 + rl * 128 + ((lg ^ (rl & 15)) * 8)];
                    acc = __builtin_amdgcn_mfma_f32_32x32x16_f16(ah, wh, acc, 0, 0, 0);
                }
            }
#pragma unroll
            for (int rr = 0; rr < 16; ++rr) {
                int row = m0g + wid * 32 + (rr & 3) + 8 * (rr >> 2) + 4 * kq;
                st2cc(gCp + (size_t)row * 2560 + gcol, (f16)(acc[rr] + gbv));
            }
            sigdone(flags, DG_BASE + gT * 96 + didx, (unsigned)(t + 1));
        }

        // ===== phase S: dec_step(t) =====
        waitdone(flags, DG_BASE + sT * 96, 96, (unsigned)(t + 1));
        const bool last = (t == TM1 - 1);
        unsigned ug[6];
        {
            int e = tid * 2;
            const f16* q = gu + (size_t)b * 2560 + e;
            ld_gu6cc(q, q + ustride, ug);
            half2v a0 = __builtin_bit_cast(half2v, ug[0]);
            half2v a1 = __builtin_bit_cast(half2v, ug[1]);
            su[e]     = (float)a0[0] + (float)a1[0];
            su[e + 1] = (float)a0[1] + (float)a1[1];
        }
        __syncthreads();
        if (tid < 248) {
            int tp = tid >> 3, l8 = tid & 7;
            const f16* vrow = V + ((size_t)b * TM1 + tp) * 512;
            float p = 0.f;
            for (int j = l8 * 8; j < 512; j += 64) {
                half8 v8 = *(const half8*)(vrow + j);
#pragma unroll
                for (int e = 0; e < 8; e++)
                    p += tanh_fast(su[j + e] + (float)v8[e]) * sw2[j + e];
            }
            p += __shfl_xor(p, 1); p += __shfl_xor(p, 2); p += __shfl_xor(p, 4);
            if (l8 == 0) s_att[tp] = p + b2[0];
        }
        __syncthreads();
        if (tid < 64) {
            float v = (tid < TM1) ? s_att[tid] : -3.4e38f;
            float m = v;
#pragma unroll
            for (int k = 32; k > 0; k >>= 1) m = fmaxf(m, __shfl_xor(m, k));
            float e = (tid < TM1) ? __expf(v - m) : 0.f;
            float s = e;
#pragma unroll
            for (int k = 32; k > 0; k >>= 1) s += __shfl_xor(s, k);
            if (tid < TM1) s_att[tid] = e / s;
        }
        __syncthreads();

        float part, pctx = 0.f;
        {
            int e = tid * 2;
            float cx0 = 0.f, cx1 = 0.f;
            const f16* eh = enchi + (size_t)b * TM1 * 512 + e;
            for (int tp = 0; tp < TM1; tp++) {
                half2v v2 = *(const half2v*)(eh + tp * 512);
                cx0 += s_att[tp] * (float)v2[0];
                cx1 += s_att[tp] * (float)v2[1];
            }
            float2 fw = *(const float2*)(fcW + e);
            part = cx0 * fw.x + cx1 * fw.y;
            if (last) {
                float2 fw2 = *(const float2*)(fcfW + 512 + e);
                pctx = cx0 * fw2.x + cx1 * fw2.y;
            }
        }
        float y = inputs[((size_t)b * TM1 + t) * 257];
        float ysum = blockReduceSum256(part, sred);
        float y_til = ysum + y * fcW[512] + fcb[0];

        float ph = 0.f;
        {
            int e = tid * 2;
            half2v a = __builtin_bit_cast(half2v, ug[2]);
            half2v f = __builtin_bit_cast(half2v, ug[3]);
            half2v gv = __builtin_bit_cast(half2v, ug[4]);
            half2v o = __builtin_bit_cast(half2v, ug[5]);
            float gi0 = (float)a[0], gi1 = (float)a[1];
            float gf0 = (float)f[0], gf1 = (float)f[1];
            float gg0 = (float)gv[0], gg1 = (float)gv[1];
            float go0 = (float)o[0], go1 = (float)o[1];
            gi0 += y_til * Wih[e];        gi1 += y_til * Wih[e + 1];
            gf0 += y_til * Wih[512 + e];  gf1 += y_til * Wih[512 + e + 1];
            gg0 += y_til * Wih[1024 + e]; gg1 += y_til * Wih[1024 + e + 1];
            go0 += y_til * Wih[1536 + e]; go1 += y_til * Wih[1536 + e + 1];
            float c20 = sigmf(gf0) * s_c[e]     + sigmf(gi0) * tanh_fast(gg0);
            float c21 = sigmf(gf1) * s_c[e + 1] + sigmf(gi1) * tanh_fast(gg1);
            float h20 = sigmf(go0) * tanh_fast(c20);
            float h21 = sigmf(go1) * tanh_fast(c21);
            if (!last) {
                s_c[e] = c20; s_c[e + 1] = c21;
                half2v hv; hv[0] = (f16)h20; hv[1] = (f16)h21;
                half2v cv; cv[0] = (f16)c20; cv[1] = (f16)c21;
                st4cc(hdhi + (size_t)b * 1024 + e, __builtin_bit_cast(unsigned, hv));
                st4cc(hdhi + (size_t)b * 1024 + 512 + e, __builtin_bit_cast(unsigned, cv));
            } else {
                ph += h20 * fcfW[e] + h21 * fcfW[e + 1];
            }
        }
        if (!last) {
            sigdone(flags, DS_BASE + sT * 128 + (b & 127), (unsigned)(t + 1));
        } else {
            float s = blockReduceSum256(ph + pctx, sred);
            if (tid == 0) out[b] = s + fcfb[0];
        }
    }
}

extern "C" void kernel_launch(void* const* d_in, const int* in_sizes, int n_in,
                              void* d_out, int out_size, void* d_ws, size_t ws_size,
                              hipStream_t stream) {
    const float* inputs  = (const float*)d_in[0];
    const float* eWih    = (const float*)d_in[1];
    const float* eWhh    = (const float*)d_in[2];
    const float* ebih    = (const float*)d_in[3];
    const float* ebhh    = (const float*)d_in[4];
    const float* eWc     = (const float*)d_in[5];
    const float* ebc     = (const float*)d_in[6];
    const float* eWd     = (const float*)d_in[7];
    const float* ebd     = (const float*)d_in[8];
    const float* eWa     = (const float*)d_in[9];
    const float* eba     = (const float*)d_in[10];
    const float* dW1     = (const float*)d_in[11];
    const float* db1     = (const float*)d_in[12];
    const float* dW2     = (const float*)d_in[13];
    const float* db2     = (const float*)d_in[14];
    const float* dWih    = (const float*)d_in[15];
    const float* dWhh    = (const float*)d_in[16];
    const float* dbih    = (const float*)d_in[17];
    const float* dbhh    = (const float*)d_in[18];
    const float* fcW     = (const float*)d_in[19];
    const float* fcb     = (const float*)d_in[20];
    const float* fcfW    = (const float*)d_in[21];
    const float* fcfb    = (const float*)d_in[22];
    float* out = (float*)d_out;

    float* scr = (float*)d_ws;
    f16* t2s = (f16*)scr;                       // 4,063,232 h
    f16* Vf  = (f16*)scr;                       // 8,126,464 h
    f16* g0e = (f16*)(scr + 4063232);           // 2 x 1,048,576 h
    f16* gu0 = (f16*)(scr + 4063232);           // 2 x 1,310,720 h
    // hc_enc hole doubles as the done-word region (coop never uses hc_enc;
    // fallback never uses flags — prep's zeroing is harmless either way).
    float* hc_enc = scr + 6684672;              //   524,288 f (2 MB hole)
    unsigned* flags = (unsigned*)(scr + 6684672); // 1920 entries x 64B = 120 KB
    f16*   Ahi    = (f16*)(scr + 7208960);      //   393,216 h
    float* hc_dec = scr + 7405568;              //   524,288 f
    f16*   hdhi   = (f16*)(scr + 7929856);      //   524,288 h
    f16* fp = (f16*)(scr + 8192000);
    f16* eWf   = fp;             fp += 1572864;
    f16* dWcf  = fp;             fp += 2621440;
    f16* Vwf   = fp;             fp += 262144;
    f16* enchi = fp;             fp += 8126464;
    float* ebcomb = (float*)(((uintptr_t)fp + 15) & ~(uintptr_t)15);
    float* dbias  = ebcomb + 2048;              // 2560 f
    f16* Wcf = (f16*)(dbias + 2560);            // 31,744 h

    hipLaunchKernelGGL(prep_t2s_kernel, dim3(2048), dim3(256), 0, stream,
                       inputs, eWih, eWhh, ebih, ebhh, dW1, dWhh, dbih, dbhh,
                       eWd, ebd, eWc, eWf, dWcf, Vwf,
                       ebcomb, dbias, t2s, Wcf, flags);

    long long gstride = 1048576;   // halves per g slice
    long long ustride = 1310720;   // halves per gu slice

    // -------- encoder: cooperative; fall back to per-step on launch error --
    bool enc_ok = false;
    {
        void* a[] = {(void*)&inputs, (void*)&t2s, (void*)&Wcf, (void*)&ebc,
                     (void*)&eWa, (void*)&eba, (void*)&g0e, (void*)&gstride,
                     (void*)&Ahi, (void*)&enchi, (void*)&hc_dec, (void*)&hdhi,
                     (void*)&eWf, (void*)&ebcomb, (void*)&flags};
        enc_ok = (hipLaunchCooperativeKernel((const void*)enc_coop, dim3(512),
                                             dim3(256), a, 0, stream) == hipSuccess);
    }
    if (!enc_ok) {
        for (int t = 0; t < TM1; t++) {
            hipLaunchKernelGGL(enc_step_kernel, dim3(BATCH), dim3(256), 0, stream,
                               inputs, t2s, Wcf, ebc, eWa, eba, g0e, gstride, hc_enc,
                               Ahi, enchi, hc_dec, hdhi, t);
            hipLaunchKernelGGL(gemm1f, dim3(512), dim3(256), 0, stream,
                               Ahi, 768, eWf, 768, ebcomb,
                               g0e, 2048, gstride, 768, 1 << 30, 32, 8, 2);
        }
        hipLaunchKernelGGL(enc_step_kernel, dim3(BATCH), dim3(256), 0, stream,
                           inputs, t2s, Wcf, ebc, eWa, eba, g0e, gstride, hc_enc,
                           Ahi, enchi, hc_dec, hdhi, TM1);
    }

    // -------- V = enc_out @ dec_W1[:,1024:]^T + b1 (f16 out) --------
    hipLaunchKernelGGL(gemm_v, dim3(992), dim3(256), 0, stream,
                       enchi, 512, Vwf, 512, db1,
                       Vf, 512, 512, 4, 248, 2);

    // -------- decoder: cooperative; fall back to per-step on launch error --
    bool dec_ok = false;
    {
        void* a[] = {(void*)&inputs, (void*)&Vf, (void*)&dW2, (void*)&db2,
                     (void*)&enchi, (void*)&fcW, (void*)&fcb, (void*)&dWih,
                     (void*)&gu0, (void*)&ustride, (void*)&hdhi,
                     (void*)&fcfW, (void*)&fcfb, (void*)&out,
                     (void*)&dWcf, (void*)&dbias, (void*)&flags};
        dec_ok = (hipLaunchCooperativeKernel((const void*)dec_coop, dim3(512),
                                             dim3(256), a, 0, stream) == hipSuccess);
    }
    if (!dec_ok) {
        for (int t = 0; t < TM1; t++) {
            hipLaunchKernelGGL(gemm1f, dim3(640), dim3(256), 0, stream,
                               hdhi, 1024, dWcf, 1024, dbias,
                               gu0, 2560, ustride, 1024, 512, 40, 8, 2);
            hipLaunchKernelGGL(dec_step_kernel, dim3(BATCH), dim3(256), 0, stream,
                               inputs, Vf, dW2, db2, enchi, fcW, fcb, dWih,
                               gu0, ustride, hc_dec, hdhi, fcfW, fcfb, out, t);
        }
    }
}

// Round 10
// 1674.669 us; speedup vs baseline: 10.5230x; 1.0882x over previous
//
#include <hip/hip_runtime.h>
#include <math.h>

#define BATCH 512
#define TM1   31
#define DIMD  256

typedef _Float16 f16;
typedef _Float16 half2v __attribute__((ext_vector_type(2)));
typedef _Float16 half8 __attribute__((ext_vector_type(8)));
typedef float floatx16 __attribute__((ext_vector_type(16)));
typedef float floatx4 __attribute__((ext_vector_type(4)));

__device__ __forceinline__ float sigmf(float x) { return 1.f / (1.f + __expf(-x)); }

__device__ __forceinline__ float tanh_fast(float x) {
    float ax = fabsf(x);
    float t  = __expf(-2.f * ax);
    float r  = (1.f - t) / (1.f + t);
    return copysignf(r, x);
}

__device__ __forceinline__ float blockReduceSum256(float v, float* sred) {
#pragma unroll
    for (int m = 32; m > 0; m >>= 1) v += __shfl_xor(v, m);
    __syncthreads();
    if ((threadIdx.x & 63) == 0) sred[threadIdx.x >> 6] = v;
    __syncthreads();
    return sred[0] + sred[1] + sred[2] + sred[3];
}

__device__ __forceinline__ float blockReduceMax256(float v, float* sred) {
#pragma unroll
    for (int m = 32; m > 0; m >>= 1) v = fmaxf(v, __shfl_xor(v, m));
    __syncthreads();
    if ((threadIdx.x & 63) == 0) sred[threadIdx.x >> 6] = v;
    __syncthreads();
    return fmaxf(fmaxf(sred[0], sred[1]), fmaxf(sred[2], sred[3]));
}

// ---------------------------------------------------------------------------
// Coherence-point (sc0 sc1) access helpers: write-through to IF$, loads
// bypass stale per-XCD L2. No cache-maintenance ops needed anywhere.
// R28: bulk sc-stores are 16B (dwordx4) via LDS staging; payload is an
// ext_vector floatx4 (clang rejects HIP float4 struct as asm INPUT operand).
// ---------------------------------------------------------------------------
__device__ __forceinline__ void st16cc(f16* p, floatx4 v) {
    asm volatile("global_store_dwordx4 %0, %1, off sc0 sc1" :: "v"(p), "v"(v) : "memory");
}
__device__ __forceinline__ void st4cc(void* p, unsigned v) {
    asm volatile("global_store_dword %0, %1, off sc0 sc1" :: "v"(p), "v"(v) : "memory");
}
__device__ __forceinline__ unsigned ld4cc(const unsigned* p) {
    unsigned v;
    asm volatile("global_load_dword %0, %1, off sc0 sc1\n\ts_waitcnt vmcnt(0)"
                 : "=v"(v) : "v"(p) : "memory");
    return v;
}
// 8 x 16B contiguous-stride (32B apart) loads, one waitcnt.
__device__ __forceinline__ void ld8x16cc(const f16* base, float4* r) {
    asm volatile(
        "global_load_dwordx4 %0, %8, off sc0 sc1\n\t"
        "global_load_dwordx4 %1, %8, off offset:32 sc0 sc1\n\t"
        "global_load_dwordx4 %2, %8, off offset:64 sc0 sc1\n\t"
        "global_load_dwordx4 %3, %8, off offset:96 sc0 sc1\n\t"
        "global_load_dwordx4 %4, %8, off offset:128 sc0 sc1\n\t"
        "global_load_dwordx4 %5, %8, off offset:160 sc0 sc1\n\t"
        "global_load_dwordx4 %6, %8, off offset:192 sc0 sc1\n\t"
        "global_load_dwordx4 %7, %8, off offset:224 sc0 sc1\n\t"
        "s_waitcnt vmcnt(0)"
        : "=&v"(r[0]), "=&v"(r[1]), "=&v"(r[2]), "=&v"(r[3]),
          "=&v"(r[4]), "=&v"(r[5]), "=&v"(r[6]), "=&v"(r[7])
        : "v"(base) : "memory");
}
// enc A-phase: 8 x 4B gate loads from two slices.
__device__ __forceinline__ void ld_g8cc(const f16* q0, const f16* q1, unsigned* u) {
    asm volatile(
        "global_load_dword %0, %8, off sc0 sc1\n\t"
        "global_load_dword %1, %8, off offset:1024 sc0 sc1\n\t"
        "global_load_dword %2, %8, off offset:2048 sc0 sc1\n\t"
        "global_load_dword %3, %8, off offset:3072 sc0 sc1\n\t"
        "global_load_dword %4, %9, off sc0 sc1\n\t"
        "global_load_dword %5, %9, off offset:1024 sc0 sc1\n\t"
        "global_load_dword %6, %9, off offset:2048 sc0 sc1\n\t"
        "global_load_dword %7, %9, off offset:3072 sc0 sc1\n\t"
        "s_waitcnt vmcnt(0)"
        : "=&v"(u[0]), "=&v"(u[1]), "=&v"(u[2]), "=&v"(u[3]),
          "=&v"(u[4]), "=&v"(u[5]), "=&v"(u[6]), "=&v"(u[7])
        : "v"(q0), "v"(q1) : "memory");
}
// dec S-phase: su (2 slices) + 4 gates (slice 0), 6 x 4B.
__device__ __forceinline__ void ld_gu6cc(const f16* q, const f16* q1, unsigned* u) {
    const f16* qo = q + 2048;
    asm volatile(
        "global_load_dword %0, %6, off sc0 sc1\n\t"
        "global_load_dword %1, %7, off sc0 sc1\n\t"
        "global_load_dword %2, %6, off offset:1024 sc0 sc1\n\t"
        "global_load_dword %3, %6, off offset:2048 sc0 sc1\n\t"
        "global_load_dword %4, %6, off offset:3072 sc0 sc1\n\t"
        "global_load_dword %5, %8, off sc0 sc1\n\t"
        "s_waitcnt vmcnt(0)"
        : "=&v"(u[0]), "=&v"(u[1]), "=&v"(u[2]), "=&v"(u[3]), "=&v"(u[4]), "=&v"(u[5])
        : "v"(q), "v"(q1), "v"(qo) : "memory");
}

// ---------------------------------------------------------------------------
// Per-producer done-words (R25-proven): signal = plain sc0sc1 store of the
// monotonic step number; waiter = wave 0, lane l polls producer l, __all().
// Spin bound 2^12 turns any liveness bug into a fast wrong-answer, no hang.
//   EA  = 0    : 8 tiles x 64 producers   (enc A-phase)
//   EG  = 512  : 8 tiles x 64 producers   (enc G-phase)
//   DG  = 1024 : 4 tiles x 96 producers   (dec G-phase)
//   DS  = 1408 : 4 tiles x 128 producers  (dec S-phase)
// ---------------------------------------------------------------------------
#define EA_BASE 0
#define EG_BASE 512
#define DG_BASE 1024
#define DS_BASE 1408

__device__ __forceinline__ void sigdone(unsigned* d, int entry, unsigned val) {
    asm volatile("s_waitcnt vmcnt(0)" ::: "memory");
    __syncthreads();
    if (threadIdx.x == 0)
        st4cc(d + (size_t)entry * 16, val);
}
__device__ __forceinline__ void waitdone(unsigned* d, int base, int n, unsigned tgt) {
    if (threadIdx.x < 64) {
        int l = threadIdx.x;
        const unsigned* p0 = d + (size_t)(base + l) * 16;
        const unsigned* p1 = d + (size_t)(base + 64 + l) * 16;
        const bool one = l < n;
        const bool two = (64 + l) < n;
        for (int it = 0; it < (1 << 12); ++it) {
            unsigned v0 = one ? ld4cc(p0) : tgt;
            unsigned v1 = two ? ld4cc(p1) : tgt;
            if (__all(v0 >= tgt && v1 >= tgt)) break;
            __builtin_amdgcn_s_sleep(1);
        }
    }
    __syncthreads();
    __builtin_amdgcn_sched_barrier(0);
}

// ---------------------------------------------------------------------------
// prep + t2s fused (+ done-word zeroing).
// ---------------------------------------------------------------------------
__global__ __launch_bounds__(256) void prep_t2s_kernel(
    const float* __restrict__ inputs,
    const float* __restrict__ eWih, const float* __restrict__ eWhh,
    const float* __restrict__ ebih, const float* __restrict__ ebhh,
    const float* __restrict__ dW1,  const float* __restrict__ dWhh,
    const float* __restrict__ dbih, const float* __restrict__ dbhh,
    const float* __restrict__ Wd,   const float* __restrict__ bd,
    const float* __restrict__ Wc,
    f16* __restrict__ eWf, f16* __restrict__ dWcf, f16* __restrict__ Vwf,
    float* __restrict__ ebcomb, float* __restrict__ dbias,
    f16* __restrict__ t2s, f16* __restrict__ Wcf,
    unsigned* __restrict__ flags)
{
    __shared__ float sX[TM1 * DIMD];
    __shared__ float sWd[TM1 * TM1];
    int b = blockIdx.x, tid = threadIdx.x;
    int idx = b * 256 + tid;
    const int stride = gridDim.x * 256;

    if (b < 512) {
        for (int i = tid; i < TM1 * DIMD; i += 256) {
            int tt = i >> 8, d = i & 255;
            sX[i] = inputs[((size_t)b * TM1 + tt) * 257 + 1 + d];
        }
        for (int i = tid; i < TM1 * TM1; i += 256) sWd[i] = Wd[i];
        __syncthreads();
        int d = tid;
        for (int s = 0; s < TM1; s++) {
            float acc = bd[s];
            for (int tt = 0; tt < TM1; tt++) acc += sX[tt * DIMD + d] * sWd[s * TM1 + tt];
            t2s[((size_t)b * TM1 + s) * DIMD + d] = (f16)acc;
        }
    }

    for (int g = idx; g < 2048 * 96; g += stride) {
        int n = g / 96, k0 = (g % 96) * 8;
        const float* src = (k0 < 256) ? (eWih + n * 256 + k0)
                                      : (eWhh + n * 512 + (k0 - 256));
        float4 v0 = *(const float4*)src;
        float4 v1 = *(const float4*)(src + 4);
        f16 h[8] = {(f16)v0.x, (f16)v0.y, (f16)v0.z, (f16)v0.w,
                    (f16)v1.x, (f16)v1.y, (f16)v1.z, (f16)v1.w};
        *(half8*)(eWf + n * 768 + k0) = *(half8*)h;
    }
    for (int g = idx; g < 2560 * 128; g += stride) {
        int n = g >> 7, k0 = (g & 127) * 8;
        float vv[8] = {};
        if (n < 512) {
            const float* src = dW1 + n * 1536 + k0;
            float4 v0 = *(const float4*)src, v1 = *(const float4*)(src + 4);
            vv[0]=v0.x; vv[1]=v0.y; vv[2]=v0.z; vv[3]=v0.w;
            vv[4]=v1.x; vv[5]=v1.y; vv[6]=v1.z; vv[7]=v1.w;
        } else if (k0 < 512) {
            const float* src = dWhh + (n - 512) * 512 + k0;
            float4 v0 = *(const float4*)src, v1 = *(const float4*)(src + 4);
            vv[0]=v0.x; vv[1]=v0.y; vv[2]=v0.z; vv[3]=v0.w;
            vv[4]=v1.x; vv[5]=v1.y; vv[6]=v1.z; vv[7]=v1.w;
        }
        f16 h[8];
#pragma unroll
        for (int e = 0; e < 8; e++) h[e] = (f16)vv[e];
        *(half8*)(dWcf + n * 1024 + k0) = *(half8*)h;
    }
    for (int g = idx; g < 512 * 64; g += stride) {
        int n = g >> 6, k0 = (g & 63) * 8;
        const float* src = dW1 + n * 1536 + 1024 + k0;
        float4 v0 = *(const float4*)src, v1 = *(const float4*)(src + 4);
        f16 h[8] = {(f16)v0.x, (f16)v0.y, (f16)v0.z, (f16)v0.w,
                    (f16)v1.x, (f16)v1.y, (f16)v1.z, (f16)v1.w};
        *(half8*)(Vwf + n * 512 + k0) = *(half8*)h;
    }
    for (int g = idx; g < 3968; g += stride) {
        int k0 = g * 8;
        float4 v0 = *(const float4*)(Wc + k0);
        float4 v1 = *(const float4*)(Wc + k0 + 4);
        f16 h[8] = {(f16)v0.x, (f16)v0.y, (f16)v0.z, (f16)v0.w,
                    (f16)v1.x, (f16)v1.y, (f16)v1.z, (f16)v1.w};
        *(half8*)(Wcf + k0) = *(half8*)h;
    }
    for (int i = idx; i < 2048; i += stride) ebcomb[i] = ebih[i] + ebhh[i];
    for (int i = idx; i < 2560; i += stride)
        dbias[i] = (i < 512) ? 0.f : (dbih[i - 512] + dbhh[i - 512]);
    for (int i = idx; i < 1920 * 16; i += stride) flags[i] = 0u;
}

// ---------------------------------------------------------------------------
// FALLBACK: step GEMM (R14-validated).
// ---------------------------------------------------------------------------
__global__ __launch_bounds__(256) void gemm1f(
    const f16* __restrict__ A, int lda,
    const f16* __restrict__ W, int ldw,
    const float* __restrict__ bias, f16* __restrict__ C, int ldc,
    long long Cstride, int K, int nsplit, int NT, int MT, int KS)
{
    __shared__ f16 sAh[64 * 128];
    __shared__ f16 sWh[64 * 128];
    int tid = threadIdx.x, bid = blockIdx.x;
    int nbase = bid % NT;
    int m0 = ((bid / NT) % MT) * 64;
    int ks = bid / (NT * MT);
    int lane = tid & 63, wid = tid >> 6;
    int wm = wid >> 1, wn = wid & 1;
    int rl = lane & 31, kq = lane >> 5;

    int sr = tid >> 2;
    int gb = (tid & 3) * 4;
    int st0 = sr * 128 + (((gb + 0) ^ (sr & 15)) * 8);
    int st1 = sr * 128 + (((gb + 1) ^ (sr & 15)) * 8);
    int st2 = sr * 128 + (((gb + 2) ^ (sr & 15)) * 8);
    int st3 = sr * 128 + (((gb + 3) ^ (sr & 15)) * 8);
    int arow = (wm * 32 + rl) * 128;
    int wrow = (wn * 32 + rl) * 128;
    int swk = rl & 15;

    int n0 = nbase * 64;
    int Kfull = (n0 >= nsplit) ? 512 : K;
    int ksz = Kfull / KS;
    int kbeg = ks * ksz, kend = kbeg + ksz;

    const f16* pA = A + (size_t)(m0 + sr) * lda + gb * 8;
    const f16* pW = W + (size_t)(n0 + sr) * ldw + gb * 8;

    float4 rA0 = *(const float4*)(pA + kbeg);
    float4 rA1 = *(const float4*)(pA + kbeg + 8);
    float4 rA2 = *(const float4*)(pA + kbeg + 16);
    float4 rA3 = *(const float4*)(pA + kbeg + 24);
    float4 rW0 = *(const float4*)(pW + kbeg);
    float4 rW1 = *(const float4*)(pW + kbeg + 8);
    float4 rW2 = *(const float4*)(pW + kbeg + 16);
    float4 rW3 = *(const float4*)(pW + kbeg + 24);

    floatx16 acc = {};
    for (int k0 = kbeg; k0 < kend; k0 += 128) {
        __syncthreads();
        *(float4*)&sAh[st0] = rA0; *(float4*)&sAh[st1] = rA1;
        *(float4*)&sAh[st2] = rA2; *(float4*)&sAh[st3] = rA3;
        *(float4*)&sWh[st0] = rW0; *(float4*)&sWh[st1] = rW1;
        *(float4*)&sWh[st2] = rW2; *(float4*)&sWh[st3] = rW3;
        __syncthreads();
        int kn = k0 + 128;
        if (kn < kend) {
            rA0 = *(const float4*)(pA + kn);      rA1 = *(const float4*)(pA + kn + 8);
            rA2 = *(const float4*)(pA + kn + 16); rA3 = *(const float4*)(pA + kn + 24);
            rW0 = *(const float4*)(pW + kn);      rW1 = *(const float4*)(pW + kn + 8);
            rW2 = *(const float4*)(pW + kn + 16); rW3 = *(const float4*)(pW + kn + 24);
        }
#pragma unroll
        for (int kk = 0; kk < 128; kk += 16) {
            int lg = (kk >> 3) + kq;
            half8 ah = *(const half8*)&sAh[arow + ((lg ^ swk) * 8)];
            half8 wh = *(const half8*)&sWh[wrow + ((lg ^ swk) * 8)];
            acc = __builtin_amdgcn_mfma_f32_32x32x16_f16(ah, wh, acc, 0, 0, 0);
        }
    }

    int col = n0 + wn * 32 + rl;
    float bv = (ks == 0) ? bias[col] : 0.f;
    f16* Cp = C + (size_t)ks * Cstride;
#pragma unroll
    for (int rr = 0; rr < 16; ++rr) {
        int row = m0 + wm * 32 + (rr & 3) + 8 * (rr >> 2) + 4 * kq;
        Cp[(size_t)row * ldc + col] = (f16)(acc[rr] + bv);
    }
}

// ---------------------------------------------------------------------------
// FALLBACK: encoder step (R14-validated).
// ---------------------------------------------------------------------------
__global__ __launch_bounds__(256) void enc_step_kernel(
    const float* __restrict__ inputs, const f16* __restrict__ t2s,
    const f16* __restrict__ Wcf, const float* __restrict__ bc,
    const float* __restrict__ Wa, const float* __restrict__ ba,
    const f16* __restrict__ g, long long gstride,
    float* __restrict__ hc,
    f16* __restrict__ Ahi, f16* __restrict__ enchi,
    float* __restrict__ hc_dec, f16* __restrict__ hdhi,
    int t) {
    __shared__ float sh_hc[1024];
    __shared__ float t1s[32];
    __shared__ float sred[4];
    int b = blockIdx.x, tid = threadIdx.x;

    if (t > 0) {
        int e = tid * 2;
        const f16* gp = g + (size_t)b * 2048 + e;
        float gi0 = 0.f, gi1 = 0.f, gf0 = 0.f, gf1 = 0.f;
        float gg0 = 0.f, gg1 = 0.f, go0 = 0.f, go1 = 0.f;
#pragma unroll
        for (int s = 0; s < 2; s++) {
            const f16* q = gp + s * gstride;
            half2v a = *(const half2v*)(q);
            half2v f = *(const half2v*)(q + 512);
            half2v gv = *(const half2v*)(q + 1024);
            half2v o = *(const half2v*)(q + 1536);
            gi0 += (float)a[0]; gi1 += (float)a[1];
            gf0 += (float)f[0]; gf1 += (float)f[1];
            gg0 += (float)gv[0]; gg1 += (float)gv[1];
            go0 += (float)o[0]; go1 += (float)o[1];
        }
        float2 cpv = *(const float2*)(hc + b * 1024 + 512 + e);
        float c20 = sigmf(gf0) * cpv.x + sigmf(gi0) * tanh_fast(gg0);
        float c21 = sigmf(gf1) * cpv.y + sigmf(gi1) * tanh_fast(gg1);
        float h20 = sigmf(go0) * tanh_fast(c20);
        float h21 = sigmf(go1) * tanh_fast(c21);
        *(float2*)(hc + b * 1024 + 512 + e) = make_float2(c20, c21);
        sh_hc[e] = h20; sh_hc[e + 1] = h21;
        sh_hc[512 + e] = c20; sh_hc[512 + e + 1] = c21;
        half2v hv; hv[0] = (f16)h20; hv[1] = (f16)h21;
        *(half2v*)(enchi + ((size_t)b * TM1 + (t - 1)) * 512 + e) = hv;
    } else {
        for (int j = tid; j < 1024; j += 256) { sh_hc[j] = 0.f; }
        for (int j = tid; j < 512; j += 256) hc[b * 1024 + 512 + j] = 0.f;
    }
    if (t == TM1) {
        for (int j = tid; j < 512; j += 256) hc_dec[b * 1024 + 512 + j] = 0.f;
        for (int j = tid; j < 1024; j += 256) hdhi[b * 1024 + j] = (f16)0.f;
        return;
    }
    __syncthreads();

    if (tid < 248) {
        int s = tid >> 3, l8 = tid & 7;
        const f16* wrow = Wcf + s * 1024;
        float p = 0.f;
        for (int j = l8 * 8; j < 1024; j += 64) {
            half8 w8 = *(const half8*)(wrow + j);
#pragma unroll
            for (int e = 0; e < 8; e++) p += (float)w8[e] * sh_hc[j + e];
        }
        p += __shfl_xor(p, 1); p += __shfl_xor(p, 2); p += __shfl_xor(p, 4);
        if (l8 == 0) t1s[s] = p + bc[s];
    }
    __syncthreads();

    int d = tid;
    float sc = ba[0];
    const f16* t2p = t2s + ((size_t)b * TM1) * DIMD + d;
    for (int s = 0; s < TM1; s++) sc += tanh_fast(t1s[s] + (float)t2p[s * DIMD]) * Wa[s];
    float mx = blockReduceMax256(sc, sred);
    float ex = __expf(sc - mx);
    float sm = blockReduceSum256(ex, sred);
    float w = (ex / sm) * inputs[((size_t)b * TM1 + t) * 257 + 1 + d];
    Ahi[b * 768 + d] = (f16)w;
    {
        int j = tid * 2;
        half2v hv; hv[0] = (f16)sh_hc[j]; hv[1] = (f16)sh_hc[j + 1];
        *(half2v*)(Ahi + b * 768 + 256 + j) = hv;
    }
}

// ---------------------------------------------------------------------------
// FALLBACK: decoder step (R14-validated).
// ---------------------------------------------------------------------------
__global__ __launch_bounds__(256) void dec_step_kernel(
    const float* __restrict__ inputs, const f16* __restrict__ V,
    const float* __restrict__ W2, const float* __restrict__ b2,
    const f16* __restrict__ enchi,
    const float* __restrict__ fcW, const float* __restrict__ fcb,
    const float* __restrict__ Wih,
    const f16* __restrict__ gu, long long ustride,
    float* __restrict__ hc, f16* __restrict__ hdhi,
    const float* __restrict__ fcfW, const float* __restrict__ fcfb,
    float* __restrict__ out, int t) {
    __shared__ float su[512];
    __shared__ float sw2[512];
    __shared__ float s_att[TM1];
    __shared__ float sred[4];
    int b = blockIdx.x, tid = threadIdx.x;
    const bool last = (t == TM1 - 1);
    {
        int e = tid * 2;
        const f16* q = gu + (size_t)b * 2560 + e;
        half2v a0 = *(const half2v*)(q);
        half2v a1 = *(const half2v*)(q + ustride);
        su[e]     = (float)a0[0] + (float)a1[0];
        su[e + 1] = (float)a0[1] + (float)a1[1];
        sw2[e] = W2[e]; sw2[e + 1] = W2[e + 1];
    }
    __syncthreads();
    if (tid < 248) {
        int tp = tid >> 3, l8 = tid & 7;
        const f16* vrow = V + ((size_t)b * TM1 + tp) * 512;
        float p = 0.f;
        for (int j = l8 * 8; j < 512; j += 64) {
            half8 v8 = *(const half8*)(vrow + j);
#pragma unroll
            for (int e = 0; e < 8; e++)
                p += tanh_fast(su[j + e] + (float)v8[e]) * sw2[j + e];
        }
        p += __shfl_xor(p, 1); p += __shfl_xor(p, 2); p += __shfl_xor(p, 4);
        if (l8 == 0) s_att[tp] = p + b2[0];
    }
    __syncthreads();
    if (tid < 64) {
        float v = (tid < TM1) ? s_att[tid] : -3.4e38f;
        float m = v;
#pragma unroll
        for (int k = 32; k > 0; k >>= 1) m = fmaxf(m, __shfl_xor(m, k));
        float e = (tid < TM1) ? __expf(v - m) : 0.f;
        float s = e;
#pragma unroll
        for (int k = 32; k > 0; k >>= 1) s += __shfl_xor(s, k);
        if (tid < TM1) s_att[tid] = e / s;
    }
    __syncthreads();

    float part, pctx = 0.f;
    {
        int e = tid * 2;
        float cx0 = 0.f, cx1 = 0.f;
        const f16* eh = enchi + (size_t)b * TM1 * 512 + e;
        for (int tp = 0; tp < TM1; tp++) {
            half2v v2 = *(const half2v*)(eh + tp * 512);
            cx0 += s_att[tp] * (float)v2[0];
            cx1 += s_att[tp] * (float)v2[1];
        }
        float2 fw = *(const float2*)(fcW + e);
        part = cx0 * fw.x + cx1 * fw.y;
        if (last) {
            float2 fw2 = *(const float2*)(fcfW + 512 + e);
            pctx = cx0 * fw2.x + cx1 * fw2.y;
        }
    }
    float y = inputs[((size_t)b * TM1 + t) * 257];
    float ysum = blockReduceSum256(part, sred);
    float y_til = ysum + y * fcW[512] + fcb[0];

    float ph = 0.f;
    {
        int e = tid * 2;
        const f16* q = gu + (size_t)b * 2560 + e;
        float gi0 = 0.f, gi1 = 0.f, gf0 = 0.f, gf1 = 0.f;
        float gg0 = 0.f, gg1 = 0.f, go0 = 0.f, go1 = 0.f;
#pragma unroll
        for (int s = 0; s < 2; s++) {
            const f16* qq = q + s * ustride;
            half2v a = *(const half2v*)(qq + 512);
            half2v f = *(const half2v*)(qq + 1024);
            half2v gv = *(const half2v*)(qq + 1536);
            half2v o = *(const half2v*)(qq + 2048);
            gi0 += (float)a[0]; gi1 += (float)a[1];
            gf0 += (float)f[0]; gf1 += (float)f[1];
            gg0 += (float)gv[0]; gg1 += (float)gv[1];
            go0 += (float)o[0]; go1 += (float)o[1];
        }
        gi0 += y_til * Wih[e];        gi1 += y_til * Wih[e + 1];
        gf0 += y_til * Wih[512 + e];  gf1 += y_til * Wih[512 + e + 1];
        gg0 += y_til * Wih[1024 + e]; gg1 += y_til * Wih[1024 + e + 1];
        go0 += y_til * Wih[1536 + e]; go1 += y_til * Wih[1536 + e + 1];
        float2 cpv = *(const float2*)(hc + b * 1024 + 512 + e);
        float c20 = sigmf(gf0) * cpv.x + sigmf(gi0) * tanh_fast(gg0);
        float c21 = sigmf(gf1) * cpv.y + sigmf(gi1) * tanh_fast(gg1);
        float h20 = sigmf(go0) * tanh_fast(c20);
        float h21 = sigmf(go1) * tanh_fast(c21);
        if (!last) {
            *(float2*)(hc + b * 1024 + 512 + e) = make_float2(c20, c21);
            half2v hv; hv[0] = (f16)h20; hv[1] = (f16)h21;
            half2v cv; cv[0] = (f16)c20; cv[1] = (f16)c21;
            *(half2v*)(hdhi + (size_t)b * 1024 + e) = hv;
            *(half2v*)(hdhi + (size_t)b * 1024 + 512 + e) = cv;
        } else {
            ph += h20 * fcfW[e] + h21 * fcfW[e + 1];
        }
    }
    if (last) {
        float s = blockReduceSum256(ph + pctx, sred);
        if (tid == 0) out[b] = s + fcfb[0];
    }
}

// ---------------------------------------------------------------------------
// COOP encoder: done-words + sc0sc1 data, 16B-staged epilogue stores (R28).
// ---------------------------------------------------------------------------
__global__ __launch_bounds__(256, 2) void enc_coop(
    const float* __restrict__ inputs, const f16* __restrict__ t2s,
    const f16* __restrict__ Wcf, const float* __restrict__ bc,
    const float* __restrict__ Wa, const float* __restrict__ ba,
    f16* __restrict__ g, long long gstride,
    f16* __restrict__ Ahi, f16* __restrict__ enchi,
    float* __restrict__ hc_dec, f16* __restrict__ hdhi,
    const f16* __restrict__ eWf, const float* __restrict__ ebcomb,
    unsigned* __restrict__ flags)
{
    __shared__ f16 sWh[3 * 8192];                  // resident W tile (48 KB)
    __shared__ __align__(16) f16 sCst[64 * 80];    // C staging (10 KB), pitch 80
    __shared__ __align__(16) f16 sAst[768];        // Ahi staging (1.5 KB)
    __shared__ float sh_hc[1024];
    __shared__ float t1s[32];
    __shared__ float sred[4];
    const int b = blockIdx.x, tid = threadIdx.x;

    const int lane = tid & 63, wid = tid >> 6;
    const int wm = wid >> 1, wn = wid & 1;
    const int rl = lane & 31, kq = lane >> 5;
    const int sr = tid >> 2;
    const int gb = (tid & 3) * 4;
    const int st0 = sr * 128 + (((gb + 0) ^ (sr & 15)) * 8);
    const int st1 = sr * 128 + (((gb + 1) ^ (sr & 15)) * 8);
    const int st2_ = sr * 128 + (((gb + 2) ^ (sr & 15)) * 8);
    const int st3 = sr * 128 + (((gb + 3) ^ (sr & 15)) * 8);
    const int n0g = (b & 31) * 64;
    const int m0g = ((b >> 5) & 7) * 64;
    const int ksg = b >> 8;
    const int kbeg = ksg * 384;
    const int wrow = (wn * 32 + rl) * 128;
    const int swk = rl & 15;
    const int atile = b >> 6;                       // tile of this block's batch row
    const int gtile = (b >> 5) & 7;                 // m-tile this block computes in G
    const int gidx  = (b & 31) | (ksg << 5);        // producer index within G tile
    const f16* pW  = eWf + (size_t)(n0g + sr) * 768 + gb * 8;
    const f16* pAg = Ahi + (size_t)(m0g + wm * 32 + rl) * 768 + kbeg + kq * 8;
    const float gbv = (ksg == 0) ? ebcomb[n0g + wn * 32 + rl] : 0.f;
    f16* gCp = g + (size_t)ksg * gstride;

    // one-time resident W preload (normal loads; written by prep cross-kernel)
#pragma unroll
    for (int p = 0; p < 3; ++p) {
        *(float4*)&sWh[p * 8192 + st0]  = *(const float4*)(pW + kbeg + p * 128);
        *(float4*)&sWh[p * 8192 + st1]  = *(const float4*)(pW + kbeg + p * 128 + 8);
        *(float4*)&sWh[p * 8192 + st2_] = *(const float4*)(pW + kbeg + p * 128 + 16);
        *(float4*)&sWh[p * 8192 + st3]  = *(const float4*)(pW + kbeg + p * 128 + 24);
    }
    __syncthreads();

    for (int t = 0; t <= TM1; ++t) {
        // ===== phase A: finalize LSTM(t-1) + attention(t) =====
        if (t > 0) {
            waitdone(flags, EG_BASE + atile * 64, 64, (unsigned)t);
            int e = tid * 2;
            unsigned u[8];
            const f16* q0 = g + (size_t)b * 2048 + e;
            ld_g8cc(q0, q0 + gstride, u);
            half2v a0 = __builtin_bit_cast(half2v, u[0]), a1 = __builtin_bit_cast(half2v, u[4]);
            half2v f0 = __builtin_bit_cast(half2v, u[1]), f1 = __builtin_bit_cast(half2v, u[5]);
            half2v g0 = __builtin_bit_cast(half2v, u[2]), g1 = __builtin_bit_cast(half2v, u[6]);
            half2v o0 = __builtin_bit_cast(half2v, u[3]), o1 = __builtin_bit_cast(half2v, u[7]);
            float gi0 = (float)a0[0] + (float)a1[0], gi1 = (float)a0[1] + (float)a1[1];
            float gf0 = (float)f0[0] + (float)f1[0], gf1 = (float)f0[1] + (float)f1[1];
            float gg0 = (float)g0[0] + (float)g1[0], gg1 = (float)g0[1] + (float)g1[1];
            float go0 = (float)o0[0] + (float)o1[0], go1 = (float)o0[1] + (float)o1[1];
            float c0 = sh_hc[512 + e], c1 = sh_hc[513 + e];
            float c20 = sigmf(gf0) * c0 + sigmf(gi0) * tanh_fast(gg0);
            float c21 = sigmf(gf1) * c1 + sigmf(gi1) * tanh_fast(gg1);
            float h20 = sigmf(go0) * tanh_fast(c20);
            float h21 = sigmf(go1) * tanh_fast(c21);
            sh_hc[e] = h20; sh_hc[e + 1] = h21;
            sh_hc[512 + e] = c20; sh_hc[513 + e] = c21;
            half2v hv; hv[0] = (f16)h20; hv[1] = (f16)h21;
            *(half2v*)(enchi + ((size_t)b * TM1 + (t - 1)) * 512 + e) = hv;
        } else {
            for (int j = tid; j < 1024; j += 256) sh_hc[j] = 0.f;
        }
        if (t == TM1) {
            for (int j = tid; j < 512; j += 256) hc_dec[b * 1024 + 512 + j] = 0.f;
            for (int j = tid; j < 1024; j += 256) hdhi[(size_t)b * 1024 + j] = (f16)0.f;
            break;
        }
        __syncthreads();

        if (tid < 248) {
            int s = tid >> 3, l8 = tid & 7;
            const f16* wr = Wcf + s * 1024;
            float p = 0.f;
            for (int j = l8 * 8; j < 1024; j += 64) {
                half8 w8 = *(const half8*)(wr + j);
#pragma unroll
                for (int e2 = 0; e2 < 8; e2++) p += (float)w8[e2] * sh_hc[j + e2];
            }
            p += __shfl_xor(p, 1); p += __shfl_xor(p, 2); p += __shfl_xor(p, 4);
            if (l8 == 0) t1s[s] = p + bc[s];
        }
        __syncthreads();
        {
            int d = tid;
            float sc = ba[0];
            const f16* t2p = t2s + ((size_t)b * TM1) * DIMD + d;
            for (int s = 0; s < TM1; s++) sc += tanh_fast(t1s[s] + (float)t2p[s * DIMD]) * Wa[s];
            float mx = blockReduceMax256(sc, sred);
            float ex = __expf(sc - mx);
            float sm = blockReduceSum256(ex, sred);
            float w = (ex / sm) * inputs[((size_t)b * TM1 + t) * 257 + 1 + d];
            sAst[tid] = (f16)w;
            int j = tid * 2;
            half2v hv; hv[0] = (f16)sh_hc[j]; hv[1] = (f16)sh_hc[j + 1];
            *(half2v*)&sAst[256 + j] = hv;
        }
        __syncthreads();
        if (tid < 96) {
            floatx4 v = *(const floatx4*)&sAst[tid * 8];
            st16cc(Ahi + b * 768 + tid * 8, v);
        }
        sigdone(flags, EA_BASE + atile * 64 + (b & 63), (unsigned)(t + 1));

        // ===== phase G: g(t) = Ahi @ W^T (tile) =====
        waitdone(flags, EA_BASE + gtile * 64, 64, (unsigned)(t + 1));
        {
            float4 ra[8];
            floatx16 acc = {};
            for (int p = 0; p < 3; ++p) {
                ld8x16cc(pAg + p * 128, ra);
#pragma unroll
                for (int j = 0; j < 8; ++j) {
                    int lg = 2 * j + kq;
                    half8 ah = __builtin_bit_cast(half8, ra[j]);
                    half8 wh = *(const half8*)&sWh[p * 8192 + wrow + ((lg ^ swk) * 8)];
                    acc = __builtin_amdgcn_mfma_f32_32x32x16_f16(ah, wh, acc, 0, 0, 0);
                }
            }
            // stage C tile to LDS (bias added), then 16B sc-stores
            int rbase = wm * 32 + 4 * kq;
            int cl = wn * 32 + rl;
#pragma unroll
            for (int rr = 0; rr < 16; ++rr) {
                int row = rbase + (rr & 3) + 8 * (rr >> 2);
                sCst[row * 80 + cl] = (f16)(acc[rr] + gbv);
            }
            __syncthreads();
#pragma unroll
            for (int c = 0; c < 2; ++c) {
                int chunk = tid + c * 256;
                int row = chunk >> 3, o8 = (chunk & 7) * 8;
                floatx4 v = *(const floatx4*)&sCst[row * 80 + o8];
                st16cc(gCp + (size_t)(m0g + row) * 2048 + n0g + o8, v);
            }
        }
        sigdone(flags, EG_BASE + gtile * 64 + gidx, (unsigned)(t + 1));
    }
}

// ---------------------------------------------------------------------------
// V GEMM (unchanged).
// ---------------------------------------------------------------------------
__global__ __launch_bounds__(256) void gemm_v(
    const f16* __restrict__ A, int lda,
    const f16* __restrict__ W, int ldw,
    const float* __restrict__ bias, f16* __restrict__ C, int ldc,
    int K, int NT, int MT, int NREP)
{
    __shared__ f16 sAh[64 * 64];
    __shared__ f16 sWh[64 * 64];
    int tid = threadIdx.x, bid = blockIdx.x;
    int nbase = bid % NT;
    int m0 = ((bid / NT) % MT) * 64;
    int lane = tid & 63, wid = tid >> 6;
    int wm = wid >> 1, wn = wid & 1;
    int rl = lane & 31, kq = lane >> 5;
    int sr = tid >> 2;
    int g0 = (tid & 3) * 2;
    int s0 = sr * 64 + ((g0 ^ (sr & 7)) * 8);
    int s1 = sr * 64 + (((g0 + 1) ^ (sr & 7)) * 8);
    int arow = (wm * 32 + rl) * 64;
    int wrow = (wn * 32 + rl) * 64;
    int sw = (rl & 7);

    const f16* pA = A + (size_t)(m0 + sr) * lda + g0 * 8;

    for (int r = 0; r < NREP; ++r) {
        int n0 = (nbase + r * NT) * 64;
        const f16* pW = W + (size_t)(n0 + sr) * ldw + g0 * 8;
        float4 rA0 = *(const float4*)(pA);
        float4 rA1 = *(const float4*)(pA + 8);
        float4 rW0 = *(const float4*)(pW);
        float4 rW1 = *(const float4*)(pW + 8);
        floatx16 acc = {};
        for (int k0 = 0; k0 < K; k0 += 64) {
            __syncthreads();
            *(float4*)&sAh[s0] = rA0; *(float4*)&sAh[s1] = rA1;
            *(float4*)&sWh[s0] = rW0; *(float4*)&sWh[s1] = rW1;
            __syncthreads();
            int kn = k0 + 64;
            if (kn < K) {
                rA0 = *(const float4*)(pA + kn); rA1 = *(const float4*)(pA + kn + 8);
                rW0 = *(const float4*)(pW + kn); rW1 = *(const float4*)(pW + kn + 8);
            }
#pragma unroll
            for (int kk = 0; kk < 64; kk += 16) {
                int lg = (kk >> 3) + kq;
                int off = ((lg ^ sw) * 8);
                half8 ah = *(const half8*)&sAh[arow + off];
                half8 wh = *(const half8*)&sWh[wrow + off];
                acc = __builtin_amdgcn_mfma_f32_32x32x16_f16(ah, wh, acc, 0, 0, 0);
            }
        }
        int col = n0 + wn * 32 + rl;
        float bv = bias[col];
#pragma unroll
        for (int rr = 0; rr < 16; ++rr) {
            int row = m0 + wm * 32 + (rr & 3) + 8 * (rr >> 2) + 4 * kq;
            C[(size_t)row * ldc + col] = (f16)(acc[rr] + bv);
        }
    }
}

// ---------------------------------------------------------------------------
// COOP decoder: done-words + sc0sc1 data, 16B-staged epilogue stores (R28).
// ---------------------------------------------------------------------------
__global__ __launch_bounds__(256, 2) void dec_coop(
    const float* __restrict__ inputs, const f16* __restrict__ V,
    const float* __restrict__ W2, const float* __restrict__ b2,
    const f16* __restrict__ enchi,
    const float* __restrict__ fcW, const float* __restrict__ fcb,
    const float* __restrict__ Wih,
    f16* __restrict__ gu, long long ustride,
    f16* __restrict__ hdhi,
    const float* __restrict__ fcfW, const float* __restrict__ fcfb,
    float* __restrict__ out,
    const f16* __restrict__ dWcf, const float* __restrict__ dbias,
    unsigned* __restrict__ flags)
{
    __shared__ f16 sW[4 * 4096];                   // resident W tile (32 KB)
    __shared__ __align__(16) f16 sCst[128 * 48];   // C staging (12 KB), pitch 48
    __shared__ __align__(16) f16 sHst[1024];       // hdhi staging (2 KB)
    __shared__ float su[512];
    __shared__ float sw2[512];
    __shared__ float s_c[512];
    __shared__ float s_att[TM1];
    __shared__ float sred[4];
    const int b = blockIdx.x, tid = threadIdx.x;
    const int lane = tid & 63, wid = tid >> 6;
    const int rl = lane & 31, kq = lane >> 5;

    const bool gact = (b < 384);
    int n0g = 0, m0g = 0, kbeg = 0, ksf = 0, didx = 0;
    if (b < 256) {            // gate tiles: K=512 (h only), slice 0
        n0g = 512 + (b & 63) * 32; m0g = (b >> 6) * 128; kbeg = 0; ksf = 0;
        didx = b & 63;
    } else if (b < 384) {     // su tiles: 2 ks over K=1024 ([h,c])
        int i = b - 256;
        n0g = (i & 15) * 32; m0g = ((i >> 4) & 3) * 128;
        ksf = i >> 6; kbeg = ksf * 512;
        didx = 64 + ksf * 16 + (i & 15);
    }
    const int gT = m0g >> 7;          // G-phase m-tile (0..3)
    const int sT = b >> 7;            // S-phase tile of this batch

    if (gact) {
        for (int u = tid; u < 512; u += 256) {
            int r = u >> 4, c = u & 15;
#pragma unroll
            for (int p = 0; p < 4; ++p) {
                *(float4*)&sW[p * 4096 + r * 128 + ((c ^ (r & 15)) * 8)] =
                    *(const float4*)(dWcf + (size_t)(n0g + r) * 1024 + kbeg + p * 128 + c * 8);
            }
        }
    }
    {
        int e = tid * 2;
        sw2[e] = W2[e]; sw2[e + 1] = W2[e + 1];
        s_c[e] = 0.f;  s_c[e + 1] = 0.f;
    }
    __syncthreads();

    const f16* pAg = hdhi + (size_t)(m0g + wid * 32 + rl) * 1024 + kbeg + kq * 8;
    const float gbv = (gact && ksf == 0) ? dbias[n0g + rl] : 0.f;
    f16* gCp = gu + (size_t)ksf * ustride;

    for (int t = 0; t < TM1; ++t) {
        // ===== phase G: gu(t) from hdhi =====
        if (gact) {
            if (t > 0) waitdone(flags, DS_BASE + gT * 128, 128, (unsigned)t);
            float4 ra[8];
            floatx16 acc = {};
            for (int p = 0; p < 4; ++p) {
                ld8x16cc(pAg + p * 128, ra);
#pragma unroll
                for (int j = 0; j < 8; ++j) {
                    int lg = 2 * j + kq;
                    half8 ah = __builtin_bit_cast(half8, ra[j]);
                    half8 wh = *(const half8*)&sW[p * 4096 + rl * 128 + ((lg ^ (rl & 15)) * 8)];
                    acc = __builtin_amdgcn_mfma_f32_32x32x16_f16(ah, wh, acc, 0, 0, 0);
                }
            }
            // stage C tile (128 rows x 32 cols) to LDS, then 16B sc-stores
            int rbase = wid * 32 + 4 * kq;
#pragma unroll
            for (int rr = 0; rr < 16; ++rr) {
                int row = rbase + (rr & 3) + 8 * (rr >> 2);
                sCst[row * 48 + rl] = (f16)(acc[rr] + gbv);
            }
            __syncthreads();
#pragma unroll
            for (int c = 0; c < 2; ++c) {
                int chunk = tid + c * 256;
                int row = chunk >> 2, o8 = (chunk & 3) * 8;
                floatx4 v = *(const floatx4*)&sCst[row * 48 + o8];
                st16cc(gCp + (size_t)(m0g + row) * 2560 + n0g + o8, v);
            }
            sigdone(flags, DG_BASE + gT * 96 + didx, (unsigned)(t + 1));
        }

        // ===== phase S: dec_step(t) =====
        waitdone(flags, DG_BASE + sT * 96, 96, (unsigned)(t + 1));
        const bool last = (t == TM1 - 1);
        unsigned ug[6];
        {
            int e = tid * 2;
            const f16* q = gu + (size_t)b * 2560 + e;
            ld_gu6cc(q, q + ustride, ug);
            half2v a0 = __builtin_bit_cast(half2v, ug[0]);
            half2v a1 = __builtin_bit_cast(half2v, ug[1]);
            su[e]     = (float)a0[0] + (float)a1[0];
            su[e + 1] = (float)a0[1] + (float)a1[1];
        }
        __syncthreads();
        if (tid < 248) {
            int tp = tid >> 3, l8 = tid & 7;
            const f16* vrow = V + ((size_t)b * TM1 + tp) * 512;
            float p = 0.f;
            for (int j = l8 * 8; j < 512; j += 64) {
                half8 v8 = *(const half8*)(vrow + j);
#pragma unroll
                for (int e = 0; e < 8; e++)
                    p += tanh_fast(su[j + e] + (float)v8[e]) * sw2[j + e];
            }
            p += __shfl_xor(p, 1); p += __shfl_xor(p, 2); p += __shfl_xor(p, 4);
            if (l8 == 0) s_att[tp] = p + b2[0];
        }
        __syncthreads();
        if (tid < 64) {
            float v = (tid < TM1) ? s_att[tid] : -3.4e38f;
            float m = v;
#pragma unroll
            for (int k = 32; k > 0; k >>= 1) m = fmaxf(m, __shfl_xor(m, k));
            float e = (tid < TM1) ? __expf(v - m) : 0.f;
            float s = e;
#pragma unroll
            for (int k = 32; k > 0; k >>= 1) s += __shfl_xor(s, k);
            if (tid < TM1) s_att[tid] = e / s;
        }
        __syncthreads();

        float part, pctx = 0.f;
        {
            int e = tid * 2;
            float cx0 = 0.f, cx1 = 0.f;
            const f16* eh = enchi + (size_t)b * TM1 * 512 + e;
            for (int tp = 0; tp < TM1; tp++) {
                half2v v2 = *(const half2v*)(eh + tp * 512);
                cx0 += s_att[tp] * (float)v2[0];
                cx1 += s_att[tp] * (float)v2[1];
            }
            float2 fw = *(const float2*)(fcW + e);
            part = cx0 * fw.x + cx1 * fw.y;
            if (last) {
                float2 fw2 = *(const float2*)(fcfW + 512 + e);
                pctx = cx0 * fw2.x + cx1 * fw2.y;
            }
        }
        float y = inputs[((size_t)b * TM1 + t) * 257];
        float ysum = blockReduceSum256(part, sred);
        float y_til = ysum + y * fcW[512] + fcb[0];

        float ph = 0.f;
        {
            int e = tid * 2;
            half2v a = __builtin_bit_cast(half2v, ug[2]);
            half2v f = __builtin_bit_cast(half2v, ug[3]);
            half2v gv = __builtin_bit_cast(half2v, ug[4]);
            half2v o = __builtin_bit_cast(half2v, ug[5]);
            float gi0 = (float)a[0], gi1 = (float)a[1];
            float gf0 = (float)f[0], gf1 = (float)f[1];
            float gg0 = (float)gv[0], gg1 = (float)gv[1];
            float go0 = (float)o[0], go1 = (float)o[1];
            gi0 += y_til * Wih[e];        gi1 += y_til * Wih[e + 1];
            gf0 += y_til * Wih[512 + e];  gf1 += y_til * Wih[512 + e + 1];
            gg0 += y_til * Wih[1024 + e]; gg1 += y_til * Wih[1024 + e + 1];
            go0 += y_til * Wih[1536 + e]; go1 += y_til * Wih[1536 + e + 1];
            float c20 = sigmf(gf0) * s_c[e]     + sigmf(gi0) * tanh_fast(gg0);
            float c21 = sigmf(gf1) * s_c[e + 1] + sigmf(gi1) * tanh_fast(gg1);
            float h20 = sigmf(go0) * tanh_fast(c20);
            float h21 = sigmf(go1) * tanh_fast(c21);
            if (!last) {
                s_c[e] = c20; s_c[e + 1] = c21;
                half2v hv; hv[0] = (f16)h20; hv[1] = (f16)h21;
                half2v cv; cv[0] = (f16)c20; cv[1] = (f16)c21;
                *(half2v*)&sHst[e] = hv;
                *(half2v*)&sHst[512 + e] = cv;
            } else {
                ph += h20 * fcfW[e] + h21 * fcfW[e + 1];
            }
        }
        if (!last) {
            __syncthreads();
            if (tid < 128) {
                floatx4 v = *(const floatx4*)&sHst[tid * 8];
                st16cc(hdhi + (size_t)b * 1024 + tid * 8, v);
            }
            sigdone(flags, DS_BASE + sT * 128 + (b & 127), (unsigned)(t + 1));
        } else {
            float s = blockReduceSum256(ph + pctx, sred);
            if (tid == 0) out[b] = s + fcfb[0];
        }
    }
}

extern "C" void kernel_launch(void* const* d_in, const int* in_sizes, int n_in,
                              void* d_out, int out_size, void* d_ws, size_t ws_size,
                              hipStream_t stream) {
    const float* inputs  = (const float*)d_in[0];
    const float* eWih    = (const float*)d_in[1];
    const float* eWhh    = (const float*)d_in[2];
    const float* ebih    = (const float*)d_in[3];
    const float* ebhh    = (const float*)d_in[4];
    const float* eWc     = (const float*)d_in[5];
    const float* ebc     = (const float*)d_in[6];
    const float* eWd     = (const float*)d_in[7];
    const float* ebd     = (const float*)d_in[8];
    const float* eWa     = (const float*)d_in[9];
    const float* eba     = (const float*)d_in[10];
    const float* dW1     = (const float*)d_in[11];
    const float* db1     = (const float*)d_in[12];
    const float* dW2     = (const float*)d_in[13];
    const float* db2     = (const float*)d_in[14];
    const float* dWih    = (const float*)d_in[15];
    const float* dWhh    = (const float*)d_in[16];
    const float* dbih    = (const float*)d_in[17];
    const float* dbhh    = (const float*)d_in[18];
    const float* fcW     = (const float*)d_in[19];
    const float* fcb     = (const float*)d_in[20];
    const float* fcfW    = (const float*)d_in[21];
    const float* fcfb    = (const float*)d_in[22];
    float* out = (float*)d_out;

    float* scr = (float*)d_ws;
    f16* t2s = (f16*)scr;                       // 4,063,232 h
    f16* Vf  = (f16*)scr;                       // 8,126,464 h
    f16* g0e = (f16*)(scr + 4063232);           // 2 x 1,048,576 h
    f16* gu0 = (f16*)(scr + 4063232);           // 2 x 1,310,720 h
    // hc_enc hole doubles as the done-word region (coop never uses hc_enc;
    // fallback never uses flags — prep's zeroing is harmless either way).
    float* hc_enc = scr + 6684672;              //   524,288 f (2 MB hole)
    unsigned* flags = (unsigned*)(scr + 6684672); // 1920 entries x 64B = 120 KB
    f16*   Ahi    = (f16*)(scr + 7208960);      //   393,216 h
    float* hc_dec = scr + 7405568;              //   524,288 f
    f16*   hdhi   = (f16*)(scr + 7929856);      //   524,288 h
    f16* fp = (f16*)(scr + 8192000);
    f16* eWf   = fp;             fp += 1572864;
    f16* dWcf  = fp;             fp += 2621440;
    f16* Vwf   = fp;             fp += 262144;
    f16* enchi = fp;             fp += 8126464;
    float* ebcomb = (float*)(((uintptr_t)fp + 15) & ~(uintptr_t)15);
    float* dbias  = ebcomb + 2048;              // 2560 f
    f16* Wcf = (f16*)(dbias + 2560);            // 31,744 h

    hipLaunchKernelGGL(prep_t2s_kernel, dim3(2048), dim3(256), 0, stream,
                       inputs, eWih, eWhh, ebih, ebhh, dW1, dWhh, dbih, dbhh,
                       eWd, ebd, eWc, eWf, dWcf, Vwf,
                       ebcomb, dbias, t2s, Wcf, flags);

    long long gstride = 1048576;   // halves per g slice
    long long ustride = 1310720;   // halves per gu slice

    // -------- encoder: cooperative; fall back to per-step on launch error --
    bool enc_ok = false;
    {
        void* a[] = {(void*)&inputs, (void*)&t2s, (void*)&Wcf, (void*)&ebc,
                     (void*)&eWa, (void*)&eba, (void*)&g0e, (void*)&gstride,
                     (void*)&Ahi, (void*)&enchi, (void*)&hc_dec, (void*)&hdhi,
                     (void*)&eWf, (void*)&ebcomb, (void*)&flags};
        enc_ok = (hipLaunchCooperativeKernel((const void*)enc_coop, dim3(512),
                                             dim3(256), a, 0, stream) == hipSuccess);
    }
    if (!enc_ok) {
        for (int t = 0; t < TM1; t++) {
            hipLaunchKernelGGL(enc_step_kernel, dim3(BATCH), dim3(256), 0, stream,
                               inputs, t2s, Wcf, ebc, eWa, eba, g0e, gstride, hc_enc,
                               Ahi, enchi, hc_dec, hdhi, t);
            hipLaunchKernelGGL(gemm1f, dim3(512), dim3(256), 0, stream,
                               Ahi, 768, eWf, 768, ebcomb,
                               g0e, 2048, gstride, 768, 1 << 30, 32, 8, 2);
        }
        hipLaunchKernelGGL(enc_step_kernel, dim3(BATCH), dim3(256), 0, stream,
                           inputs, t2s, Wcf, ebc, eWa, eba, g0e, gstride, hc_enc,
                           Ahi, enchi, hc_dec, hdhi, TM1);
    }

    // -------- V = enc_out @ dec_W1[:,1024:]^T + b1 (f16 out) --------
    hipLaunchKernelGGL(gemm_v, dim3(992), dim3(256), 0, stream,
                       enchi, 512, Vwf, 512, db1,
                       Vf, 512, 512, 4, 248, 2);

    // -------- decoder: cooperative; fall back to per-step on launch error --
    bool dec_ok = false;
    {
        void* a[] = {(void*)&inputs, (void*)&Vf, (void*)&dW2, (void*)&db2,
                     (void*)&enchi, (void*)&fcW, (void*)&fcb, (void*)&dWih,
                     (void*)&gu0, (void*)&ustride, (void*)&hdhi,
                     (void*)&fcfW, (void*)&fcfb, (void*)&out,
                     (void*)&dWcf, (void*)&dbias, (void*)&flags};
        dec_ok = (hipLaunchCooperativeKernel((const void*)dec_coop, dim3(512),
                                             dim3(256), a, 0, stream) == hipSuccess);
    }
    if (!dec_ok) {
        for (int t = 0; t < TM1; t++) {
            hipLaunchKernelGGL(gemm1f, dim3(640), dim3(256), 0, stream,
                               hdhi, 1024, dWcf, 1024, dbias,
                               gu0, 2560, ustride, 1024, 512, 40, 8, 2);
            hipLaunchKernelGGL(dec_step_kernel, dim3(BATCH), dim3(256), 0, stream,
                               inputs, Vf, dW2, db2, enchi, fcW, fcb, dWih,
                               gu0, ustride, hc_dec, hdhi, fcfW, fcfb, out, t);
        }
    }
}